// Round 1
// baseline (1059.297 us; speedup 1.0000x reference)
//
#include <hip/hip_runtime.h>

typedef unsigned short u16;
typedef short s16x8 __attribute__((ext_vector_type(8)));
typedef u16 u16x4 __attribute__((ext_vector_type(4)));
typedef float f32x4 __attribute__((ext_vector_type(4)));

#define T_N   1024
#define NEGV  -1e6f
#define MB    (1L << 20)

__device__ __forceinline__ u16 f2bf(float f) {
    unsigned u = __float_as_uint(f);
    u += 0x7fffu + ((u >> 16) & 1u);     // RNE
    return (u16)(u >> 16);
}
__device__ __forceinline__ float bf2f(u16 h) {
    return __uint_as_float(((unsigned)h) << 16);
}
__device__ __forceinline__ f32x4 mfma16(s16x8 a, s16x8 b, f32x4 c) {
    return __builtin_amdgcn_mfma_f32_16x16x32_bf16(a, b, c, 0, 0, 0);
}
// async global->LDS, 16B per lane; LDS dest = wave-uniform base + lane*16 (m97/m104)
__device__ __forceinline__ void gll16(const u16* g, u16* l) {
    __builtin_amdgcn_global_load_lds((const __attribute__((address_space(1))) void*)g,
                                     (__attribute__((address_space(3))) void*)l, 16, 0, 0);
}

// ---------------------------------------------------------------- transpose+cast
struct P6 { const float* s[6]; u16* d[6]; };

__global__ __launch_bounds__(256) void transpose_cast_batch(P6 pp, int K, int N) {
    const float* __restrict__ src = pp.s[blockIdx.z];
    u16* __restrict__ dst = pp.d[blockIdx.z];
    __shared__ float tile[32][33];
    int nb = blockIdx.x * 32, kb = blockIdx.y * 32;
    int tx = threadIdx.x & 31, ty = threadIdx.x >> 5;   // ty 0..7
    #pragma unroll
    for (int i = 0; i < 4; i++)
        tile[ty + 8*i][tx] = src[(long)(kb + ty + 8*i) * N + nb + tx];
    __syncthreads();
    #pragma unroll
    for (int i = 0; i < 4; i++)
        dst[(long)(nb + ty + 8*i) * K + kb + tx] = f2bf(tile[tx][ty + 8*i]);
}

__global__ __launch_bounds__(256) void cast_bf16_kernel(const float* __restrict__ src,
                                                        u16* __restrict__ dst, long n) {
    long i = ((long)blockIdx.x * 256 + threadIdx.x) * 4;
    if (i >= n) return;
    float4 v = *(const float4*)(src + i);
    u16x4 o = { f2bf(v.x), f2bf(v.y), f2bf(v.z), f2bf(v.w) };
    *(u16x4*)(dst + i) = o;
}

// ---------------------------------------------------------------- GEMM: C[M,N] = A[M,K] * Bt[N,K]^T
// 128x128-tile fallback kernel (m97 structure) — used only for shapes that
// would under-fill the GPU with 256^2 tiles (M=64 stats GEMM, N=1024 Wo projections).
template<typename OutT, bool RELU, bool HAS_BIAS>
__global__ __launch_bounds__(256) void gemm_bt(
    const u16* __restrict__ A, const u16* __restrict__ Bt, OutT* __restrict__ C,
    const float* __restrict__ bias, int M, int N, int K,
    int lda, int ldb, int ldc,
    int batchDivA, long sA, long sB, long sC)
{
    A  += (long)(blockIdx.z / batchDivA) * sA;
    Bt += (long)blockIdx.z * sB;
    C  += (long)blockIdx.z * sC;
    __shared__ __align__(16) u16 As[4096];   // [128][32] row-major, 8 KB
    __shared__ __align__(16) u16 Bs[4096];
    const int tid = threadIdx.x;
    const int wave = tid >> 6, lane = tid & 63;
    const int quad = lane >> 4, l16 = lane & 15;
    const int wr = (wave >> 1) * 64, wc = (wave & 1) * 64;
    const long row0 = (long)blockIdx.y * 128, col0 = (long)blockIdx.x * 128;

    f32x4 acc[4][4] = {};

    const int l4r = lane >> 2;
    const int l4c = (lane & 3) * 8;
    const int ra = wave * 32 + l4r;
    const u16* Ap0 = A + (row0 + ra) * (long)lda + l4c;
    const u16* Ap1 = Ap0 + 16L * lda;
    const u16* Bp0 = Bt + (col0 + ra) * (long)ldb + l4c;
    const u16* Bp1 = Bp0 + 16L * ldb;
    u16* AsW0 = &As[(wave * 32) * 32];
    u16* AsW1 = &As[(wave * 32 + 16) * 32];
    u16* BsW0 = &Bs[(wave * 32) * 32];
    u16* BsW1 = &Bs[(wave * 32 + 16) * 32];
    const bool aok0 = (row0 + wave * 32) < M;
    const bool aok1 = (row0 + wave * 32 + 16) < M;

    for (int k0 = 0; k0 < K; k0 += 32) {
        __syncthreads();
        if (aok0) gll16(Ap0 + k0, AsW0);
        if (aok1) gll16(Ap1 + k0, AsW1);
        gll16(Bp0 + k0, BsW0);
        gll16(Bp1 + k0, BsW1);
        __syncthreads();
        s16x8 af[4], bfr[4];
        #pragma unroll
        for (int i = 0; i < 4; i++)
            af[i]  = *(const s16x8*)&As[(wr + i*16 + l16) * 32 + quad*8];
        #pragma unroll
        for (int j = 0; j < 4; j++)
            bfr[j] = *(const s16x8*)&Bs[(wc + j*16 + l16) * 32 + quad*8];
        #pragma unroll
        for (int i = 0; i < 4; i++)
            #pragma unroll
            for (int j = 0; j < 4; j++)
                acc[i][j] = mfma16(af[i], bfr[j], acc[i][j]);
    }

    #pragma unroll
    for (int i = 0; i < 4; i++) {
        long row = row0 + wr + i*16 + quad*4;
        #pragma unroll
        for (int j = 0; j < 4; j++) {
            long col = col0 + wc + j*16 + l16;
            float bv = 0.f;
            if constexpr (HAS_BIAS) bv = bias[col];
            #pragma unroll
            for (int r = 0; r < 4; r++) {
                if (row + r < M) {
                    float v = acc[i][j][r] + bv;
                    if constexpr (RELU) v = fmaxf(v, 0.f);
                    if constexpr (sizeof(OutT) == 2) C[(row + r) * (long)ldc + col] = f2bf(v);
                    else                             C[(row + r) * (long)ldc + col] = v;
                }
            }
        }
    }
}

// ---------------------------------------------------------------- GEMM 256^2, deep pipeline
// 256x256 tile, BK=32, 8 waves (2Mx4N), per-wave 128x64 output.
// 4-deep LDS ring buffer: 4 x (A[256][32] + B[256][32]) bf16 = 128 KiB total.
// Schedule (T3+T4+T5): per K-slice, 2 phases of
//   {ds_read frag subtile ; issue 2 global_load_lds for slice kt+3} -> s_barrier
//   -> lgkmcnt(0) -> setprio(1) + 16 MFMA + setprio(0) -> s_barrier
// with ONE counted s_waitcnt vmcnt(8) per K-slice (2 slices = 8 loads stay in
// flight across barriers; never drained to 0 in the hot loop). Epilogue 8->4->0.
// Write-hazard-free by construction: slot (kt+3)&3 was last read in slice kt-1,
// whose reads complete (lgkmcnt(0)) before its trailing barrier; stages for
// kt+3 are only issued after that barrier.
// Row stride is 64 B, so frag ds_read_b128 uses every bank exactly 8x/wave
// (port minimum) — no swizzle needed, and linear layout keeps gll16 legal.
// Requires: M%256==0, N%256==0, K%32==0, K>=128.
template<typename OutT, bool RELU, bool HAS_BIAS>
__global__ __launch_bounds__(512, 2) void gemm_bt256(
    const u16* __restrict__ A, const u16* __restrict__ Bt, OutT* __restrict__ C,
    const float* __restrict__ bias, int M, int N, int K,
    int lda, int ldb, int ldc,
    int batchDivA, long sA, long sB, long sC)
{
    A  += (long)(blockIdx.z / batchDivA) * sA;
    Bt += (long)blockIdx.z * sB;
    C  += (long)blockIdx.z * sC;
    __shared__ __align__(16) u16 As[4][8192];   // [256][32] each, 16 KB x4
    __shared__ __align__(16) u16 Bs[4][8192];
    const int tid = threadIdx.x;
    const int wave = tid >> 6, lane = tid & 63;
    const int quad = lane >> 4, l16 = lane & 15;
    const int wm = wave >> 2, wn = wave & 3;           // 2 x 4 wave grid
    const long row0 = (long)blockIdx.y * 256, col0 = (long)blockIdx.x * 256;

    // staging: thread t covers row (t>>2), element col (t&3)*8 of a 128-row round
    const int srow = tid >> 2;
    const int scol = (tid & 3) * 8;
    const u16* Ag = A  + (row0 + srow) * (long)lda + scol;
    const u16* Bg = Bt + (col0 + srow) * (long)ldb + scol;
    const int ldsoff = wave * 512;                      // wave-uniform elem offset

    f32x4 acc[8][4] = {};
    const int NT = K >> 5;

    auto stageA = [&](int kt, int buf) {
        gll16(Ag + (long)kt * 32,            &As[buf][ldsoff]);
        gll16(Ag + (long)kt * 32 + 128L*lda, &As[buf][4096 + ldsoff]);
    };
    auto stageB = [&](int kt, int buf) {
        gll16(Bg + (long)kt * 32,            &Bs[buf][ldsoff]);
        gll16(Bg + (long)kt * 32 + 128L*ldb, &Bs[buf][4096 + ldsoff]);
    };

    // prologue: slices 0,1,2 staged (12 loads/wave); wait until slice 0 landed
    stageA(0, 0); stageB(0, 0);
    stageA(1, 1); stageB(1, 1);
    stageA(2, 2); stageB(2, 2);
    asm volatile("s_waitcnt vmcnt(8)" ::: "memory");
    __builtin_amdgcn_s_barrier();

    const int arow = wm * 128 + l16;
    const int brow = wn * 64  + l16;
    const int kq   = quad * 8;

    for (int kt = 0; kt < NT; ++kt) {
        const int b  = kt & 3;
        const int sb = (kt + 3) & 3;
        const bool st = (kt + 3) < NT;
        const u16* Ab = As[b];
        const u16* Bb = Bs[b];

        // ---- phase A: frags {B all j, A i=0..3}; stage A(kt+3) ----
        s16x8 bfr[4], af[4];
        #pragma unroll
        for (int j = 0; j < 4; ++j)
            bfr[j] = *(const s16x8*)&Bb[(brow + j*16) * 32 + kq];
        #pragma unroll
        for (int i = 0; i < 4; ++i)
            af[i] = *(const s16x8*)&Ab[(arow + i*16) * 32 + kq];
        if (st) stageA(kt + 3, sb);
        __builtin_amdgcn_s_barrier();
        asm volatile("s_waitcnt lgkmcnt(0)" ::: "memory");
        __builtin_amdgcn_sched_barrier(0);
        __builtin_amdgcn_s_setprio(1);
        #pragma unroll
        for (int i = 0; i < 4; ++i)
            #pragma unroll
            for (int j = 0; j < 4; ++j)
                acc[i][j] = mfma16(af[i], bfr[j], acc[i][j]);
        __builtin_amdgcn_s_setprio(0);
        __builtin_amdgcn_s_barrier();

        // ---- phase B: frags {A i=4..7}; stage B(kt+3) ----
        #pragma unroll
        for (int i = 0; i < 4; ++i)
            af[i] = *(const s16x8*)&Ab[(arow + (i + 4)*16) * 32 + kq];
        if (st) stageB(kt + 3, sb);
        __builtin_amdgcn_s_barrier();
        asm volatile("s_waitcnt lgkmcnt(0)" ::: "memory");
        __builtin_amdgcn_sched_barrier(0);
        __builtin_amdgcn_s_setprio(1);
        #pragma unroll
        for (int i = 0; i < 4; ++i)
            #pragma unroll
            for (int j = 0; j < 4; ++j)
                acc[i + 4][j] = mfma16(af[i], bfr[j], acc[i + 4][j]);
        __builtin_amdgcn_s_setprio(0);

        // counted wait: keep up to 2 future slices (8 loads) in flight
        const int rem = NT - 2 - kt;
        if (rem >= 2)      asm volatile("s_waitcnt vmcnt(8)" ::: "memory");
        else if (rem == 1) asm volatile("s_waitcnt vmcnt(4)" ::: "memory");
        else if (rem == 0) asm volatile("s_waitcnt vmcnt(0)" ::: "memory");
        __builtin_amdgcn_s_barrier();
    }

    #pragma unroll
    for (int i = 0; i < 8; ++i) {
        const long row = row0 + wm*128 + i*16 + quad*4;
        #pragma unroll
        for (int j = 0; j < 4; ++j) {
            const long col = col0 + wn*64 + j*16 + l16;
            float bv = 0.f;
            if constexpr (HAS_BIAS) bv = bias[col];
            #pragma unroll
            for (int r = 0; r < 4; ++r) {
                float v = acc[i][j][r] + bv;
                if constexpr (RELU) v = fmaxf(v, 0.f);
                if constexpr (sizeof(OutT) == 2) C[(row + r) * (long)ldc + col] = f2bf(v);
                else                             C[(row + r) * (long)ldc + col] = v;
            }
        }
    }
}

// ---------------------------------------------------------------- flash attention (dh=64, H=16)
template<bool CAUSAL>
__global__ __launch_bounds__(256) void flash_attn_kernel(
    const u16* __restrict__ Q, const u16* __restrict__ Kg, const u16* __restrict__ Vg,
    const int* __restrict__ valid_len, u16* __restrict__ O,
    int qld, int kld, int vld)
{
    const int h = blockIdx.y, b = blockIdx.z;
    const int qt0 = blockIdx.x * 64;
    const int tid = threadIdx.x;
    const int wave = tid >> 6, lane = tid & 63;
    const int quad = lane >> 4, l16 = lane & 15;

    __shared__ __align__(16) u16 Qs[64][72];
    __shared__ __align__(16) u16 Ks[64][72];
    __shared__ __align__(16) u16 Vt[64][72];
    __shared__ __align__(16) u16 Ps[4][16][72];

    const int sr = tid >> 2, scc = (tid & 3) * 16;
    {
        const u16* qp = Q + ((long)b * T_N + qt0 + sr) * qld + h * 64 + scc;
        *(s16x8*)&Qs[sr][scc]     = *(const s16x8*)qp;
        *(s16x8*)&Qs[sr][scc + 8] = *(const s16x8*)(qp + 8);
    }
    float m_i[4] = {-1e30f, -1e30f, -1e30f, -1e30f};
    float l_i[4] = {0.f, 0.f, 0.f, 0.f};
    f32x4 o_acc[4] = {};

    int vl = 0, kend;
    if (CAUSAL) kend = qt0 + 64;
    else { vl = valid_len[b]; kend = (vl + 63) & ~63; }

    for (int kv0 = 0; kv0 < kend; kv0 += 64) {
        __syncthreads();
        {
            const u16* kp = Kg + ((long)b * T_N + kv0 + sr) * kld + h * 64 + scc;
            *(s16x8*)&Ks[sr][scc]     = *(const s16x8*)kp;
            *(s16x8*)&Ks[sr][scc + 8] = *(const s16x8*)(kp + 8);
            const u16* vp = Vg + ((long)b * T_N + kv0 + sr) * vld + h * 64 + scc;
            s16x8 v0 = *(const s16x8*)vp;
            s16x8 v1 = *(const s16x8*)(vp + 8);
            #pragma unroll
            for (int j = 0; j < 8; j++) {
                Vt[scc + j][sr]     = (u16)v0[j];
                Vt[scc + 8 + j][sr] = (u16)v1[j];
            }
        }
        __syncthreads();
        f32x4 sc[4] = {};
        #pragma unroll
        for (int kk = 0; kk < 64; kk += 32) {
            s16x8 aq = *(const s16x8*)&Qs[wave*16 + l16][kk + quad*8];
            #pragma unroll
            for (int j = 0; j < 4; j++) {
                s16x8 bk = *(const s16x8*)&Ks[j*16 + l16][kk + quad*8];
                sc[j] = mfma16(aq, bk, sc[j]);
            }
        }
        const int qrow = qt0 + wave*16 + quad*4;
        #pragma unroll
        for (int j = 0; j < 4; j++) {
            int kcol = kv0 + j*16 + l16;
            #pragma unroll
            for (int r = 0; r < 4; r++) {
                float s = sc[j][r] * 0.125f;
                bool ok = CAUSAL ? (kcol <= qrow + r) : (kcol < vl);
                sc[j][r] = ok ? s : -1e30f;
            }
        }
        float alpha[4];
        #pragma unroll
        for (int r = 0; r < 4; r++) {
            float mx = fmaxf(fmaxf(sc[0][r], sc[1][r]), fmaxf(sc[2][r], sc[3][r]));
            #pragma unroll
            for (int d = 1; d < 16; d <<= 1) mx = fmaxf(mx, __shfl_xor(mx, d, 64));
            float mn = fmaxf(m_i[r], mx);
            alpha[r] = __expf(m_i[r] - mn);
            m_i[r] = mn;
        }
        float rsum[4] = {0.f, 0.f, 0.f, 0.f};
        #pragma unroll
        for (int j = 0; j < 4; j++)
            #pragma unroll
            for (int r = 0; r < 4; r++) {
                float pv = __expf(sc[j][r] - m_i[r]);
                sc[j][r] = pv;
                rsum[r] += pv;
            }
        #pragma unroll
        for (int r = 0; r < 4; r++) {
            #pragma unroll
            for (int d = 1; d < 16; d <<= 1) rsum[r] += __shfl_xor(rsum[r], d, 64);
            l_i[r] = l_i[r] * alpha[r] + rsum[r];
        }
        #pragma unroll
        for (int j = 0; j < 4; j++)
            #pragma unroll
            for (int r = 0; r < 4; r++)
                Ps[wave][quad*4 + r][j*16 + l16] = f2bf(sc[j][r]);
        #pragma unroll
        for (int j2 = 0; j2 < 4; j2++)
            #pragma unroll
            for (int r = 0; r < 4; r++)
                o_acc[j2][r] *= alpha[r];
        __syncthreads();
        #pragma unroll
        for (int kk = 0; kk < 64; kk += 32) {
            s16x8 ap = *(const s16x8*)&Ps[wave][l16][kk + quad*8];
            #pragma unroll
            for (int j2 = 0; j2 < 4; j2++) {
                s16x8 bv = *(const s16x8*)&Vt[j2*16 + l16][kk + quad*8];
                o_acc[j2] = mfma16(ap, bv, o_acc[j2]);
            }
        }
    }
    #pragma unroll
    for (int j2 = 0; j2 < 4; j2++) {
        #pragma unroll
        for (int r = 0; r < 4; r++) {
            float v = o_acc[j2][r] / l_i[r];
            long row = (long)b * T_N + qt0 + wave*16 + quad*4 + r;
            O[row * 1024 + h*64 + j2*16 + l16] = f2bf(v);
        }
    }
}

// ---------------------------------------------------------------- ssc[b,t,s] = qs.ks/32 (masked)
__global__ __launch_bounds__(256) void ssc_kernel(
    const u16* __restrict__ qs, const u16* __restrict__ ks,
    const int* __restrict__ svl, float* __restrict__ ssc, int qld)
{
    const int t = blockIdx.x, b = blockIdx.y;
    const int wave = threadIdx.x >> 6, lane = threadIdx.x & 63;
    const u16* qrow = qs + ((long)b * T_N + t) * qld + lane * 16;
    const int vl = svl[b];
    for (int s = wave; s < 16; s += 4) {
        const u16* krow = ks + ((long)b * 16 + s) * 1024 + lane * 16;
        float acc = 0.f;
        #pragma unroll
        for (int seg = 0; seg < 2; seg++) {
            s16x8 qv = *(const s16x8*)(qrow + seg*8);
            s16x8 kv = *(const s16x8*)(krow + seg*8);
            #pragma unroll
            for (int j = 0; j < 8; j++) acc += bf2f((u16)qv[j]) * bf2f((u16)kv[j]);
        }
        #pragma unroll
        for (int d = 1; d < 64; d <<= 1) acc += __shfl_xor(acc, d, 64);
        if (lane == 0)
            ssc[((long)b * T_N + t) * 16 + s] = (s < vl) ? acc * (1.f/32.f) : NEGV;
    }
}

// ---------------------------------------------------------------- top-8 stats, top-16 tokens, sparse combine
__global__ __launch_bounds__(256) void select_combine_kernel(
    const float* __restrict__ ssc, const float* __restrict__ tsc,
    const u16* __restrict__ vv, u16* __restrict__ out, int t0, int vld)
{
    const int tl = blockIdx.x, b = blockIdx.y;
    const int tg = t0 + tl;
    const int tid = threadIdx.x;
    const int wave = tid >> 6, lane = tid & 63;
    __shared__ float coeff[128];
    __shared__ long  rowoff[128];
    __shared__ int   sel_s[8];
    __shared__ float sel_w[8];

    if (wave == 0) {
        float cur = (lane < 16) ? ssc[((long)b * T_N + tg) * 16 + lane] : -3e38f;
        float mx0 = 0.f, ssum = 0.f, myv = -3e38f;
        int myi = 0;
        #pragma unroll
        for (int it = 0; it < 8; it++) {
            float mv = cur; int mi = lane;
            #pragma unroll
            for (int d = 1; d < 64; d <<= 1) {
                float ov = __shfl_xor(mv, d, 64);
                int   oi = __shfl_xor(mi, d, 64);
                if (ov > mv || (ov == mv && oi < mi)) { mv = ov; mi = oi; }
            }
            if (it == 0) mx0 = mv;
            ssum += __expf(mv - mx0);
            if (lane == it) { myv = mv; myi = mi; }
            if (lane == mi) cur = -3e38f;
        }
        if (lane < 8) { sel_s[lane] = myi; sel_w[lane] = __expf(myv - mx0) / ssum; }
    }
    __syncthreads();

    for (int slot = wave; slot < 8; slot += 4) {
        int s = sel_s[slot];
        float sw = sel_w[slot];
        const float* trow = tsc + (((long)b * 16 + s) * 512 + tl) * 256;
        float4 lv4 = *(const float4*)(trow + lane * 4);
        float loc[4] = { lv4.x, lv4.y, lv4.z, lv4.w };
        float mx0 = 0.f, tsum = 0.f, myv = -3e38f;
        int myi = 0;
        for (int it = 0; it < 16; it++) {
            float mv = -3e38f; int mi = 0;
            #pragma unroll
            for (int u = 0; u < 4; u++)
                if (loc[u] > mv) { mv = loc[u]; mi = lane*4 + u; }
            #pragma unroll
            for (int d = 1; d < 64; d <<= 1) {
                float ov = __shfl_xor(mv, d, 64);
                int   oi = __shfl_xor(mi, d, 64);
                if (ov > mv || (ov == mv && oi < mi)) { mv = ov; mi = oi; }
            }
            if (it == 0) mx0 = mv * (1.f/32.f);
            tsum += __expf(mv * (1.f/32.f) - mx0);
            if (lane == it) { myv = mv; myi = mi; }
            if ((mi >> 2) == lane) {
                int u = mi & 3;
                if (u == 0) loc[0] = -3e38f;
                else if (u == 1) loc[1] = -3e38f;
                else if (u == 2) loc[2] = -3e38f;
                else loc[3] = -3e38f;
            }
        }
        if (lane < 16) {
            coeff[slot * 16 + lane]  = sw * __expf(myv * (1.f/32.f) - mx0) / tsum;
            rowoff[slot * 16 + lane] = (long)((b * 16 + s) * 256 + myi) * vld;
        }
    }
    __syncthreads();

    const int d0 = tid * 4;
    float a0 = 0.f, a1 = 0.f, a2 = 0.f, a3 = 0.f;
    for (int r = 0; r < 128; r++) {
        float c = coeff[r];
        const u16* vp = vv + rowoff[r] + d0;
        u16x4 v4 = *(const u16x4*)vp;
        a0 += c * bf2f(v4[0]);
        a1 += c * bf2f(v4[1]);
        a2 += c * bf2f(v4[2]);
        a3 += c * bf2f(v4[3]);
    }
    u16x4 o4 = { f2bf(a0), f2bf(a1), f2bf(a2), f2bf(a3) };
    *(u16x4*)(out + ((long)b * T_N + tg) * 1024 + d0) = o4;
}

// ---------------------------------------------------------------- LN kernels
__device__ __forceinline__ float block_sum(float v, float* red) {
    #pragma unroll
    for (int d = 1; d < 64; d <<= 1) v += __shfl_xor(v, d, 64);
    __syncthreads();
    if ((threadIdx.x & 63) == 0) red[threadIdx.x >> 6] = v;
    __syncthreads();
    return red[0] + red[1] + red[2] + red[3];
}

__global__ __launch_bounds__(256) void ln1_kernel(
    const float* __restrict__ x, const float* __restrict__ x2,
    const float* __restrict__ intent, const float* __restrict__ g, const float* __restrict__ be,
    u16* __restrict__ yi)
{
    __shared__ float red[4];
    const long row = blockIdx.x;
    const int tid = threadIdx.x;
    const long base = row * 1024 + tid * 4;
    float4 xv = *(const float4*)(x + base);
    float4 dv = *(const float4*)(x2 + base);
    float h0 = xv.x + dv.x, h1 = xv.y + dv.y, h2 = xv.z + dv.z, h3 = xv.w + dv.w;
    float s1 = block_sum(h0 + h1 + h2 + h3, red);
    float s2 = block_sum(h0*h0 + h1*h1 + h2*h2 + h3*h3, red);
    float mean = s1 * (1.f/1024.f);
    float var = s2 * (1.f/1024.f) - mean * mean;
    float inv = rsqrtf(var + 1e-5f);
    const int c = tid * 4;
    float4 gv = *(const float4*)(g + c);
    float4 bv = *(const float4*)(be + c);
    float o0 = (h0 - mean) * inv * gv.x + bv.x;
    float o1 = (h1 - mean) * inv * gv.y + bv.y;
    float o2 = (h2 - mean) * inv * gv.z + bv.z;
    float o3 = (h3 - mean) * inv * gv.w + bv.w;
    u16x4 ob = { f2bf(o0), f2bf(o1), f2bf(o2), f2bf(o3) };
    *(u16x4*)(yi + row * 1280 + c) = ob;
    const int b = (int)(row >> 10);
    yi[row * 1280 + 1024 + tid] = f2bf(intent[b * 256 + tid]);
}

__global__ __launch_bounds__(256) void gate_ln2_kernel(
    const u16* __restrict__ yi, const float* __restrict__ y2s, const float* __restrict__ y2e,
    const float* __restrict__ Wg, const float* __restrict__ g, const float* __restrict__ be,
    float* __restrict__ z, u16* __restrict__ zbf)
{
    __shared__ float red[4];
    const long row = blockIdx.x;
    const int tid = threadIdx.x;
    const long base = row * 1024 + tid * 4;
    const int c = tid * 4;
    float4 sv = *(const float4*)(y2s + base);
    float4 ev = *(const float4*)(y2e + base);
    float4 w1 = *(const float4*)(Wg + c);
    float4 w2 = *(const float4*)(Wg + 1024 + c);
    float dot = sv.x*w1.x + sv.y*w1.y + sv.z*w1.z + sv.w*w1.w
              + ev.x*w2.x + ev.y*w2.y + ev.z*w2.z + ev.w*w2.w;
    float tot = block_sum(dot, red);
    float gate = 1.f / (1.f + __expf(-tot));
    u16x4 yv4 = *(const u16x4*)(yi + row * 1280 + c);
    float h0 = bf2f(yv4[0]) + 2.f * (gate * sv.x + (1.f - gate) * ev.x);
    float h1 = bf2f(yv4[1]) + 2.f * (gate * sv.y + (1.f - gate) * ev.y);
    float h2 = bf2f(yv4[2]) + 2.f * (gate * sv.z + (1.f - gate) * ev.z);
    float h3 = bf2f(yv4[3]) + 2.f * (gate * sv.w + (1.f - gate) * ev.w);
    float s1 = block_sum(h0 + h1 + h2 + h3, red);
    float s2 = block_sum(h0*h0 + h1*h1 + h2*h2 + h3*h3, red);
    float mean = s1 * (1.f/1024.f);
    float var = s2 * (1.f/1024.f) - mean * mean;
    float inv = rsqrtf(var + 1e-5f);
    float4 gv = *(const float4*)(g + c);
    float4 bv = *(const float4*)(be + c);
    float o0 = (h0 - mean) * inv * gv.x + bv.x;
    float o1 = (h1 - mean) * inv * gv.y + bv.y;
    float o2 = (h2 - mean) * inv * gv.z + bv.z;
    float o3 = (h3 - mean) * inv * gv.w + bv.w;
    *(float4*)(z + base) = make_float4(o0, o1, o2, o3);
    u16x4 ob = { f2bf(o0), f2bf(o1), f2bf(o2), f2bf(o3) };
    *(u16x4*)(zbf + row * 1024 + c) = ob;
}

// final LN over z + (p0 + p1 + b2)  — FFN2 split-K partials fused here
__global__ __launch_bounds__(256) void ln3_kernel(
    const float* __restrict__ z, const float* __restrict__ p0, const float* __restrict__ p1,
    const float* __restrict__ b2,
    const float* __restrict__ g, const float* __restrict__ be, float* __restrict__ out)
{
    __shared__ float red[4];
    const long row = blockIdx.x;
    const int tid = threadIdx.x;
    const long base = row * 1024 + tid * 4;
    const int c = tid * 4;
    float4 zv = *(const float4*)(z + base);
    float4 f0 = *(const float4*)(p0 + base);
    float4 f1 = *(const float4*)(p1 + base);
    float4 bb = *(const float4*)(b2 + c);
    float h0 = zv.x + f0.x + f1.x + bb.x;
    float h1 = zv.y + f0.y + f1.y + bb.y;
    float h2 = zv.z + f0.z + f1.z + bb.z;
    float h3 = zv.w + f0.w + f1.w + bb.w;
    float s1 = block_sum(h0 + h1 + h2 + h3, red);
    float s2 = block_sum(h0*h0 + h1*h1 + h2*h2 + h3*h3, red);
    float mean = s1 * (1.f/1024.f);
    float var = s2 * (1.f/1024.f) - mean * mean;
    float inv = rsqrtf(var + 1e-5f);
    float4 gv = *(const float4*)(g + c);
    float4 bv = *(const float4*)(be + c);
    float o0 = (h0 - mean) * inv * gv.x + bv.x;
    float o1 = (h1 - mean) * inv * gv.y + bv.y;
    float o2 = (h2 - mean) * inv * gv.z + bv.z;
    float o3 = (h3 - mean) * inv * gv.w + bv.w;
    *(float4*)(out + base) = make_float4(o0, o1, o2, o3);
}

// ---------------------------------------------------------------- host
extern "C" void kernel_launch(void* const* d_in, const int* in_sizes, int n_in,
                              void* d_out, int out_size, void* d_ws, size_t ws_size,
                              hipStream_t stream)
{
    (void)in_sizes; (void)n_in; (void)out_size; (void)ws_size;
    const float* x      = (const float*)d_in[0];
    const float* stat_e = (const float*)d_in[1];
    const float* exem   = (const float*)d_in[2];
    const float* sfeat  = (const float*)d_in[3];
    const float* intent = (const float*)d_in[4];
    const float* Wg  = (const float*)d_in[19];
    const float* b1  = (const float*)d_in[21];
    const float* b2  = (const float*)d_in[23];
    const float* g1  = (const float*)d_in[24]; const float* be1 = (const float*)d_in[25];
    const float* g2  = (const float*)d_in[26]; const float* be2 = (const float*)d_in[27];
    const float* g3  = (const float*)d_in[28]; const float* be3 = (const float*)d_in[29];
    const int* svl = (const int*)d_in[30];
    const int* evl = (const int*)d_in[31];
    float* outp = (float*)d_out;

    // ---- workspace plan: 171 MB, lifetime-aliased ----
    char* base = (char*)d_ws;
    u16*  bufA  = (u16*)(base + 0*MB);        // 8MB: xbf / attn-outs / y2s_pre
    u16*  qkv1  = (u16*)(base + 8*MB);        // 24MB fused [4096,3072] (phase 3)
    float* x2a  = (float*)(base + 8*MB);      // 16MB (after flash1)
    u16*  kv2   = (u16*)(base + 8*MB);        // 16MB fused [4096,2048] (phase 5)
    u16*  w1t   = (u16*)(base + 8*MB);        // 8MB (phase 7)
    u16*  w2t   = (u16*)(base + 16*MB);       // 8MB (phase 7)
    u16*  yibf  = (u16*)(base + 32*MB);       // 10MB [4096,1280]
    u16*  buf3  = (u16*)(base + 42*MB);       // 24MB fused qs|qt|q2 [4096,3072]
    u16*  zbf   = (u16*)(base + 42*MB);       // 8MB (after flash2)
    u16*  sebf  = (u16*)(base + 66*MB);       // 32MB stat_enc bf16 / tsc-half fp32 / ffn hidden
    float* tsch = (float*)(base + 66*MB);
    u16*  hid   = (u16*)(base + 66*MB);
    u16*  ktvv  = (u16*)(base + 98*MB);       // 64MB fused [16384,2048]
    float* y2sf = (float*)(base + 98*MB);     // 16MB (after select)
    float* p0f  = (float*)(base + 98*MB);     // 32MB FFN2 partials (after gate_ln2; y2ef dead)
    u16*  exbf  = (u16*)(base + 114*MB);      // 8MB
    float* y2ef = (float*)(base + 122*MB);    // 16MB
    float* zf   = (float*)(base + 138*MB);    // 16MB
    u16*  sfbf  = (u16*)(base + 162*MB);                  // 128KB
    u16*  ksbf  = (u16*)(base + 162*MB + 256*1024);       // 128KB
    float* sscf = (float*)(base + 162*MB + 512*1024);     // 256KB
    char* wpool = base + 163*MB;              // 8MB rotating weight pool (total 171MB)

    dim3 blk(256);
    dim3 blk512(512);
    auto cast = [&](const float* s, u16* d, long n) {
        cast_bf16_kernel<<<dim3((unsigned)((n/4 + 255) / 256)), blk, 0, stream>>>(s, d, n);
    };
    auto g_n = [&](const u16* A, const u16* Bt, u16* C, int M, int N, int K,
                   int lda, int ldb, int ldc) {
        gemm_bt<u16,false,false><<<dim3(N/128, (M+127)/128, 1), blk, 0, stream>>>(
            A, Bt, C, nullptr, M, N, K, lda, ldb, ldc, 1, 0, 0, 0);
    };
    auto g_f = [&](const u16* A, const u16* Bt, float* C, int M, int N, int K,
                   int lda, int ldb, int ldc) {
        gemm_bt<float,false,false><<<dim3(N/128, (M+127)/128, 1), blk, 0, stream>>>(
            A, Bt, C, nullptr, M, N, K, lda, ldb, ldc, 1, 0, 0, 0);
    };
    // 256^2 deep-pipelined GEMM — M,N multiples of 256 only
    auto g256_n = [&](const u16* A, const u16* Bt, u16* C, int M, int N, int K,
                      int lda, int ldb, int ldc) {
        gemm_bt256<u16,false,false><<<dim3(N/256, M/256, 1), blk512, 0, stream>>>(
            A, Bt, C, nullptr, M, N, K, lda, ldb, ldc, 1, 0, 0, 0);
    };

    // ---- phase 3: self-attention ----
    u16* wqkv1t = (u16*)wpool;                       // [3072,1024] stacked
    u16* wo1t   = (u16*)(wpool) + 3L*1024*1024;
    {
        P6 pp{};
        pp.s[0]=(const float*)d_in[5]; pp.d[0]=wqkv1t;
        pp.s[1]=(const float*)d_in[6]; pp.d[1]=wqkv1t + 1L*1024*1024;
        pp.s[2]=(const float*)d_in[7]; pp.d[2]=wqkv1t + 2L*1024*1024;
        pp.s[3]=(const float*)d_in[8]; pp.d[3]=wo1t;
        transpose_cast_batch<<<dim3(32, 32, 4), blk, 0, stream>>>(pp, 1024, 1024);
    }
    cast(x, bufA, 4096L*1024);
    g256_n(bufA, wqkv1t, qkv1, 4096, 3072, 1024, 1024, 1024, 3072);
    flash_attn_kernel<true><<<dim3(16, 16, 4), blk, 0, stream>>>(
        qkv1, qkv1 + 1024, qkv1 + 2048, nullptr, bufA, 3072, 3072, 3072);
    g_f(bufA, wo1t, x2a, 4096, 1024, 1024, 1024, 1024, 1024);
    ln1_kernel<<<dim3(4096), blk, 0, stream>>>(x, x2a, intent, g1, be1, yibf);

    // ---- phase 4: selective hierarchical attention ----
    u16* wq3t = (u16*)wpool;
    {
        P6 pp{};
        pp.s[0]=(const float*)d_in[9];  pp.d[0]=wq3t;
        pp.s[1]=(const float*)d_in[10]; pp.d[1]=wq3t + 1L*1024*1280;
        pp.s[2]=(const float*)d_in[15]; pp.d[2]=wq3t + 2L*1024*1280;
        transpose_cast_batch<<<dim3(32, 40, 3), blk, 0, stream>>>(pp, 1280, 1024);
    }
    g256_n(yibf, wq3t, buf3, 4096, 3072, 1280, 1280, 1280, 3072);   // qs|qt|q2
    u16* wkst = (u16*)wpool;
    u16* wkv  = (u16*)(wpool) + 1L*1024*1024;
    {
        P6 pp{};
        pp.s[0]=(const float*)d_in[11]; pp.d[0]=wkst;
        pp.s[1]=(const float*)d_in[12]; pp.d[1]=wkv;
        pp.s[2]=(const float*)d_in[13]; pp.d[2]=wkv + 1L*1024*1024;
        transpose_cast_batch<<<dim3(32, 32, 3), blk, 0, stream>>>(pp, 1024, 1024);
    }
    cast(sfeat, sfbf, 64L*1024);
    cast(stat_e, sebf, 16384L*1024);
    g_n(sfbf, wkst, ksbf, 64, 1024, 1024, 1024, 1024, 1024);
    g256_n(sebf, wkv, ktvv, 16384, 2048, 1024, 1024, 1024, 2048);   // kt|vv
    ssc_kernel<<<dim3(1024, 4), blk, 0, stream>>>(buf3, ksbf, svl, sscf, 3072);
    for (int hh = 0; hh < 2; hh++) {
        long t0 = hh * 512;
        gemm_bt256<float,false,false><<<dim3(1, 2, 64), blk512, 0, stream>>>(
            buf3 + 1024 + t0*3072, ktvv, tsch, nullptr, 512, 256, 1024,
            3072, 2048, 256, 16, (long)T_N*3072, 256L*2048, 512L*256);
        select_combine_kernel<<<dim3(512, 4), blk, 0, stream>>>(
            sscf, tsch, ktvv + 1024, bufA, (int)t0, 2048);
    }
    u16* wost = (u16*)wpool;
    u16* wkv2 = (u16*)(wpool) + 1L*1024*1024;
    u16* wo2t = (u16*)(wpool) + 3L*1024*1024;
    {
        P6 pp{};
        pp.s[0]=(const float*)d_in[14]; pp.d[0]=wost;
        pp.s[1]=(const float*)d_in[16]; pp.d[1]=wkv2;
        pp.s[2]=(const float*)d_in[17]; pp.d[2]=wkv2 + 1L*1024*1024;
        pp.s[3]=(const float*)d_in[18]; pp.d[3]=wo2t;
        transpose_cast_batch<<<dim3(32, 32, 4), blk, 0, stream>>>(pp, 1024, 1024);
    }
    g_f(bufA, wost, y2sf, 4096, 1024, 1024, 1024, 1024, 1024);

    // ---- phase 5: exemplar cross-attention ----
    cast(exem, exbf, 4096L*1024);
    g256_n(exbf, wkv2, kv2, 4096, 2048, 1024, 1024, 1024, 2048);    // k2|v2
    flash_attn_kernel<false><<<dim3(16, 16, 4), blk, 0, stream>>>(
        buf3 + 2048, kv2, kv2 + 1024, evl, bufA, 3072, 2048, 2048);
    g_f(bufA, wo2t, y2ef, 4096, 1024, 1024, 1024, 1024, 1024);

    // ---- phase 6: gate + LN2 ----
    gate_ln2_kernel<<<dim3(4096), blk, 0, stream>>>(yibf, y2sf, y2ef, Wg, g2, be2, zf, zbf);

    // ---- phase 7: FFN ----
    {
        P6 pp{}; pp.s[0] = (const float*)d_in[20]; pp.d[0] = w1t;
        transpose_cast_batch<<<dim3(128, 32, 1), blk, 0, stream>>>(pp, 1024, 4096);
    }
    {
        P6 pp{}; pp.s[0] = (const float*)d_in[22]; pp.d[0] = w2t;
        transpose_cast_batch<<<dim3(32, 128, 1), blk, 0, stream>>>(pp, 4096, 1024);
    }
    gemm_bt256<u16,true,true><<<dim3(16, 16, 1), blk512, 0, stream>>>(
        zbf, w1t, hid, b1, 4096, 4096, 1024, 1024, 1024, 4096, 1, 0, 0, 0);
    // FFN2 split-K x2 in one dispatch (z picks K-half): p[z] = hid[:,z*2048:] @ w2t[:,z*2048:]^T
    gemm_bt256<float,false,false><<<dim3(4, 16, 2), blk512, 0, stream>>>(
        hid, w2t, p0f, nullptr, 4096, 1024, 2048, 4096, 4096, 1024,
        1, 2048, 2048, 4096L*1024);

    // ---- phase 8: final LN (fuses p0+p1+b2) ----
    ln3_kernel<<<dim3(4096), blk, 0, stream>>>(zf, p0f, p0f + 4096L*1024, b2, g3, be3, outp);
}

// Round 2
// 1018.170 us; speedup vs baseline: 1.0404x; 1.0404x over previous
//
#include <hip/hip_runtime.h>

typedef unsigned short u16;
typedef short s16x8 __attribute__((ext_vector_type(8)));
typedef u16 u16x4 __attribute__((ext_vector_type(4)));
typedef float f32x4 __attribute__((ext_vector_type(4)));

#define T_N   1024
#define NEGV  -1e6f
#define MB    (1L << 20)

__device__ __forceinline__ u16 f2bf(float f) {
    unsigned u = __float_as_uint(f);
    u += 0x7fffu + ((u >> 16) & 1u);     // RNE
    return (u16)(u >> 16);
}
__device__ __forceinline__ float bf2f(u16 h) {
    return __uint_as_float(((unsigned)h) << 16);
}
__device__ __forceinline__ f32x4 mfma16(s16x8 a, s16x8 b, f32x4 c) {
    return __builtin_amdgcn_mfma_f32_16x16x32_bf16(a, b, c, 0, 0, 0);
}
// async global->LDS, 16B per lane; LDS dest = wave-uniform base + lane*16 (m97/m104)
__device__ __forceinline__ void gll16(const u16* g, u16* l) {
    __builtin_amdgcn_global_load_lds((const __attribute__((address_space(1))) void*)g,
                                     (__attribute__((address_space(3))) void*)l, 16, 0, 0);
}

// ---------------------------------------------------------------- transpose+cast
struct P6 { const float* s[6]; u16* d[6]; };

__global__ __launch_bounds__(256) void transpose_cast_batch(P6 pp, int K, int N) {
    const float* __restrict__ src = pp.s[blockIdx.z];
    u16* __restrict__ dst = pp.d[blockIdx.z];
    __shared__ float tile[32][33];
    int nb = blockIdx.x * 32, kb = blockIdx.y * 32;
    int tx = threadIdx.x & 31, ty = threadIdx.x >> 5;   // ty 0..7
    #pragma unroll
    for (int i = 0; i < 4; i++)
        tile[ty + 8*i][tx] = src[(long)(kb + ty + 8*i) * N + nb + tx];
    __syncthreads();
    #pragma unroll
    for (int i = 0; i < 4; i++)
        dst[(long)(nb + ty + 8*i) * K + kb + tx] = f2bf(tile[tx][ty + 8*i]);
}

__global__ __launch_bounds__(256) void cast_bf16_kernel(const float* __restrict__ src,
                                                        u16* __restrict__ dst, long n) {
    long i = ((long)blockIdx.x * 256 + threadIdx.x) * 4;
    if (i >= n) return;
    float4 v = *(const float4*)(src + i);
    u16x4 o = { f2bf(v.x), f2bf(v.y), f2bf(v.z), f2bf(v.w) };
    *(u16x4*)(dst + i) = o;
}

// ---------------------------------------------------------------- GEMM: C[M,N] = A[M,K] * Bt[N,K]^T
// 128x128-tile fallback kernel (m97 structure) — used for shapes whose 256^2
// grid would under-fill 256 CUs (small-M, N=1024 Wo projections, batched tsc,
// FFN2 split-K). T2 swizzle is NULL on this 2-phase structure (m228d/m230).
template<typename OutT, bool RELU, bool HAS_BIAS>
__global__ __launch_bounds__(256) void gemm_bt(
    const u16* __restrict__ A, const u16* __restrict__ Bt, OutT* __restrict__ C,
    const float* __restrict__ bias, int M, int N, int K,
    int lda, int ldb, int ldc,
    int batchDivA, long sA, long sB, long sC)
{
    A  += (long)(blockIdx.z / batchDivA) * sA;
    Bt += (long)blockIdx.z * sB;
    C  += (long)blockIdx.z * sC;
    __shared__ __align__(16) u16 As[4096];   // [128][32] row-major, 8 KB
    __shared__ __align__(16) u16 Bs[4096];
    const int tid = threadIdx.x;
    const int wave = tid >> 6, lane = tid & 63;
    const int quad = lane >> 4, l16 = lane & 15;
    const int wr = (wave >> 1) * 64, wc = (wave & 1) * 64;
    const long row0 = (long)blockIdx.y * 128, col0 = (long)blockIdx.x * 128;

    f32x4 acc[4][4] = {};

    const int l4r = lane >> 2;
    const int l4c = (lane & 3) * 8;
    const int ra = wave * 32 + l4r;
    const u16* Ap0 = A + (row0 + ra) * (long)lda + l4c;
    const u16* Ap1 = Ap0 + 16L * lda;
    const u16* Bp0 = Bt + (col0 + ra) * (long)ldb + l4c;
    const u16* Bp1 = Bp0 + 16L * ldb;
    u16* AsW0 = &As[(wave * 32) * 32];
    u16* AsW1 = &As[(wave * 32 + 16) * 32];
    u16* BsW0 = &Bs[(wave * 32) * 32];
    u16* BsW1 = &Bs[(wave * 32 + 16) * 32];
    const bool aok0 = (row0 + wave * 32) < M;
    const bool aok1 = (row0 + wave * 32 + 16) < M;

    for (int k0 = 0; k0 < K; k0 += 32) {
        __syncthreads();
        if (aok0) gll16(Ap0 + k0, AsW0);
        if (aok1) gll16(Ap1 + k0, AsW1);
        gll16(Bp0 + k0, BsW0);
        gll16(Bp1 + k0, BsW1);
        __syncthreads();
        s16x8 af[4], bfr[4];
        #pragma unroll
        for (int i = 0; i < 4; i++)
            af[i]  = *(const s16x8*)&As[(wr + i*16 + l16) * 32 + quad*8];
        #pragma unroll
        for (int j = 0; j < 4; j++)
            bfr[j] = *(const s16x8*)&Bs[(wc + j*16 + l16) * 32 + quad*8];
        #pragma unroll
        for (int i = 0; i < 4; i++)
            #pragma unroll
            for (int j = 0; j < 4; j++)
                acc[i][j] = mfma16(af[i], bfr[j], acc[i][j]);
    }

    #pragma unroll
    for (int i = 0; i < 4; i++) {
        long row = row0 + wr + i*16 + quad*4;
        #pragma unroll
        for (int j = 0; j < 4; j++) {
            long col = col0 + wc + j*16 + l16;
            float bv = 0.f;
            if constexpr (HAS_BIAS) bv = bias[col];
            #pragma unroll
            for (int r = 0; r < 4; r++) {
                if (row + r < M) {
                    float v = acc[i][j][r] + bv;
                    if constexpr (RELU) v = fmaxf(v, 0.f);
                    if constexpr (sizeof(OutT) == 2) C[(row + r) * (long)ldc + col] = f2bf(v);
                    else                             C[(row + r) * (long)ldc + col] = v;
                }
            }
        }
    }
}

// ---------------------------------------------------------------- GEMM 256^2, deep pipeline
// 256x256 tile, BK=32, 8 waves (2Mx4N), per-wave 128x64 output.
// 4-deep LDS ring buffer: 4 x (A[256][32] + B[256][32]) bf16 = 128 KiB total.
// T3+T4+T5 schedule: per K-slice, 2 phases of
//   {ds_read frag subtile ; issue 2 global_load_lds for slice kt+3} -> s_barrier
//   -> lgkmcnt(0) -> setprio(1) + 16 MFMA + setprio(0) -> s_barrier
// ONE counted s_waitcnt vmcnt(8) per K-slice (2 future slices stay in flight
// across barriers; never drained to 0 in the hot loop). Epilogue 8->4->0.
//
// T2 XOR chunk-swizzle (NEW): [256][32] rows are 64B, so un-swizzled frag reads
// (16 lanes, same quad, rows r..r+15) hit only two 4-bank groups = 8-way
// conflict (measured 6.3M SQ_LDS_BANK_CONFLICT/dispatch). Read slot =
// quad ^ ((row>>1)&3): rows 0..7 per quad cover all 8 groups, rows 8..15 repeat
// -> exactly 2-way (free, m136). global_load_lds writes stay LINEAR; the SAME
// involution is applied to the global SOURCE chunk (rule #21: linear dest +
// inverse-swz source + swz read). XOR field depends only on row bits 1..2 =
// l16 bits 1..2 on the read side (frag bases are x16) and is invariant under
// the +128-row stage offset, so it is a per-lane constant.
// Requires: M%256==0, N%256==0, K%32==0, K>=128.
template<typename OutT, bool RELU, bool HAS_BIAS>
__global__ __launch_bounds__(512, 2) void gemm_bt256(
    const u16* __restrict__ A, const u16* __restrict__ Bt, OutT* __restrict__ C,
    const float* __restrict__ bias, int M, int N, int K,
    int lda, int ldb, int ldc,
    int batchDivA, long sA, long sB, long sC)
{
    A  += (long)(blockIdx.z / batchDivA) * sA;
    Bt += (long)blockIdx.z * sB;
    C  += (long)blockIdx.z * sC;
    __shared__ __align__(16) u16 As[4][8192];   // [256][32] each, 16 KB x4
    __shared__ __align__(16) u16 Bs[4][8192];
    const int tid = threadIdx.x;
    const int wave = tid >> 6, lane = tid & 63;
    const int quad = lane >> 4, l16 = lane & 15;
    const int wm = wave >> 2, wn = wave & 3;           // 2 x 4 wave grid
    const long row0 = (long)blockIdx.y * 256, col0 = (long)blockIdx.x * 256;

    // staging: thread t covers row (t>>2); SOURCE chunk is XOR-swizzled so the
    // linear DMA write leaves LDS(r,s) = global chunk (r, s ^ ((r>>1)&3)).
    const int srow = tid >> 2;
    const int scol = ((tid & 3) ^ ((srow >> 1) & 3)) * 8;
    const u16* Ag = A  + (row0 + srow) * (long)lda + scol;
    const u16* Bg = Bt + (col0 + srow) * (long)ldb + scol;
    const int ldsoff = wave * 512;                      // wave-uniform elem offset

    f32x4 acc[8][4] = {};
    const int NT = K >> 5;

    auto stageA = [&](int kt, int buf) {
        gll16(Ag + (long)kt * 32,            &As[buf][ldsoff]);
        gll16(Ag + (long)kt * 32 + 128L*lda, &As[buf][4096 + ldsoff]);
    };
    auto stageB = [&](int kt, int buf) {
        gll16(Bg + (long)kt * 32,            &Bs[buf][ldsoff]);
        gll16(Bg + (long)kt * 32 + 128L*ldb, &Bs[buf][4096 + ldsoff]);
    };

    // prologue: slices 0,1,2 staged (12 loads/wave); wait until slice 0 landed
    stageA(0, 0); stageB(0, 0);
    stageA(1, 1); stageB(1, 1);
    stageA(2, 2); stageB(2, 2);
    asm volatile("s_waitcnt vmcnt(8)" ::: "memory");
    __builtin_amdgcn_s_barrier();

    const int arow = wm * 128 + l16;
    const int brow = wn * 64  + l16;
    const int kq   = (quad ^ ((l16 >> 1) & 3)) * 8;     // swizzled chunk offset

    for (int kt = 0; kt < NT; ++kt) {
        const int b  = kt & 3;
        const int sb = (kt + 3) & 3;
        const bool st = (kt + 3) < NT;
        const u16* Ab = As[b];
        const u16* Bb = Bs[b];

        // ---- phase A: frags {B all j, A i=0..3}; stage A(kt+3) ----
        s16x8 bfr[4], af[4];
        #pragma unroll
        for (int j = 0; j < 4; ++j)
            bfr[j] = *(const s16x8*)&Bb[(brow + j*16) * 32 + kq];
        #pragma unroll
        for (int i = 0; i < 4; ++i)
            af[i] = *(const s16x8*)&Ab[(arow + i*16) * 32 + kq];
        if (st) stageA(kt + 3, sb);
        __builtin_amdgcn_s_barrier();
        asm volatile("s_waitcnt lgkmcnt(0)" ::: "memory");
        __builtin_amdgcn_sched_barrier(0);
        __builtin_amdgcn_s_setprio(1);
        #pragma unroll
        for (int i = 0; i < 4; ++i)
            #pragma unroll
            for (int j = 0; j < 4; ++j)
                acc[i][j] = mfma16(af[i], bfr[j], acc[i][j]);
        __builtin_amdgcn_s_setprio(0);
        __builtin_amdgcn_s_barrier();

        // ---- phase B: frags {A i=4..7}; stage B(kt+3) ----
        #pragma unroll
        for (int i = 0; i < 4; ++i)
            af[i] = *(const s16x8*)&Ab[(arow + (i + 4)*16) * 32 + kq];
        if (st) stageB(kt + 3, sb);
        __builtin_amdgcn_s_barrier();
        asm volatile("s_waitcnt lgkmcnt(0)" ::: "memory");
        __builtin_amdgcn_sched_barrier(0);
        __builtin_amdgcn_s_setprio(1);
        #pragma unroll
        for (int i = 0; i < 4; ++i)
            #pragma unroll
            for (int j = 0; j < 4; ++j)
                acc[i + 4][j] = mfma16(af[i], bfr[j], acc[i + 4][j]);
        __builtin_amdgcn_s_setprio(0);

        // counted wait: keep up to 2 future slices (8 loads) in flight
        const int rem = NT - 2 - kt;
        if (rem >= 2)      asm volatile("s_waitcnt vmcnt(8)" ::: "memory");
        else if (rem == 1) asm volatile("s_waitcnt vmcnt(4)" ::: "memory");
        else if (rem == 0) asm volatile("s_waitcnt vmcnt(0)" ::: "memory");
        __builtin_amdgcn_s_barrier();
    }

    #pragma unroll
    for (int i = 0; i < 8; ++i) {
        const long row = row0 + wm*128 + i*16 + quad*4;
        #pragma unroll
        for (int j = 0; j < 4; ++j) {
            const long col = col0 + wn*64 + j*16 + l16;
            float bv = 0.f;
            if constexpr (HAS_BIAS) bv = bias[col];
            #pragma unroll
            for (int r = 0; r < 4; ++r) {
                float v = acc[i][j][r] + bv;
                if constexpr (RELU) v = fmaxf(v, 0.f);
                if constexpr (sizeof(OutT) == 2) C[(row + r) * (long)ldc + col] = f2bf(v);
                else                             C[(row + r) * (long)ldc + col] = v;
            }
        }
    }
}

// ---------------------------------------------------------------- flash attention (dh=64, H=16)
template<bool CAUSAL>
__global__ __launch_bounds__(256) void flash_attn_kernel(
    const u16* __restrict__ Q, const u16* __restrict__ Kg, const u16* __restrict__ Vg,
    const int* __restrict__ valid_len, u16* __restrict__ O,
    int qld, int kld, int vld)
{
    const int h = blockIdx.y, b = blockIdx.z;
    const int qt0 = blockIdx.x * 64;
    const int tid = threadIdx.x;
    const int wave = tid >> 6, lane = tid & 63;
    const int quad = lane >> 4, l16 = lane & 15;

    __shared__ __align__(16) u16 Qs[64][72];
    __shared__ __align__(16) u16 Ks[64][72];
    __shared__ __align__(16) u16 Vt[64][72];
    __shared__ __align__(16) u16 Ps[4][16][72];

    const int sr = tid >> 2, scc = (tid & 3) * 16;
    {
        const u16* qp = Q + ((long)b * T_N + qt0 + sr) * qld + h * 64 + scc;
        *(s16x8*)&Qs[sr][scc]     = *(const s16x8*)qp;
        *(s16x8*)&Qs[sr][scc + 8] = *(const s16x8*)(qp + 8);
    }
    float m_i[4] = {-1e30f, -1e30f, -1e30f, -1e30f};
    float l_i[4] = {0.f, 0.f, 0.f, 0.f};
    f32x4 o_acc[4] = {};

    int vl = 0, kend;
    if (CAUSAL) kend = qt0 + 64;
    else { vl = valid_len[b]; kend = (vl + 63) & ~63; }

    for (int kv0 = 0; kv0 < kend; kv0 += 64) {
        __syncthreads();
        {
            const u16* kp = Kg + ((long)b * T_N + kv0 + sr) * kld + h * 64 + scc;
            *(s16x8*)&Ks[sr][scc]     = *(const s16x8*)kp;
            *(s16x8*)&Ks[sr][scc + 8] = *(const s16x8*)(kp + 8);
            const u16* vp = Vg + ((long)b * T_N + kv0 + sr) * vld + h * 64 + scc;
            s16x8 v0 = *(const s16x8*)vp;
            s16x8 v1 = *(const s16x8*)(vp + 8);
            #pragma unroll
            for (int j = 0; j < 8; j++) {
                Vt[scc + j][sr]     = (u16)v0[j];
                Vt[scc + 8 + j][sr] = (u16)v1[j];
            }
        }
        __syncthreads();
        f32x4 sc[4] = {};
        #pragma unroll
        for (int kk = 0; kk < 64; kk += 32) {
            s16x8 aq = *(const s16x8*)&Qs[wave*16 + l16][kk + quad*8];
            #pragma unroll
            for (int j = 0; j < 4; j++) {
                s16x8 bk = *(const s16x8*)&Ks[j*16 + l16][kk + quad*8];
                sc[j] = mfma16(aq, bk, sc[j]);
            }
        }
        const int qrow = qt0 + wave*16 + quad*4;
        #pragma unroll
        for (int j = 0; j < 4; j++) {
            int kcol = kv0 + j*16 + l16;
            #pragma unroll
            for (int r = 0; r < 4; r++) {
                float s = sc[j][r] * 0.125f;
                bool ok = CAUSAL ? (kcol <= qrow + r) : (kcol < vl);
                sc[j][r] = ok ? s : -1e30f;
            }
        }
        float alpha[4];
        #pragma unroll
        for (int r = 0; r < 4; r++) {
            float mx = fmaxf(fmaxf(sc[0][r], sc[1][r]), fmaxf(sc[2][r], sc[3][r]));
            #pragma unroll
            for (int d = 1; d < 16; d <<= 1) mx = fmaxf(mx, __shfl_xor(mx, d, 64));
            float mn = fmaxf(m_i[r], mx);
            alpha[r] = __expf(m_i[r] - mn);
            m_i[r] = mn;
        }
        float rsum[4] = {0.f, 0.f, 0.f, 0.f};
        #pragma unroll
        for (int j = 0; j < 4; j++)
            #pragma unroll
            for (int r = 0; r < 4; r++) {
                float pv = __expf(sc[j][r] - m_i[r]);
                sc[j][r] = pv;
                rsum[r] += pv;
            }
        #pragma unroll
        for (int r = 0; r < 4; r++) {
            #pragma unroll
            for (int d = 1; d < 16; d <<= 1) rsum[r] += __shfl_xor(rsum[r], d, 64);
            l_i[r] = l_i[r] * alpha[r] + rsum[r];
        }
        #pragma unroll
        for (int j = 0; j < 4; j++)
            #pragma unroll
            for (int r = 0; r < 4; r++)
                Ps[wave][quad*4 + r][j*16 + l16] = f2bf(sc[j][r]);
        #pragma unroll
        for (int j2 = 0; j2 < 4; j2++)
            #pragma unroll
            for (int r = 0; r < 4; r++)
                o_acc[j2][r] *= alpha[r];
        __syncthreads();
        #pragma unroll
        for (int kk = 0; kk < 64; kk += 32) {
            s16x8 ap = *(const s16x8*)&Ps[wave][l16][kk + quad*8];
            #pragma unroll
            for (int j2 = 0; j2 < 4; j2++) {
                s16x8 bv = *(const s16x8*)&Vt[j2*16 + l16][kk + quad*8];
                o_acc[j2] = mfma16(ap, bv, o_acc[j2]);
            }
        }
    }
    #pragma unroll
    for (int j2 = 0; j2 < 4; j2++) {
        #pragma unroll
        for (int r = 0; r < 4; r++) {
            float v = o_acc[j2][r] / l_i[r];
            long row = (long)b * T_N + qt0 + wave*16 + quad*4 + r;
            O[row * 1024 + h*64 + j2*16 + l16] = f2bf(v);
        }
    }
}

// ---------------------------------------------------------------- ssc[b,t,s] = qs.ks/32 (masked)
__global__ __launch_bounds__(256) void ssc_kernel(
    const u16* __restrict__ qs, const u16* __restrict__ ks,
    const int* __restrict__ svl, float* __restrict__ ssc, int qld)
{
    const int t = blockIdx.x, b = blockIdx.y;
    const int wave = threadIdx.x >> 6, lane = threadIdx.x & 63;
    const u16* qrow = qs + ((long)b * T_N + t) * qld + lane * 16;
    const int vl = svl[b];
    for (int s = wave; s < 16; s += 4) {
        const u16* krow = ks + ((long)b * 16 + s) * 1024 + lane * 16;
        float acc = 0.f;
        #pragma unroll
        for (int seg = 0; seg < 2; seg++) {
            s16x8 qv = *(const s16x8*)(qrow + seg*8);
            s16x8 kv = *(const s16x8*)(krow + seg*8);
            #pragma unroll
            for (int j = 0; j < 8; j++) acc += bf2f((u16)qv[j]) * bf2f((u16)kv[j]);
        }
        #pragma unroll
        for (int d = 1; d < 64; d <<= 1) acc += __shfl_xor(acc, d, 64);
        if (lane == 0)
            ssc[((long)b * T_N + t) * 16 + s] = (s < vl) ? acc * (1.f/32.f) : NEGV;
    }
}

// ---------------------------------------------------------------- top-8 stats, top-16 tokens, sparse combine
__global__ __launch_bounds__(256) void select_combine_kernel(
    const float* __restrict__ ssc, const float* __restrict__ tsc,
    const u16* __restrict__ vv, u16* __restrict__ out, int t0, int vld)
{
    const int tl = blockIdx.x, b = blockIdx.y;
    const int tg = t0 + tl;
    const int tid = threadIdx.x;
    const int wave = tid >> 6, lane = tid & 63;
    __shared__ float coeff[128];
    __shared__ long  rowoff[128];
    __shared__ int   sel_s[8];
    __shared__ float sel_w[8];

    if (wave == 0) {
        float cur = (lane < 16) ? ssc[((long)b * T_N + tg) * 16 + lane] : -3e38f;
        float mx0 = 0.f, ssum = 0.f, myv = -3e38f;
        int myi = 0;
        #pragma unroll
        for (int it = 0; it < 8; it++) {
            float mv = cur; int mi = lane;
            #pragma unroll
            for (int d = 1; d < 64; d <<= 1) {
                float ov = __shfl_xor(mv, d, 64);
                int   oi = __shfl_xor(mi, d, 64);
                if (ov > mv || (ov == mv && oi < mi)) { mv = ov; mi = oi; }
            }
            if (it == 0) mx0 = mv;
            ssum += __expf(mv - mx0);
            if (lane == it) { myv = mv; myi = mi; }
            if (lane == mi) cur = -3e38f;
        }
        if (lane < 8) { sel_s[lane] = myi; sel_w[lane] = __expf(myv - mx0) / ssum; }
    }
    __syncthreads();

    for (int slot = wave; slot < 8; slot += 4) {
        int s = sel_s[slot];
        float sw = sel_w[slot];
        const float* trow = tsc + (((long)b * 16 + s) * 512 + tl) * 256;
        float4 lv4 = *(const float4*)(trow + lane * 4);
        float loc[4] = { lv4.x, lv4.y, lv4.z, lv4.w };
        float mx0 = 0.f, tsum = 0.f, myv = -3e38f;
        int myi = 0;
        for (int it = 0; it < 16; it++) {
            float mv = -3e38f; int mi = 0;
            #pragma unroll
            for (int u = 0; u < 4; u++)
                if (loc[u] > mv) { mv = loc[u]; mi = lane*4 + u; }
            #pragma unroll
            for (int d = 1; d < 64; d <<= 1) {
                float ov = __shfl_xor(mv, d, 64);
                int   oi = __shfl_xor(mi, d, 64);
                if (ov > mv || (ov == mv && oi < mi)) { mv = ov; mi = oi; }
            }
            if (it == 0) mx0 = mv * (1.f/32.f);
            tsum += __expf(mv * (1.f/32.f) - mx0);
            if (lane == it) { myv = mv; myi = mi; }
            if ((mi >> 2) == lane) {
                int u = mi & 3;
                if (u == 0) loc[0] = -3e38f;
                else if (u == 1) loc[1] = -3e38f;
                else if (u == 2) loc[2] = -3e38f;
                else loc[3] = -3e38f;
            }
        }
        if (lane < 16) {
            coeff[slot * 16 + lane]  = sw * __expf(myv * (1.f/32.f) - mx0) / tsum;
            rowoff[slot * 16 + lane] = (long)((b * 16 + s) * 256 + myi) * vld;
        }
    }
    __syncthreads();

    const int d0 = tid * 4;
    float a0 = 0.f, a1 = 0.f, a2 = 0.f, a3 = 0.f;
    for (int r = 0; r < 128; r++) {
        float c = coeff[r];
        const u16* vp = vv + rowoff[r] + d0;
        u16x4 v4 = *(const u16x4*)vp;
        a0 += c * bf2f(v4[0]);
        a1 += c * bf2f(v4[1]);
        a2 += c * bf2f(v4[2]);
        a3 += c * bf2f(v4[3]);
    }
    u16x4 o4 = { f2bf(a0), f2bf(a1), f2bf(a2), f2bf(a3) };
    *(u16x4*)(out + ((long)b * T_N + tg) * 1024 + d0) = o4;
}

// ---------------------------------------------------------------- LN kernels
__device__ __forceinline__ float block_sum(float v, float* red) {
    #pragma unroll
    for (int d = 1; d < 64; d <<= 1) v += __shfl_xor(v, d, 64);
    __syncthreads();
    if ((threadIdx.x & 63) == 0) red[threadIdx.x >> 6] = v;
    __syncthreads();
    return red[0] + red[1] + red[2] + red[3];
}

__global__ __launch_bounds__(256) void ln1_kernel(
    const float* __restrict__ x, const float* __restrict__ x2,
    const float* __restrict__ intent, const float* __restrict__ g, const float* __restrict__ be,
    u16* __restrict__ yi)
{
    __shared__ float red[4];
    const long row = blockIdx.x;
    const int tid = threadIdx.x;
    const long base = row * 1024 + tid * 4;
    float4 xv = *(const float4*)(x + base);
    float4 dv = *(const float4*)(x2 + base);
    float h0 = xv.x + dv.x, h1 = xv.y + dv.y, h2 = xv.z + dv.z, h3 = xv.w + dv.w;
    float s1 = block_sum(h0 + h1 + h2 + h3, red);
    float s2 = block_sum(h0*h0 + h1*h1 + h2*h2 + h3*h3, red);
    float mean = s1 * (1.f/1024.f);
    float var = s2 * (1.f/1024.f) - mean * mean;
    float inv = rsqrtf(var + 1e-5f);
    const int c = tid * 4;
    float4 gv = *(const float4*)(g + c);
    float4 bv = *(const float4*)(be + c);
    float o0 = (h0 - mean) * inv * gv.x + bv.x;
    float o1 = (h1 - mean) * inv * gv.y + bv.y;
    float o2 = (h2 - mean) * inv * gv.z + bv.z;
    float o3 = (h3 - mean) * inv * gv.w + bv.w;
    u16x4 ob = { f2bf(o0), f2bf(o1), f2bf(o2), f2bf(o3) };
    *(u16x4*)(yi + row * 1280 + c) = ob;
    const int b = (int)(row >> 10);
    yi[row * 1280 + 1024 + tid] = f2bf(intent[b * 256 + tid]);
}

__global__ __launch_bounds__(256) void gate_ln2_kernel(
    const u16* __restrict__ yi, const float* __restrict__ y2s, const float* __restrict__ y2e,
    const float* __restrict__ Wg, const float* __restrict__ g, const float* __restrict__ be,
    float* __restrict__ z, u16* __restrict__ zbf)
{
    __shared__ float red[4];
    const long row = blockIdx.x;
    const int tid = threadIdx.x;
    const long base = row * 1024 + tid * 4;
    const int c = tid * 4;
    float4 sv = *(const float4*)(y2s + base);
    float4 ev = *(const float4*)(y2e + base);
    float4 w1 = *(const float4*)(Wg + c);
    float4 w2 = *(const float4*)(Wg + 1024 + c);
    float dot = sv.x*w1.x + sv.y*w1.y + sv.z*w1.z + sv.w*w1.w
              + ev.x*w2.x + ev.y*w2.y + ev.z*w2.z + ev.w*w2.w;
    float tot = block_sum(dot, red);
    float gate = 1.f / (1.f + __expf(-tot));
    u16x4 yv4 = *(const u16x4*)(yi + row * 1280 + c);
    float h0 = bf2f(yv4[0]) + 2.f * (gate * sv.x + (1.f - gate) * ev.x);
    float h1 = bf2f(yv4[1]) + 2.f * (gate * sv.y + (1.f - gate) * ev.y);
    float h2 = bf2f(yv4[2]) + 2.f * (gate * sv.z + (1.f - gate) * ev.z);
    float h3 = bf2f(yv4[3]) + 2.f * (gate * sv.w + (1.f - gate) * ev.w);
    float s1 = block_sum(h0 + h1 + h2 + h3, red);
    float s2 = block_sum(h0*h0 + h1*h1 + h2*h2 + h3*h3, red);
    float mean = s1 * (1.f/1024.f);
    float var = s2 * (1.f/1024.f) - mean * mean;
    float inv = rsqrtf(var + 1e-5f);
    float4 gv = *(const float4*)(g + c);
    float4 bv = *(const float4*)(be + c);
    float o0 = (h0 - mean) * inv * gv.x + bv.x;
    float o1 = (h1 - mean) * inv * gv.y + bv.y;
    float o2 = (h2 - mean) * inv * gv.z + bv.z;
    float o3 = (h3 - mean) * inv * gv.w + bv.w;
    *(float4*)(z + base) = make_float4(o0, o1, o2, o3);
    u16x4 ob = { f2bf(o0), f2bf(o1), f2bf(o2), f2bf(o3) };
    *(u16x4*)(zbf + row * 1024 + c) = ob;
}

// final LN over z + (p0 + p1 + b2)  — FFN2 split-K partials fused here
__global__ __launch_bounds__(256) void ln3_kernel(
    const float* __restrict__ z, const float* __restrict__ p0, const float* __restrict__ p1,
    const float* __restrict__ b2,
    const float* __restrict__ g, const float* __restrict__ be, float* __restrict__ out)
{
    __shared__ float red[4];
    const long row = blockIdx.x;
    const int tid = threadIdx.x;
    const long base = row * 1024 + tid * 4;
    const int c = tid * 4;
    float4 zv = *(const float4*)(z + base);
    float4 f0 = *(const float4*)(p0 + base);
    float4 f1 = *(const float4*)(p1 + base);
    float4 bb = *(const float4*)(b2 + c);
    float h0 = zv.x + f0.x + f1.x + bb.x;
    float h1 = zv.y + f0.y + f1.y + bb.y;
    float h2 = zv.z + f0.z + f1.z + bb.z;
    float h3 = zv.w + f0.w + f1.w + bb.w;
    float s1 = block_sum(h0 + h1 + h2 + h3, red);
    float s2 = block_sum(h0*h0 + h1*h1 + h2*h2 + h3*h3, red);
    float mean = s1 * (1.f/1024.f);
    float var = s2 * (1.f/1024.f) - mean * mean;
    float inv = rsqrtf(var + 1e-5f);
    float4 gv = *(const float4*)(g + c);
    float4 bv = *(const float4*)(be + c);
    float o0 = (h0 - mean) * inv * gv.x + bv.x;
    float o1 = (h1 - mean) * inv * gv.y + bv.y;
    float o2 = (h2 - mean) * inv * gv.z + bv.z;
    float o3 = (h3 - mean) * inv * gv.w + bv.w;
    *(float4*)(out + base) = make_float4(o0, o1, o2, o3);
}

// ---------------------------------------------------------------- host
extern "C" void kernel_launch(void* const* d_in, const int* in_sizes, int n_in,
                              void* d_out, int out_size, void* d_ws, size_t ws_size,
                              hipStream_t stream)
{
    (void)in_sizes; (void)n_in; (void)out_size; (void)ws_size;
    const float* x      = (const float*)d_in[0];
    const float* stat_e = (const float*)d_in[1];
    const float* exem   = (const float*)d_in[2];
    const float* sfeat  = (const float*)d_in[3];
    const float* intent = (const float*)d_in[4];
    const float* Wg  = (const float*)d_in[19];
    const float* b1  = (const float*)d_in[21];
    const float* b2  = (const float*)d_in[23];
    const float* g1  = (const float*)d_in[24]; const float* be1 = (const float*)d_in[25];
    const float* g2  = (const float*)d_in[26]; const float* be2 = (const float*)d_in[27];
    const float* g3  = (const float*)d_in[28]; const float* be3 = (const float*)d_in[29];
    const int* svl = (const int*)d_in[30];
    const int* evl = (const int*)d_in[31];
    float* outp = (float*)d_out;

    // ---- workspace plan: 171 MB, lifetime-aliased ----
    char* base = (char*)d_ws;
    u16*  bufA  = (u16*)(base + 0*MB);        // 8MB: xbf / attn-outs / y2s_pre
    u16*  qkv1  = (u16*)(base + 8*MB);        // 24MB fused [4096,3072] (phase 3)
    float* x2a  = (float*)(base + 8*MB);      // 16MB (after flash1)
    u16*  kv2   = (u16*)(base + 8*MB);        // 16MB fused [4096,2048] (phase 5)
    u16*  w1t   = (u16*)(base + 8*MB);        // 8MB (phase 7)
    u16*  w2t   = (u16*)(base + 16*MB);       // 8MB (phase 7)
    u16*  yibf  = (u16*)(base + 32*MB);       // 10MB [4096,1280]
    u16*  buf3  = (u16*)(base + 42*MB);       // 24MB fused qs|qt|q2 [4096,3072]
    u16*  zbf   = (u16*)(base + 42*MB);       // 8MB (after flash2)
    u16*  sebf  = (u16*)(base + 66*MB);       // 32MB stat_enc bf16 / tsc-half fp32 / ffn hidden
    float* tsch = (float*)(base + 66*MB);
    u16*  hid   = (u16*)(base + 66*MB);
    u16*  ktvv  = (u16*)(base + 98*MB);       // 64MB fused [16384,2048]
    float* y2sf = (float*)(base + 98*MB);     // 16MB (after select)
    float* p0f  = (float*)(base + 98*MB);     // 32MB FFN2 partials (after gate_ln2; y2ef dead)
    u16*  exbf  = (u16*)(base + 114*MB);      // 8MB
    float* y2ef = (float*)(base + 122*MB);    // 16MB
    float* zf   = (float*)(base + 138*MB);    // 16MB
    u16*  sfbf  = (u16*)(base + 162*MB);                  // 128KB
    u16*  ksbf  = (u16*)(base + 162*MB + 256*1024);       // 128KB
    float* sscf = (float*)(base + 162*MB + 512*1024);     // 256KB
    char* wpool = base + 163*MB;              // 8MB rotating weight pool (total 171MB)

    dim3 blk(256);
    dim3 blk512(512);
    auto cast = [&](const float* s, u16* d, long n) {
        cast_bf16_kernel<<<dim3((unsigned)((n/4 + 255) / 256)), blk, 0, stream>>>(s, d, n);
    };
    auto g_n = [&](const u16* A, const u16* Bt, u16* C, int M, int N, int K,
                   int lda, int ldb, int ldc) {
        gemm_bt<u16,false,false><<<dim3(N/128, (M+127)/128, 1), blk, 0, stream>>>(
            A, Bt, C, nullptr, M, N, K, lda, ldb, ldc, 1, 0, 0, 0);
    };
    auto g_f = [&](const u16* A, const u16* Bt, float* C, int M, int N, int K,
                   int lda, int ldb, int ldc) {
        gemm_bt<float,false,false><<<dim3(N/128, (M+127)/128, 1), blk, 0, stream>>>(
            A, Bt, C, nullptr, M, N, K, lda, ldb, ldc, 1, 0, 0, 0);
    };
    // 256^2 deep-pipelined GEMM — M,N multiples of 256, grid must fill >=192 CUs
    auto g256_n = [&](const u16* A, const u16* Bt, u16* C, int M, int N, int K,
                      int lda, int ldb, int ldc) {
        gemm_bt256<u16,false,false><<<dim3(N/256, M/256, 1), blk512, 0, stream>>>(
            A, Bt, C, nullptr, M, N, K, lda, ldb, ldc, 1, 0, 0, 0);
    };

    // ---- phase 3: self-attention ----
    u16* wqkv1t = (u16*)wpool;                       // [3072,1024] stacked
    u16* wo1t   = (u16*)(wpool) + 3L*1024*1024;
    {
        P6 pp{};
        pp.s[0]=(const float*)d_in[5]; pp.d[0]=wqkv1t;
        pp.s[1]=(const float*)d_in[6]; pp.d[1]=wqkv1t + 1L*1024*1024;
        pp.s[2]=(const float*)d_in[7]; pp.d[2]=wqkv1t + 2L*1024*1024;
        pp.s[3]=(const float*)d_in[8]; pp.d[3]=wo1t;
        transpose_cast_batch<<<dim3(32, 32, 4), blk, 0, stream>>>(pp, 1024, 1024);
    }
    cast(x, bufA, 4096L*1024);
    g256_n(bufA, wqkv1t, qkv1, 4096, 3072, 1024, 1024, 1024, 3072);
    flash_attn_kernel<true><<<dim3(16, 16, 4), blk, 0, stream>>>(
        qkv1, qkv1 + 1024, qkv1 + 2048, nullptr, bufA, 3072, 3072, 3072);
    g_f(bufA, wo1t, x2a, 4096, 1024, 1024, 1024, 1024, 1024);
    ln1_kernel<<<dim3(4096), blk, 0, stream>>>(x, x2a, intent, g1, be1, yibf);

    // ---- phase 4: selective hierarchical attention ----
    u16* wq3t = (u16*)wpool;
    {
        P6 pp{};
        pp.s[0]=(const float*)d_in[9];  pp.d[0]=wq3t;
        pp.s[1]=(const float*)d_in[10]; pp.d[1]=wq3t + 1L*1024*1280;
        pp.s[2]=(const float*)d_in[15]; pp.d[2]=wq3t + 2L*1024*1280;
        transpose_cast_batch<<<dim3(32, 40, 3), blk, 0, stream>>>(pp, 1280, 1024);
    }
    g256_n(yibf, wq3t, buf3, 4096, 3072, 1280, 1280, 1280, 3072);   // qs|qt|q2
    u16* wkst = (u16*)wpool;
    u16* wkv  = (u16*)(wpool) + 1L*1024*1024;
    {
        P6 pp{};
        pp.s[0]=(const float*)d_in[11]; pp.d[0]=wkst;
        pp.s[1]=(const float*)d_in[12]; pp.d[1]=wkv;
        pp.s[2]=(const float*)d_in[13]; pp.d[2]=wkv + 1L*1024*1024;
        transpose_cast_batch<<<dim3(32, 32, 3), blk, 0, stream>>>(pp, 1024, 1024);
    }
    cast(sfeat, sfbf, 64L*1024);
    cast(stat_e, sebf, 16384L*1024);
    g_n(sfbf, wkst, ksbf, 64, 1024, 1024, 1024, 1024, 1024);
    g256_n(sebf, wkv, ktvv, 16384, 2048, 1024, 1024, 1024, 2048);   // kt|vv
    ssc_kernel<<<dim3(1024, 4), blk, 0, stream>>>(buf3, ksbf, svl, sscf, 3072);
    for (int hh = 0; hh < 2; hh++) {
        long t0 = hh * 512;
        gemm_bt<float,false,false><<<dim3(2, 4, 64), blk, 0, stream>>>(
            buf3 + 1024 + t0*3072, ktvv, tsch, nullptr, 512, 256, 1024,
            3072, 2048, 256, 16, (long)T_N*3072, 256L*2048, 512L*256);
        select_combine_kernel<<<dim3(512, 4), blk, 0, stream>>>(
            sscf, tsch, ktvv + 1024, bufA, (int)t0, 2048);
    }
    u16* wost = (u16*)wpool;
    u16* wkv2 = (u16*)(wpool) + 1L*1024*1024;
    u16* wo2t = (u16*)(wpool) + 3L*1024*1024;
    {
        P6 pp{};
        pp.s[0]=(const float*)d_in[14]; pp.d[0]=wost;
        pp.s[1]=(const float*)d_in[16]; pp.d[1]=wkv2;
        pp.s[2]=(const float*)d_in[17]; pp.d[2]=wkv2 + 1L*1024*1024;
        pp.s[3]=(const float*)d_in[18]; pp.d[3]=wo2t;
        transpose_cast_batch<<<dim3(32, 32, 4), blk, 0, stream>>>(pp, 1024, 1024);
    }
    g_f(bufA, wost, y2sf, 4096, 1024, 1024, 1024, 1024, 1024);

    // ---- phase 5: exemplar cross-attention ----
    cast(exem, exbf, 4096L*1024);
    g_n(exbf, wkv2, kv2, 4096, 2048, 1024, 1024, 1024, 2048);       // k2|v2 (128^2: 512 blocks)
    flash_attn_kernel<false><<<dim3(16, 16, 4), blk, 0, stream>>>(
        buf3 + 2048, kv2, kv2 + 1024, evl, bufA, 3072, 2048, 2048);
    g_f(bufA, wo2t, y2ef, 4096, 1024, 1024, 1024, 1024, 1024);

    // ---- phase 6: gate + LN2 ----
    gate_ln2_kernel<<<dim3(4096), blk, 0, stream>>>(yibf, y2sf, y2ef, Wg, g2, be2, zf, zbf);

    // ---- phase 7: FFN ----
    {
        P6 pp{}; pp.s[0] = (const float*)d_in[20]; pp.d[0] = w1t;
        transpose_cast_batch<<<dim3(128, 32, 1), blk, 0, stream>>>(pp, 1024, 4096);
    }
    {
        P6 pp{}; pp.s[0] = (const float*)d_in[22]; pp.d[0] = w2t;
        transpose_cast_batch<<<dim3(32, 128, 1), blk, 0, stream>>>(pp, 4096, 1024);
    }
    gemm_bt256<u16,true,true><<<dim3(16, 16, 1), blk512, 0, stream>>>(
        zbf, w1t, hid, b1, 4096, 4096, 1024, 1024, 1024, 4096, 1, 0, 0, 0);
    // FFN2 split-K x2 in one dispatch (z picks K-half): p[z] = hid[:,z*2048:] @ w2t[:,z*2048:]^T
    // 128^2 path: 512 blocks (256^2 grid would be 128 blocks -> half the CUs idle)
    gemm_bt<float,false,false><<<dim3(8, 32, 2), blk, 0, stream>>>(
        hid, w2t, p0f, nullptr, 4096, 1024, 2048, 4096, 4096, 1024,
        1, 2048, 2048, 4096L*1024);

    // ---- phase 8: final LN (fuses p0+p1+b2) ----
    ln3_kernel<<<dim3(4096), blk, 0, stream>>>(zf, p0f, p0f + 4096L*1024, b2, g3, be3, outp);
}

// Round 3
// 1005.410 us; speedup vs baseline: 1.0536x; 1.0127x over previous
//
#include <hip/hip_runtime.h>

typedef unsigned short u16;
typedef short s16x8 __attribute__((ext_vector_type(8)));
typedef u16 u16x4 __attribute__((ext_vector_type(4)));
typedef float f32x4 __attribute__((ext_vector_type(4)));

#define T_N   1024
#define NEGV  -1e6f
#define MB    (1L << 20)

__device__ __forceinline__ u16 f2bf(float f) {
    unsigned u = __float_as_uint(f);
    u += 0x7fffu + ((u >> 16) & 1u);     // RNE
    return (u16)(u >> 16);
}
__device__ __forceinline__ float bf2f(u16 h) {
    return __uint_as_float(((unsigned)h) << 16);
}
__device__ __forceinline__ f32x4 mfma16(s16x8 a, s16x8 b, f32x4 c) {
    return __builtin_amdgcn_mfma_f32_16x16x32_bf16(a, b, c, 0, 0, 0);
}
// async global->LDS, 16B per lane; LDS dest = wave-uniform base + lane*16 (m97/m104)
__device__ __forceinline__ void gll16(const u16* g, u16* l) {
    __builtin_amdgcn_global_load_lds((const __attribute__((address_space(1))) void*)g,
                                     (__attribute__((address_space(3))) void*)l, 16, 0, 0);
}

// ---------------------------------------------------------------- transpose+cast
struct P6 { const float* s[6]; u16* d[6]; };

__global__ __launch_bounds__(256) void transpose_cast_batch(P6 pp, int K, int N) {
    const float* __restrict__ src = pp.s[blockIdx.z];
    u16* __restrict__ dst = pp.d[blockIdx.z];
    __shared__ float tile[32][33];
    int nb = blockIdx.x * 32, kb = blockIdx.y * 32;
    int tx = threadIdx.x & 31, ty = threadIdx.x >> 5;   // ty 0..7
    #pragma unroll
    for (int i = 0; i < 4; i++)
        tile[ty + 8*i][tx] = src[(long)(kb + ty + 8*i) * N + nb + tx];
    __syncthreads();
    #pragma unroll
    for (int i = 0; i < 4; i++)
        dst[(long)(nb + ty + 8*i) * K + kb + tx] = f2bf(tile[tx][ty + 8*i]);
}

__global__ __launch_bounds__(256) void cast_bf16_kernel(const float* __restrict__ src,
                                                        u16* __restrict__ dst, long n) {
    long i = ((long)blockIdx.x * 256 + threadIdx.x) * 4;
    if (i >= n) return;
    float4 v = *(const float4*)(src + i);
    u16x4 o = { f2bf(v.x), f2bf(v.y), f2bf(v.z), f2bf(v.w) };
    *(u16x4*)(dst + i) = o;
}

// ---------------------------------------------------------------- GEMM: C[M,N] = A[M,K] * Bt[N,K]^T
// 128x128-tile fallback kernel (m97 structure) — used for shapes whose 256^2
// grid would under-fill 256 CUs (small-M, N=1024 Wo projections, batched tsc,
// FFN2 split-K).
template<typename OutT, bool RELU, bool HAS_BIAS>
__global__ __launch_bounds__(256) void gemm_bt(
    const u16* __restrict__ A, const u16* __restrict__ Bt, OutT* __restrict__ C,
    const float* __restrict__ bias, int M, int N, int K,
    int lda, int ldb, int ldc,
    int batchDivA, long sA, long sB, long sC)
{
    A  += (long)(blockIdx.z / batchDivA) * sA;
    Bt += (long)blockIdx.z * sB;
    C  += (long)blockIdx.z * sC;
    __shared__ __align__(16) u16 As[4096];   // [128][32] row-major, 8 KB
    __shared__ __align__(16) u16 Bs[4096];
    const int tid = threadIdx.x;
    const int wave = tid >> 6, lane = tid & 63;
    const int quad = lane >> 4, l16 = lane & 15;
    const int wr = (wave >> 1) * 64, wc = (wave & 1) * 64;
    const long row0 = (long)blockIdx.y * 128, col0 = (long)blockIdx.x * 128;

    f32x4 acc[4][4] = {};

    const int l4r = lane >> 2;
    const int l4c = (lane & 3) * 8;
    const int ra = wave * 32 + l4r;
    const u16* Ap0 = A + (row0 + ra) * (long)lda + l4c;
    const u16* Ap1 = Ap0 + 16L * lda;
    const u16* Bp0 = Bt + (col0 + ra) * (long)ldb + l4c;
    const u16* Bp1 = Bp0 + 16L * ldb;
    u16* AsW0 = &As[(wave * 32) * 32];
    u16* AsW1 = &As[(wave * 32 + 16) * 32];
    u16* BsW0 = &Bs[(wave * 32) * 32];
    u16* BsW1 = &Bs[(wave * 32 + 16) * 32];
    const bool aok0 = (row0 + wave * 32) < M;
    const bool aok1 = (row0 + wave * 32 + 16) < M;

    for (int k0 = 0; k0 < K; k0 += 32) {
        __syncthreads();
        if (aok0) gll16(Ap0 + k0, AsW0);
        if (aok1) gll16(Ap1 + k0, AsW1);
        gll16(Bp0 + k0, BsW0);
        gll16(Bp1 + k0, BsW1);
        __syncthreads();
        s16x8 af[4], bfr[4];
        #pragma unroll
        for (int i = 0; i < 4; i++)
            af[i]  = *(const s16x8*)&As[(wr + i*16 + l16) * 32 + quad*8];
        #pragma unroll
        for (int j = 0; j < 4; j++)
            bfr[j] = *(const s16x8*)&Bs[(wc + j*16 + l16) * 32 + quad*8];
        #pragma unroll
        for (int i = 0; i < 4; i++)
            #pragma unroll
            for (int j = 0; j < 4; j++)
                acc[i][j] = mfma16(af[i], bfr[j], acc[i][j]);
    }

    #pragma unroll
    for (int i = 0; i < 4; i++) {
        long row = row0 + wr + i*16 + quad*4;
        #pragma unroll
        for (int j = 0; j < 4; j++) {
            long col = col0 + wc + j*16 + l16;
            float bv = 0.f;
            if constexpr (HAS_BIAS) bv = bias[col];
            #pragma unroll
            for (int r = 0; r < 4; r++) {
                if (row + r < M) {
                    float v = acc[i][j][r] + bv;
                    if constexpr (RELU) v = fmaxf(v, 0.f);
                    if constexpr (sizeof(OutT) == 2) C[(row + r) * (long)ldc + col] = f2bf(v);
                    else                             C[(row + r) * (long)ldc + col] = v;
                }
            }
        }
    }
}

// ---------------------------------------------------------------- GEMM 256^2, de-lockstepped pipeline
// 256x256 tile, BK=32, 8 waves (2Mx4N), per-wave 128x64 output.
// 4-deep LDS ring buffer: 4 x (A[256][32] + B[256][32]) bf16 = 128 KiB total.
//
// ONE barrier + ONE counted vmcnt per K-slice (was 4 barriers + 2 lgkmcnt(0)
// + 2 sched_barrier(0) in the lockstep version, which pinned all 8 waves into
// read-burst/MFMA-burst alternation: LDS saturated while MFMA idle, then
// vice-versa; measured MfmaUtil 32%). Inside a slice the compiler schedules
// {12 ds_read_b128, 4 global_load_lds, 32 MFMA} freely: it emits incremental
// lgkmcnt waits so MFMA starts when its first frags land, and waves drift
// between barriers so one wave's MFMA overlaps another's LDS reads (m114).
//
// Hazards (audited): stage into slot (kt+3)&3 is separated from that slot's
// last readers (slice kt-1) by the end-of-slice-(kt-1) barrier. The vmcnt(8)
// at end of slice kt retires exactly slice-(kt-2)'s 4 loads = buffer (kt+1),
// the one read next slice; barrier makes it block-wide. sched_barrier(0)
// after each s_barrier stops cross-slice instruction motion (raw s_barrier
// alone is not a compiler memory fence).
//
// T2 chunk swizzle kept (conflicts measured 0): read chunk = quad^((l16>>1)&3),
// stage source column gets the same involution, LDS stays DMA-linear.
// T1 XCD swizzle: bijective chunked remap when grid %8==0 (all our 256^2 grids).
// Requires: M%256==0, N%256==0, K%32==0, K>=128.
template<typename OutT, bool RELU, bool HAS_BIAS>
__global__ __launch_bounds__(512, 2) void gemm_bt256(
    const u16* __restrict__ A, const u16* __restrict__ Bt, OutT* __restrict__ C,
    const float* __restrict__ bias, int M, int N, int K,
    int lda, int ldb, int ldc,
    int batchDivA, long sA, long sB, long sC)
{
    // T1: XCD-aware bijective block remap (contiguous chunk per XCD)
    int bx = blockIdx.x, by = blockIdx.y;
    {
        const int nwg = gridDim.x * gridDim.y;
        if ((nwg & 7) == 0) {
            const int flat = by * gridDim.x + bx;
            const int nf = (flat & 7) * (nwg >> 3) + (flat >> 3);
            bx = nf % gridDim.x;
            by = nf / gridDim.x;
        }
    }
    A  += (long)(blockIdx.z / batchDivA) * sA;
    Bt += (long)blockIdx.z * sB;
    C  += (long)blockIdx.z * sC;
    __shared__ __align__(16) u16 As[4][8192];   // [256][32] each, 16 KB x4
    __shared__ __align__(16) u16 Bs[4][8192];
    const int tid = threadIdx.x;
    const int wave = tid >> 6, lane = tid & 63;
    const int quad = lane >> 4, l16 = lane & 15;
    const int wm = wave >> 2, wn = wave & 3;           // 2 x 4 wave grid
    const long row0 = (long)by * 256, col0 = (long)bx * 256;

    // staging: thread t covers row (t>>2); SOURCE chunk is XOR-swizzled so the
    // linear DMA write leaves LDS(r,s) = global chunk (r, s ^ ((r>>1)&3)).
    const int srow = tid >> 2;
    const int scol = ((tid & 3) ^ ((srow >> 1) & 3)) * 8;
    const u16* Ag = A  + (row0 + srow) * (long)lda + scol;
    const u16* Bg = Bt + (col0 + srow) * (long)ldb + scol;
    const int ldsoff = wave * 512;                      // wave-uniform elem offset

    f32x4 acc[8][4] = {};
    const int NT = K >> 5;

    auto stageA = [&](int kt, int buf) {
        gll16(Ag + (long)kt * 32,            &As[buf][ldsoff]);
        gll16(Ag + (long)kt * 32 + 128L*lda, &As[buf][4096 + ldsoff]);
    };
    auto stageB = [&](int kt, int buf) {
        gll16(Bg + (long)kt * 32,            &Bs[buf][ldsoff]);
        gll16(Bg + (long)kt * 32 + 128L*ldb, &Bs[buf][4096 + ldsoff]);
    };

    // prologue: slices 0,1,2 staged (12 loads/wave); wait until slice 0 landed
    stageA(0, 0); stageB(0, 0);
    stageA(1, 1); stageB(1, 1);
    stageA(2, 2); stageB(2, 2);
    asm volatile("s_waitcnt vmcnt(8)" ::: "memory");
    __builtin_amdgcn_s_barrier();
    __builtin_amdgcn_sched_barrier(0);

    const int arow = wm * 128 + l16;
    const int brow = wn * 64  + l16;
    const int kq   = (quad ^ ((l16 >> 1) & 3)) * 8;     // swizzled chunk offset

    for (int kt = 0; kt < NT; ++kt) {
        const int b  = kt & 3;
        const int sb = (kt + 3) & 3;
        const bool st = (kt + 3) < NT;
        const u16* Ab = As[b];
        const u16* Bb = Bs[b];

        // frag reads (compiler interleaves incremental lgkm waits with MFMA)
        s16x8 bfr[4], af[8];
        #pragma unroll
        for (int j = 0; j < 4; ++j)
            bfr[j] = *(const s16x8*)&Bb[(brow + j*16) * 32 + kq];
        #pragma unroll
        for (int i = 0; i < 8; ++i)
            af[i] = *(const s16x8*)&Ab[(arow + i*16) * 32 + kq];

        // prefetch slice kt+3 into its ring slot (disjoint from b; publishers
        // of slot sb's previous contents were fenced by slice kt-1's barrier)
        if (st) { stageA(kt + 3, sb); stageB(kt + 3, sb); }

        #pragma unroll
        for (int i = 0; i < 8; ++i)
            #pragma unroll
            for (int j = 0; j < 4; ++j)
                acc[i][j] = mfma16(af[i], bfr[j], acc[i][j]);

        // counted wait: retire slice kt-2's loads (= buffer kt+1, read next)
        const int rem = NT - 2 - kt;
        if (rem >= 2)      asm volatile("s_waitcnt vmcnt(8)" ::: "memory");
        else if (rem == 1) asm volatile("s_waitcnt vmcnt(4)" ::: "memory");
        else if (rem == 0) asm volatile("s_waitcnt vmcnt(0)" ::: "memory");
        __builtin_amdgcn_s_barrier();
        __builtin_amdgcn_sched_barrier(0);
    }

    #pragma unroll
    for (int i = 0; i < 8; ++i) {
        const long row = row0 + wm*128 + i*16 + quad*4;
        #pragma unroll
        for (int j = 0; j < 4; ++j) {
            const long col = col0 + wn*64 + j*16 + l16;
            float bv = 0.f;
            if constexpr (HAS_BIAS) bv = bias[col];
            #pragma unroll
            for (int r = 0; r < 4; ++r) {
                float v = acc[i][j][r] + bv;
                if constexpr (RELU) v = fmaxf(v, 0.f);
                if constexpr (sizeof(OutT) == 2) C[(row + r) * (long)ldc + col] = f2bf(v);
                else                             C[(row + r) * (long)ldc + col] = v;
            }
        }
    }
}

// ---------------------------------------------------------------- flash attention (dh=64, H=16)
template<bool CAUSAL>
__global__ __launch_bounds__(256) void flash_attn_kernel(
    const u16* __restrict__ Q, const u16* __restrict__ Kg, const u16* __restrict__ Vg,
    const int* __restrict__ valid_len, u16* __restrict__ O,
    int qld, int kld, int vld)
{
    const int h = blockIdx.y, b = blockIdx.z;
    const int qt0 = blockIdx.x * 64;
    const int tid = threadIdx.x;
    const int wave = tid >> 6, lane = tid & 63;
    const int quad = lane >> 4, l16 = lane & 15;

    __shared__ __align__(16) u16 Qs[64][72];
    __shared__ __align__(16) u16 Ks[64][72];
    __shared__ __align__(16) u16 Vt[64][72];
    __shared__ __align__(16) u16 Ps[4][16][72];

    const int sr = tid >> 2, scc = (tid & 3) * 16;
    {
        const u16* qp = Q + ((long)b * T_N + qt0 + sr) * qld + h * 64 + scc;
        *(s16x8*)&Qs[sr][scc]     = *(const s16x8*)qp;
        *(s16x8*)&Qs[sr][scc + 8] = *(const s16x8*)(qp + 8);
    }
    float m_i[4] = {-1e30f, -1e30f, -1e30f, -1e30f};
    float l_i[4] = {0.f, 0.f, 0.f, 0.f};
    f32x4 o_acc[4] = {};

    int vl = 0, kend;
    if (CAUSAL) kend = qt0 + 64;
    else { vl = valid_len[b]; kend = (vl + 63) & ~63; }

    for (int kv0 = 0; kv0 < kend; kv0 += 64) {
        __syncthreads();
        {
            const u16* kp = Kg + ((long)b * T_N + kv0 + sr) * kld + h * 64 + scc;
            *(s16x8*)&Ks[sr][scc]     = *(const s16x8*)kp;
            *(s16x8*)&Ks[sr][scc + 8] = *(const s16x8*)(kp + 8);
            const u16* vp = Vg + ((long)b * T_N + kv0 + sr) * vld + h * 64 + scc;
            s16x8 v0 = *(const s16x8*)vp;
            s16x8 v1 = *(const s16x8*)(vp + 8);
            #pragma unroll
            for (int j = 0; j < 8; j++) {
                Vt[scc + j][sr]     = (u16)v0[j];
                Vt[scc + 8 + j][sr] = (u16)v1[j];
            }
        }
        __syncthreads();
        f32x4 sc[4] = {};
        #pragma unroll
        for (int kk = 0; kk < 64; kk += 32) {
            s16x8 aq = *(const s16x8*)&Qs[wave*16 + l16][kk + quad*8];
            #pragma unroll
            for (int j = 0; j < 4; j++) {
                s16x8 bk = *(const s16x8*)&Ks[j*16 + l16][kk + quad*8];
                sc[j] = mfma16(aq, bk, sc[j]);
            }
        }
        const int qrow = qt0 + wave*16 + quad*4;
        #pragma unroll
        for (int j = 0; j < 4; j++) {
            int kcol = kv0 + j*16 + l16;
            #pragma unroll
            for (int r = 0; r < 4; r++) {
                float s = sc[j][r] * 0.125f;
                bool ok = CAUSAL ? (kcol <= qrow + r) : (kcol < vl);
                sc[j][r] = ok ? s : -1e30f;
            }
        }
        float alpha[4];
        #pragma unroll
        for (int r = 0; r < 4; r++) {
            float mx = fmaxf(fmaxf(sc[0][r], sc[1][r]), fmaxf(sc[2][r], sc[3][r]));
            #pragma unroll
            for (int d = 1; d < 16; d <<= 1) mx = fmaxf(mx, __shfl_xor(mx, d, 64));
            float mn = fmaxf(m_i[r], mx);
            alpha[r] = __expf(m_i[r] - mn);
            m_i[r] = mn;
        }
        float rsum[4] = {0.f, 0.f, 0.f, 0.f};
        #pragma unroll
        for (int j = 0; j < 4; j++)
            #pragma unroll
            for (int r = 0; r < 4; r++) {
                float pv = __expf(sc[j][r] - m_i[r]);
                sc[j][r] = pv;
                rsum[r] += pv;
            }
        #pragma unroll
        for (int r = 0; r < 4; r++) {
            #pragma unroll
            for (int d = 1; d < 16; d <<= 1) rsum[r] += __shfl_xor(rsum[r], d, 64);
            l_i[r] = l_i[r] * alpha[r] + rsum[r];
        }
        #pragma unroll
        for (int j = 0; j < 4; j++)
            #pragma unroll
            for (int r = 0; r < 4; r++)
                Ps[wave][quad*4 + r][j*16 + l16] = f2bf(sc[j][r]);
        #pragma unroll
        for (int j2 = 0; j2 < 4; j2++)
            #pragma unroll
            for (int r = 0; r < 4; r++)
                o_acc[j2][r] *= alpha[r];
        __syncthreads();
        #pragma unroll
        for (int kk = 0; kk < 64; kk += 32) {
            s16x8 ap = *(const s16x8*)&Ps[wave][l16][kk + quad*8];
            #pragma unroll
            for (int j2 = 0; j2 < 4; j2++) {
                s16x8 bv = *(const s16x8*)&Vt[j2*16 + l16][kk + quad*8];
                o_acc[j2] = mfma16(ap, bv, o_acc[j2]);
            }
        }
    }
    #pragma unroll
    for (int j2 = 0; j2 < 4; j2++) {
        #pragma unroll
        for (int r = 0; r < 4; r++) {
            float v = o_acc[j2][r] / l_i[r];
            long row = (long)b * T_N + qt0 + wave*16 + quad*4 + r;
            O[row * 1024 + h*64 + j2*16 + l16] = f2bf(v);
        }
    }
}

// ---------------------------------------------------------------- ssc[b,t,s] = qs.ks/32 (masked)
__global__ __launch_bounds__(256) void ssc_kernel(
    const u16* __restrict__ qs, const u16* __restrict__ ks,
    const int* __restrict__ svl, float* __restrict__ ssc, int qld)
{
    const int t = blockIdx.x, b = blockIdx.y;
    const int wave = threadIdx.x >> 6, lane = threadIdx.x & 63;
    const u16* qrow = qs + ((long)b * T_N + t) * qld + lane * 16;
    const int vl = svl[b];
    for (int s = wave; s < 16; s += 4) {
        const u16* krow = ks + ((long)b * 16 + s) * 1024 + lane * 16;
        float acc = 0.f;
        #pragma unroll
        for (int seg = 0; seg < 2; seg++) {
            s16x8 qv = *(const s16x8*)(qrow + seg*8);
            s16x8 kv = *(const s16x8*)(krow + seg*8);
            #pragma unroll
            for (int j = 0; j < 8; j++) acc += bf2f((u16)qv[j]) * bf2f((u16)kv[j]);
        }
        #pragma unroll
        for (int d = 1; d < 64; d <<= 1) acc += __shfl_xor(acc, d, 64);
        if (lane == 0)
            ssc[((long)b * T_N + t) * 16 + s] = (s < vl) ? acc * (1.f/32.f) : NEGV;
    }
}

// ---------------------------------------------------------------- top-8 stats, top-16 tokens, sparse combine
__global__ __launch_bounds__(256) void select_combine_kernel(
    const float* __restrict__ ssc, const float* __restrict__ tsc,
    const u16* __restrict__ vv, u16* __restrict__ out, int t0, int vld)
{
    const int tl = blockIdx.x, b = blockIdx.y;
    const int tg = t0 + tl;
    const int tid = threadIdx.x;
    const int wave = tid >> 6, lane = tid & 63;
    __shared__ float coeff[128];
    __shared__ long  rowoff[128];
    __shared__ int   sel_s[8];
    __shared__ float sel_w[8];

    if (wave == 0) {
        float cur = (lane < 16) ? ssc[((long)b * T_N + tg) * 16 + lane] : -3e38f;
        float mx0 = 0.f, ssum = 0.f, myv = -3e38f;
        int myi = 0;
        #pragma unroll
        for (int it = 0; it < 8; it++) {
            float mv = cur; int mi = lane;
            #pragma unroll
            for (int d = 1; d < 64; d <<= 1) {
                float ov = __shfl_xor(mv, d, 64);
                int   oi = __shfl_xor(mi, d, 64);
                if (ov > mv || (ov == mv && oi < mi)) { mv = ov; mi = oi; }
            }
            if (it == 0) mx0 = mv;
            ssum += __expf(mv - mx0);
            if (lane == it) { myv = mv; myi = mi; }
            if (lane == mi) cur = -3e38f;
        }
        if (lane < 8) { sel_s[lane] = myi; sel_w[lane] = __expf(myv - mx0) / ssum; }
    }
    __syncthreads();

    for (int slot = wave; slot < 8; slot += 4) {
        int s = sel_s[slot];
        float sw = sel_w[slot];
        const float* trow = tsc + (((long)b * 16 + s) * 512 + tl) * 256;
        float4 lv4 = *(const float4*)(trow + lane * 4);
        float loc[4] = { lv4.x, lv4.y, lv4.z, lv4.w };
        float mx0 = 0.f, tsum = 0.f, myv = -3e38f;
        int myi = 0;
        for (int it = 0; it < 16; it++) {
            float mv = -3e38f; int mi = 0;
            #pragma unroll
            for (int u = 0; u < 4; u++)
                if (loc[u] > mv) { mv = loc[u]; mi = lane*4 + u; }
            #pragma unroll
            for (int d = 1; d < 64; d <<= 1) {
                float ov = __shfl_xor(mv, d, 64);
                int   oi = __shfl_xor(mi, d, 64);
                if (ov > mv || (ov == mv && oi < mi)) { mv = ov; mi = oi; }
            }
            if (it == 0) mx0 = mv * (1.f/32.f);
            tsum += __expf(mv * (1.f/32.f) - mx0);
            if (lane == it) { myv = mv; myi = mi; }
            if ((mi >> 2) == lane) {
                int u = mi & 3;
                if (u == 0) loc[0] = -3e38f;
                else if (u == 1) loc[1] = -3e38f;
                else if (u == 2) loc[2] = -3e38f;
                else loc[3] = -3e38f;
            }
        }
        if (lane < 16) {
            coeff[slot * 16 + lane]  = sw * __expf(myv * (1.f/32.f) - mx0) / tsum;
            rowoff[slot * 16 + lane] = (long)((b * 16 + s) * 256 + myi) * vld;
        }
    }
    __syncthreads();

    const int d0 = tid * 4;
    float a0 = 0.f, a1 = 0.f, a2 = 0.f, a3 = 0.f;
    for (int r = 0; r < 128; r++) {
        float c = coeff[r];
        const u16* vp = vv + rowoff[r] + d0;
        u16x4 v4 = *(const u16x4*)vp;
        a0 += c * bf2f(v4[0]);
        a1 += c * bf2f(v4[1]);
        a2 += c * bf2f(v4[2]);
        a3 += c * bf2f(v4[3]);
    }
    u16x4 o4 = { f2bf(a0), f2bf(a1), f2bf(a2), f2bf(a3) };
    *(u16x4*)(out + ((long)b * T_N + tg) * 1024 + d0) = o4;
}

// ---------------------------------------------------------------- LN kernels
__device__ __forceinline__ float block_sum(float v, float* red) {
    #pragma unroll
    for (int d = 1; d < 64; d <<= 1) v += __shfl_xor(v, d, 64);
    __syncthreads();
    if ((threadIdx.x & 63) == 0) red[threadIdx.x >> 6] = v;
    __syncthreads();
    return red[0] + red[1] + red[2] + red[3];
}

__global__ __launch_bounds__(256) void ln1_kernel(
    const float* __restrict__ x, const float* __restrict__ x2,
    const float* __restrict__ intent, const float* __restrict__ g, const float* __restrict__ be,
    u16* __restrict__ yi)
{
    __shared__ float red[4];
    const long row = blockIdx.x;
    const int tid = threadIdx.x;
    const long base = row * 1024 + tid * 4;
    float4 xv = *(const float4*)(x + base);
    float4 dv = *(const float4*)(x2 + base);
    float h0 = xv.x + dv.x, h1 = xv.y + dv.y, h2 = xv.z + dv.z, h3 = xv.w + dv.w;
    float s1 = block_sum(h0 + h1 + h2 + h3, red);
    float s2 = block_sum(h0*h0 + h1*h1 + h2*h2 + h3*h3, red);
    float mean = s1 * (1.f/1024.f);
    float var = s2 * (1.f/1024.f) - mean * mean;
    float inv = rsqrtf(var + 1e-5f);
    const int c = tid * 4;
    float4 gv = *(const float4*)(g + c);
    float4 bv = *(const float4*)(be + c);
    float o0 = (h0 - mean) * inv * gv.x + bv.x;
    float o1 = (h1 - mean) * inv * gv.y + bv.y;
    float o2 = (h2 - mean) * inv * gv.z + bv.z;
    float o3 = (h3 - mean) * inv * gv.w + bv.w;
    u16x4 ob = { f2bf(o0), f2bf(o1), f2bf(o2), f2bf(o3) };
    *(u16x4*)(yi + row * 1280 + c) = ob;
    const int b = (int)(row >> 10);
    yi[row * 1280 + 1024 + tid] = f2bf(intent[b * 256 + tid]);
}

__global__ __launch_bounds__(256) void gate_ln2_kernel(
    const u16* __restrict__ yi, const float* __restrict__ y2s, const float* __restrict__ y2e,
    const float* __restrict__ Wg, const float* __restrict__ g, const float* __restrict__ be,
    float* __restrict__ z, u16* __restrict__ zbf)
{
    __shared__ float red[4];
    const long row = blockIdx.x;
    const int tid = threadIdx.x;
    const long base = row * 1024 + tid * 4;
    const int c = tid * 4;
    float4 sv = *(const float4*)(y2s + base);
    float4 ev = *(const float4*)(y2e + base);
    float4 w1 = *(const float4*)(Wg + c);
    float4 w2 = *(const float4*)(Wg + 1024 + c);
    float dot = sv.x*w1.x + sv.y*w1.y + sv.z*w1.z + sv.w*w1.w
              + ev.x*w2.x + ev.y*w2.y + ev.z*w2.z + ev.w*w2.w;
    float tot = block_sum(dot, red);
    float gate = 1.f / (1.f + __expf(-tot));
    u16x4 yv4 = *(const u16x4*)(yi + row * 1280 + c);
    float h0 = bf2f(yv4[0]) + 2.f * (gate * sv.x + (1.f - gate) * ev.x);
    float h1 = bf2f(yv4[1]) + 2.f * (gate * sv.y + (1.f - gate) * ev.y);
    float h2 = bf2f(yv4[2]) + 2.f * (gate * sv.z + (1.f - gate) * ev.z);
    float h3 = bf2f(yv4[3]) + 2.f * (gate * sv.w + (1.f - gate) * ev.w);
    float s1 = block_sum(h0 + h1 + h2 + h3, red);
    float s2 = block_sum(h0*h0 + h1*h1 + h2*h2 + h3*h3, red);
    float mean = s1 * (1.f/1024.f);
    float var = s2 * (1.f/1024.f) - mean * mean;
    float inv = rsqrtf(var + 1e-5f);
    float4 gv = *(const float4*)(g + c);
    float4 bv = *(const float4*)(be + c);
    float o0 = (h0 - mean) * inv * gv.x + bv.x;
    float o1 = (h1 - mean) * inv * gv.y + bv.y;
    float o2 = (h2 - mean) * inv * gv.z + bv.z;
    float o3 = (h3 - mean) * inv * gv.w + bv.w;
    *(float4*)(z + base) = make_float4(o0, o1, o2, o3);
    u16x4 ob = { f2bf(o0), f2bf(o1), f2bf(o2), f2bf(o3) };
    *(u16x4*)(zbf + row * 1024 + c) = ob;
}

// final LN over z + (p0 + p1 + b2)  — FFN2 split-K partials fused here
__global__ __launch_bounds__(256) void ln3_kernel(
    const float* __restrict__ z, const float* __restrict__ p0, const float* __restrict__ p1,
    const float* __restrict__ b2,
    const float* __restrict__ g, const float* __restrict__ be, float* __restrict__ out)
{
    __shared__ float red[4];
    const long row = blockIdx.x;
    const int tid = threadIdx.x;
    const long base = row * 1024 + tid * 4;
    const int c = tid * 4;
    float4 zv = *(const float4*)(z + base);
    float4 f0 = *(const float4*)(p0 + base);
    float4 f1 = *(const float4*)(p1 + base);
    float4 bb = *(const float4*)(b2 + c);
    float h0 = zv.x + f0.x + f1.x + bb.x;
    float h1 = zv.y + f0.y + f1.y + bb.y;
    float h2 = zv.z + f0.z + f1.z + bb.z;
    float h3 = zv.w + f0.w + f1.w + bb.w;
    float s1 = block_sum(h0 + h1 + h2 + h3, red);
    float s2 = block_sum(h0*h0 + h1*h1 + h2*h2 + h3*h3, red);
    float mean = s1 * (1.f/1024.f);
    float var = s2 * (1.f/1024.f) - mean * mean;
    float inv = rsqrtf(var + 1e-5f);
    float4 gv = *(const float4*)(g + c);
    float4 bv = *(const float4*)(be + c);
    float o0 = (h0 - mean) * inv * gv.x + bv.x;
    float o1 = (h1 - mean) * inv * gv.y + bv.y;
    float o2 = (h2 - mean) * inv * gv.z + bv.z;
    float o3 = (h3 - mean) * inv * gv.w + bv.w;
    *(float4*)(out + base) = make_float4(o0, o1, o2, o3);
}

// ---------------------------------------------------------------- host
extern "C" void kernel_launch(void* const* d_in, const int* in_sizes, int n_in,
                              void* d_out, int out_size, void* d_ws, size_t ws_size,
                              hipStream_t stream)
{
    (void)in_sizes; (void)n_in; (void)out_size; (void)ws_size;
    const float* x      = (const float*)d_in[0];
    const float* stat_e = (const float*)d_in[1];
    const float* exem   = (const float*)d_in[2];
    const float* sfeat  = (const float*)d_in[3];
    const float* intent = (const float*)d_in[4];
    const float* Wg  = (const float*)d_in[19];
    const float* b1  = (const float*)d_in[21];
    const float* b2  = (const float*)d_in[23];
    const float* g1  = (const float*)d_in[24]; const float* be1 = (const float*)d_in[25];
    const float* g2  = (const float*)d_in[26]; const float* be2 = (const float*)d_in[27];
    const float* g3  = (const float*)d_in[28]; const float* be3 = (const float*)d_in[29];
    const int* svl = (const int*)d_in[30];
    const int* evl = (const int*)d_in[31];
    float* outp = (float*)d_out;

    // ---- workspace plan: 171 MB, lifetime-aliased ----
    char* base = (char*)d_ws;
    u16*  bufA  = (u16*)(base + 0*MB);        // 8MB: xbf / attn-outs / y2s_pre
    u16*  qkv1  = (u16*)(base + 8*MB);        // 24MB fused [4096,3072] (phase 3)
    float* x2a  = (float*)(base + 8*MB);      // 16MB (after flash1)
    u16*  kv2   = (u16*)(base + 8*MB);        // 16MB fused [4096,2048] (phase 5)
    u16*  w1t   = (u16*)(base + 8*MB);        // 8MB (phase 7)
    u16*  w2t   = (u16*)(base + 16*MB);       // 8MB (phase 7)
    u16*  yibf  = (u16*)(base + 32*MB);       // 10MB [4096,1280]
    u16*  buf3  = (u16*)(base + 42*MB);       // 24MB fused qs|qt|q2 [4096,3072]
    u16*  zbf   = (u16*)(base + 42*MB);       // 8MB (after flash2)
    u16*  sebf  = (u16*)(base + 66*MB);       // 32MB stat_enc bf16 / tsc-half fp32 / ffn hidden
    float* tsch = (float*)(base + 66*MB);
    u16*  hid   = (u16*)(base + 66*MB);
    u16*  ktvv  = (u16*)(base + 98*MB);       // 64MB fused [16384,2048]
    float* y2sf = (float*)(base + 98*MB);     // 16MB (after select)
    float* p0f  = (float*)(base + 98*MB);     // 32MB FFN2 partials (after gate_ln2; y2ef dead)
    u16*  exbf  = (u16*)(base + 114*MB);      // 8MB
    float* y2ef = (float*)(base + 122*MB);    // 16MB
    float* zf   = (float*)(base + 138*MB);    // 16MB
    u16*  sfbf  = (u16*)(base + 162*MB);                  // 128KB
    u16*  ksbf  = (u16*)(base + 162*MB + 256*1024);       // 128KB
    float* sscf = (float*)(base + 162*MB + 512*1024);     // 256KB
    char* wpool = base + 163*MB;              // 8MB rotating weight pool (total 171MB)

    dim3 blk(256);
    dim3 blk512(512);
    auto cast = [&](const float* s, u16* d, long n) {
        cast_bf16_kernel<<<dim3((unsigned)((n/4 + 255) / 256)), blk, 0, stream>>>(s, d, n);
    };
    auto g_n = [&](const u16* A, const u16* Bt, u16* C, int M, int N, int K,
                   int lda, int ldb, int ldc) {
        gemm_bt<u16,false,false><<<dim3(N/128, (M+127)/128, 1), blk, 0, stream>>>(
            A, Bt, C, nullptr, M, N, K, lda, ldb, ldc, 1, 0, 0, 0);
    };
    auto g_f = [&](const u16* A, const u16* Bt, float* C, int M, int N, int K,
                   int lda, int ldb, int ldc) {
        gemm_bt<float,false,false><<<dim3(N/128, (M+127)/128, 1), blk, 0, stream>>>(
            A, Bt, C, nullptr, M, N, K, lda, ldb, ldc, 1, 0, 0, 0);
    };
    // 256^2 deep-pipelined GEMM — M,N multiples of 256, grid must fill >=192 CUs
    auto g256_n = [&](const u16* A, const u16* Bt, u16* C, int M, int N, int K,
                      int lda, int ldb, int ldc) {
        gemm_bt256<u16,false,false><<<dim3(N/256, M/256, 1), blk512, 0, stream>>>(
            A, Bt, C, nullptr, M, N, K, lda, ldb, ldc, 1, 0, 0, 0);
    };

    // ---- phase 3: self-attention ----
    u16* wqkv1t = (u16*)wpool;                       // [3072,1024] stacked
    u16* wo1t   = (u16*)(wpool) + 3L*1024*1024;
    {
        P6 pp{};
        pp.s[0]=(const float*)d_in[5]; pp.d[0]=wqkv1t;
        pp.s[1]=(const float*)d_in[6]; pp.d[1]=wqkv1t + 1L*1024*1024;
        pp.s[2]=(const float*)d_in[7]; pp.d[2]=wqkv1t + 2L*1024*1024;
        pp.s[3]=(const float*)d_in[8]; pp.d[3]=wo1t;
        transpose_cast_batch<<<dim3(32, 32, 4), blk, 0, stream>>>(pp, 1024, 1024);
    }
    cast(x, bufA, 4096L*1024);
    g256_n(bufA, wqkv1t, qkv1, 4096, 3072, 1024, 1024, 1024, 3072);
    flash_attn_kernel<true><<<dim3(16, 16, 4), blk, 0, stream>>>(
        qkv1, qkv1 + 1024, qkv1 + 2048, nullptr, bufA, 3072, 3072, 3072);
    g_f(bufA, wo1t, x2a, 4096, 1024, 1024, 1024, 1024, 1024);
    ln1_kernel<<<dim3(4096), blk, 0, stream>>>(x, x2a, intent, g1, be1, yibf);

    // ---- phase 4: selective hierarchical attention ----
    u16* wq3t = (u16*)wpool;
    {
        P6 pp{};
        pp.s[0]=(const float*)d_in[9];  pp.d[0]=wq3t;
        pp.s[1]=(const float*)d_in[10]; pp.d[1]=wq3t + 1L*1024*1280;
        pp.s[2]=(const float*)d_in[15]; pp.d[2]=wq3t + 2L*1024*1280;
        transpose_cast_batch<<<dim3(32, 40, 3), blk, 0, stream>>>(pp, 1280, 1024);
    }
    g256_n(yibf, wq3t, buf3, 4096, 3072, 1280, 1280, 1280, 3072);   // qs|qt|q2
    u16* wkst = (u16*)wpool;
    u16* wkv  = (u16*)(wpool) + 1L*1024*1024;
    {
        P6 pp{};
        pp.s[0]=(const float*)d_in[11]; pp.d[0]=wkst;
        pp.s[1]=(const float*)d_in[12]; pp.d[1]=wkv;
        pp.s[2]=(const float*)d_in[13]; pp.d[2]=wkv + 1L*1024*1024;
        transpose_cast_batch<<<dim3(32, 32, 3), blk, 0, stream>>>(pp, 1024, 1024);
    }
    cast(sfeat, sfbf, 64L*1024);
    cast(stat_e, sebf, 16384L*1024);
    g_n(sfbf, wkst, ksbf, 64, 1024, 1024, 1024, 1024, 1024);
    g256_n(sebf, wkv, ktvv, 16384, 2048, 1024, 1024, 1024, 2048);   // kt|vv
    ssc_kernel<<<dim3(1024, 4), blk, 0, stream>>>(buf3, ksbf, svl, sscf, 3072);
    for (int hh = 0; hh < 2; hh++) {
        long t0 = hh * 512;
        gemm_bt<float,false,false><<<dim3(2, 4, 64), blk, 0, stream>>>(
            buf3 + 1024 + t0*3072, ktvv, tsch, nullptr, 512, 256, 1024,
            3072, 2048, 256, 16, (long)T_N*3072, 256L*2048, 512L*256);
        select_combine_kernel<<<dim3(512, 4), blk, 0, stream>>>(
            sscf, tsch, ktvv + 1024, bufA, (int)t0, 2048);
    }
    u16* wost = (u16*)wpool;
    u16* wkv2 = (u16*)(wpool) + 1L*1024*1024;
    u16* wo2t = (u16*)(wpool) + 3L*1024*1024;
    {
        P6 pp{};
        pp.s[0]=(const float*)d_in[14]; pp.d[0]=wost;
        pp.s[1]=(const float*)d_in[16]; pp.d[1]=wkv2;
        pp.s[2]=(const float*)d_in[17]; pp.d[2]=wkv2 + 1L*1024*1024;
        pp.s[3]=(const float*)d_in[18]; pp.d[3]=wo2t;
        transpose_cast_batch<<<dim3(32, 32, 4), blk, 0, stream>>>(pp, 1024, 1024);
    }
    g_f(bufA, wost, y2sf, 4096, 1024, 1024, 1024, 1024, 1024);

    // ---- phase 5: exemplar cross-attention ----
    cast(exem, exbf, 4096L*1024);
    g_n(exbf, wkv2, kv2, 4096, 2048, 1024, 1024, 1024, 2048);       // k2|v2 (128^2: 512 blocks)
    flash_attn_kernel<false><<<dim3(16, 16, 4), blk, 0, stream>>>(
        buf3 + 2048, kv2, kv2 + 1024, evl, bufA, 3072, 2048, 2048);
    g_f(bufA, wo2t, y2ef, 4096, 1024, 1024, 1024, 1024, 1024);

    // ---- phase 6: gate + LN2 ----
    gate_ln2_kernel<<<dim3(4096), blk, 0, stream>>>(yibf, y2sf, y2ef, Wg, g2, be2, zf, zbf);

    // ---- phase 7: FFN ----
    {
        P6 pp{}; pp.s[0] = (const float*)d_in[20]; pp.d[0] = w1t;
        transpose_cast_batch<<<dim3(128, 32, 1), blk, 0, stream>>>(pp, 1024, 4096);
    }
    {
        P6 pp{}; pp.s[0] = (const float*)d_in[22]; pp.d[0] = w2t;
        transpose_cast_batch<<<dim3(32, 128, 1), blk, 0, stream>>>(pp, 4096, 1024);
    }
    gemm_bt256<u16,true,true><<<dim3(16, 16, 1), blk512, 0, stream>>>(
        zbf, w1t, hid, b1, 4096, 4096, 1024, 1024, 1024, 4096, 1, 0, 0, 0);
    // FFN2 split-K x2 in one dispatch (z picks K-half): p[z] = hid[:,z*2048:] @ w2t[:,z*2048:]^T
    // 128^2 path: 512 blocks (256^2 grid would be 128 blocks -> half the CUs idle)
    gemm_bt<float,false,false><<<dim3(8, 32, 2), blk, 0, stream>>>(
        hid, w2t, p0f, nullptr, 4096, 1024, 2048, 4096, 4096, 1024,
        1, 2048, 2048, 4096L*1024);

    // ---- phase 8: final LN (fuses p0+p1+b2) ----
    ln3_kernel<<<dim3(4096), blk, 0, stream>>>(zf, p0f, p0f + 4096L*1024, b2, g3, be3, outp);
}

// Round 4
// 987.994 us; speedup vs baseline: 1.0722x; 1.0176x over previous
//
#include <hip/hip_runtime.h>

typedef unsigned short u16;
typedef short s16x8 __attribute__((ext_vector_type(8)));
typedef u16 u16x4 __attribute__((ext_vector_type(4)));
typedef float f32x4 __attribute__((ext_vector_type(4)));

#define T_N   1024
#define NEGV  -1e6f
#define MB    (1L << 20)

__device__ __forceinline__ u16 f2bf(float f) {
    unsigned u = __float_as_uint(f);
    u += 0x7fffu + ((u >> 16) & 1u);     // RNE
    return (u16)(u >> 16);
}
__device__ __forceinline__ float bf2f(u16 h) {
    return __uint_as_float(((unsigned)h) << 16);
}
__device__ __forceinline__ f32x4 mfma16(s16x8 a, s16x8 b, f32x4 c) {
    return __builtin_amdgcn_mfma_f32_16x16x32_bf16(a, b, c, 0, 0, 0);
}
// async global->LDS, 16B per lane; LDS dest = wave-uniform base + lane*16 (m97/m104)
__device__ __forceinline__ void gll16(const u16* g, u16* l) {
    __builtin_amdgcn_global_load_lds((const __attribute__((address_space(1))) void*)g,
                                     (__attribute__((address_space(3))) void*)l, 16, 0, 0);
}
// 3-bit row-derived chunk swizzle for [.][64] u16 LDS arrays (stride 64 elems
// = 32 dwords == 0 mod 32 banks, so the XOR field must carry all of row&7).
__device__ __forceinline__ int swzf(int row) {
    return ((row >> 1) & 3) | ((row & 1) << 2);
}
__device__ __forceinline__ int swzc(int col, int row) {
    return (((col >> 3) ^ swzf(row)) << 3) | (col & 7);
}

// ---------------------------------------------------------------- transpose+cast
struct P6 { const float* s[6]; u16* d[6]; };

__global__ __launch_bounds__(256) void transpose_cast_batch(P6 pp, int K, int N) {
    const float* __restrict__ src = pp.s[blockIdx.z];
    u16* __restrict__ dst = pp.d[blockIdx.z];
    __shared__ float tile[32][33];
    int nb = blockIdx.x * 32, kb = blockIdx.y * 32;
    int tx = threadIdx.x & 31, ty = threadIdx.x >> 5;   // ty 0..7
    #pragma unroll
    for (int i = 0; i < 4; i++)
        tile[ty + 8*i][tx] = src[(long)(kb + ty + 8*i) * N + nb + tx];
    __syncthreads();
    #pragma unroll
    for (int i = 0; i < 4; i++)
        dst[(long)(nb + ty + 8*i) * K + kb + tx] = f2bf(tile[tx][ty + 8*i]);
}

__global__ __launch_bounds__(256) void cast_bf16_kernel(const float* __restrict__ src,
                                                        u16* __restrict__ dst, long n) {
    long i = ((long)blockIdx.x * 256 + threadIdx.x) * 4;
    if (i >= n) return;
    float4 v = *(const float4*)(src + i);
    u16x4 o = { f2bf(v.x), f2bf(v.y), f2bf(v.z), f2bf(v.w) };
    *(u16x4*)(dst + i) = o;
}

// ---------------------------------------------------------------- GEMM: C[M,N] = A[M,K] * Bt[N,K]^T
// 128x128-tile fallback kernel (m97 structure) — for shapes whose 256^2 grid
// would under-fill 256 CUs.
template<typename OutT, bool RELU, bool HAS_BIAS>
__global__ __launch_bounds__(256) void gemm_bt(
    const u16* __restrict__ A, const u16* __restrict__ Bt, OutT* __restrict__ C,
    const float* __restrict__ bias, int M, int N, int K,
    int lda, int ldb, int ldc,
    int batchDivA, long sA, long sB, long sC)
{
    A  += (long)(blockIdx.z / batchDivA) * sA;
    Bt += (long)blockIdx.z * sB;
    C  += (long)blockIdx.z * sC;
    __shared__ __align__(16) u16 As[4096];   // [128][32] row-major, 8 KB
    __shared__ __align__(16) u16 Bs[4096];
    const int tid = threadIdx.x;
    const int wave = tid >> 6, lane = tid & 63;
    const int quad = lane >> 4, l16 = lane & 15;
    const int wr = (wave >> 1) * 64, wc = (wave & 1) * 64;
    const long row0 = (long)blockIdx.y * 128, col0 = (long)blockIdx.x * 128;

    f32x4 acc[4][4] = {};

    const int l4r = lane >> 2;
    const int l4c = (lane & 3) * 8;
    const int ra = wave * 32 + l4r;
    const u16* Ap0 = A + (row0 + ra) * (long)lda + l4c;
    const u16* Ap1 = Ap0 + 16L * lda;
    const u16* Bp0 = Bt + (col0 + ra) * (long)ldb + l4c;
    const u16* Bp1 = Bp0 + 16L * ldb;
    u16* AsW0 = &As[(wave * 32) * 32];
    u16* AsW1 = &As[(wave * 32 + 16) * 32];
    u16* BsW0 = &Bs[(wave * 32) * 32];
    u16* BsW1 = &Bs[(wave * 32 + 16) * 32];
    const bool aok0 = (row0 + wave * 32) < M;
    const bool aok1 = (row0 + wave * 32 + 16) < M;

    for (int k0 = 0; k0 < K; k0 += 32) {
        __syncthreads();
        if (aok0) gll16(Ap0 + k0, AsW0);
        if (aok1) gll16(Ap1 + k0, AsW1);
        gll16(Bp0 + k0, BsW0);
        gll16(Bp1 + k0, BsW1);
        __syncthreads();
        s16x8 af[4], bfr[4];
        #pragma unroll
        for (int i = 0; i < 4; i++)
            af[i]  = *(const s16x8*)&As[(wr + i*16 + l16) * 32 + quad*8];
        #pragma unroll
        for (int j = 0; j < 4; j++)
            bfr[j] = *(const s16x8*)&Bs[(wc + j*16 + l16) * 32 + quad*8];
        #pragma unroll
        for (int i = 0; i < 4; i++)
            #pragma unroll
            for (int j = 0; j < 4; j++)
                acc[i][j] = mfma16(af[i], bfr[j], acc[i][j]);
    }

    #pragma unroll
    for (int i = 0; i < 4; i++) {
        long row = row0 + wr + i*16 + quad*4;
        #pragma unroll
        for (int j = 0; j < 4; j++) {
            long col = col0 + wc + j*16 + l16;
            float bv = 0.f;
            if constexpr (HAS_BIAS) bv = bias[col];
            #pragma unroll
            for (int r = 0; r < 4; r++) {
                if (row + r < M) {
                    float v = acc[i][j][r] + bv;
                    if constexpr (RELU) v = fmaxf(v, 0.f);
                    if constexpr (sizeof(OutT) == 2) C[(row + r) * (long)ldc + col] = f2bf(v);
                    else                             C[(row + r) * (long)ldc + col] = v;
                }
            }
        }
    }
}

// ---------------------------------------------------------------- GEMM 256^2, de-lockstepped pipeline
// (unchanged from round 3 — no longer in the top-5)
template<typename OutT, bool RELU, bool HAS_BIAS>
__global__ __launch_bounds__(512, 2) void gemm_bt256(
    const u16* __restrict__ A, const u16* __restrict__ Bt, OutT* __restrict__ C,
    const float* __restrict__ bias, int M, int N, int K,
    int lda, int ldb, int ldc,
    int batchDivA, long sA, long sB, long sC)
{
    int bx = blockIdx.x, by = blockIdx.y;
    {
        const int nwg = gridDim.x * gridDim.y;
        if ((nwg & 7) == 0) {
            const int flat = by * gridDim.x + bx;
            const int nf = (flat & 7) * (nwg >> 3) + (flat >> 3);
            bx = nf % gridDim.x;
            by = nf / gridDim.x;
        }
    }
    A  += (long)(blockIdx.z / batchDivA) * sA;
    Bt += (long)blockIdx.z * sB;
    C  += (long)blockIdx.z * sC;
    __shared__ __align__(16) u16 As[4][8192];   // [256][32] each, 16 KB x4
    __shared__ __align__(16) u16 Bs[4][8192];
    const int tid = threadIdx.x;
    const int wave = tid >> 6, lane = tid & 63;
    const int quad = lane >> 4, l16 = lane & 15;
    const int wm = wave >> 2, wn = wave & 3;           // 2 x 4 wave grid
    const long row0 = (long)by * 256, col0 = (long)bx * 256;

    const int srow = tid >> 2;
    const int scol = ((tid & 3) ^ ((srow >> 1) & 3)) * 8;
    const u16* Ag = A  + (row0 + srow) * (long)lda + scol;
    const u16* Bg = Bt + (col0 + srow) * (long)ldb + scol;
    const int ldsoff = wave * 512;                      // wave-uniform elem offset

    f32x4 acc[8][4] = {};
    const int NT = K >> 5;

    auto stageA = [&](int kt, int buf) {
        gll16(Ag + (long)kt * 32,            &As[buf][ldsoff]);
        gll16(Ag + (long)kt * 32 + 128L*lda, &As[buf][4096 + ldsoff]);
    };
    auto stageB = [&](int kt, int buf) {
        gll16(Bg + (long)kt * 32,            &Bs[buf][ldsoff]);
        gll16(Bg + (long)kt * 32 + 128L*ldb, &Bs[buf][4096 + ldsoff]);
    };

    stageA(0, 0); stageB(0, 0);
    stageA(1, 1); stageB(1, 1);
    stageA(2, 2); stageB(2, 2);
    asm volatile("s_waitcnt vmcnt(8)" ::: "memory");
    __builtin_amdgcn_s_barrier();
    __builtin_amdgcn_sched_barrier(0);

    const int arow = wm * 128 + l16;
    const int brow = wn * 64  + l16;
    const int kq   = (quad ^ ((l16 >> 1) & 3)) * 8;     // swizzled chunk offset

    for (int kt = 0; kt < NT; ++kt) {
        const int b  = kt & 3;
        const int sb = (kt + 3) & 3;
        const bool st = (kt + 3) < NT;
        const u16* Ab = As[b];
        const u16* Bb = Bs[b];

        s16x8 bfr[4], af[8];
        #pragma unroll
        for (int j = 0; j < 4; ++j)
            bfr[j] = *(const s16x8*)&Bb[(brow + j*16) * 32 + kq];
        #pragma unroll
        for (int i = 0; i < 8; ++i)
            af[i] = *(const s16x8*)&Ab[(arow + i*16) * 32 + kq];

        if (st) { stageA(kt + 3, sb); stageB(kt + 3, sb); }

        #pragma unroll
        for (int i = 0; i < 8; ++i)
            #pragma unroll
            for (int j = 0; j < 4; ++j)
                acc[i][j] = mfma16(af[i], bfr[j], acc[i][j]);

        const int rem = NT - 2 - kt;
        if (rem >= 2)      asm volatile("s_waitcnt vmcnt(8)" ::: "memory");
        else if (rem == 1) asm volatile("s_waitcnt vmcnt(4)" ::: "memory");
        else if (rem == 0) asm volatile("s_waitcnt vmcnt(0)" ::: "memory");
        __builtin_amdgcn_s_barrier();
        __builtin_amdgcn_sched_barrier(0);
    }

    #pragma unroll
    for (int i = 0; i < 8; ++i) {
        const long row = row0 + wm*128 + i*16 + quad*4;
        #pragma unroll
        for (int j = 0; j < 4; ++j) {
            const long col = col0 + wn*64 + j*16 + l16;
            float bv = 0.f;
            if constexpr (HAS_BIAS) bv = bias[col];
            #pragma unroll
            for (int r = 0; r < 4; ++r) {
                float v = acc[i][j][r] + bv;
                if constexpr (RELU) v = fmaxf(v, 0.f);
                if constexpr (sizeof(OutT) == 2) C[(row + r) * (long)ldc + col] = f2bf(v);
                else                             C[(row + r) * (long)ldc + col] = v;
            }
        }
    }
}

// ---------------------------------------------------------------- flash attention (dh=64, H=16)
// Latency-bound fix (round 4): T14 async double-buffer (issue K/V global->reg
// loads BEFORE compute, ds_write AFTER PV -> HBM latency hides under compute),
// ONE barrier per KV tile (was 3; Ps is per-wave private so no barrier needed
// between P-write and PV-read — same-wave DS ops are in-order), Q fragments
// hoisted to registers pre-loop (Qs LDS dropped), stride-64 LDS with 3-bit
// chunk-XOR swizzle (port-minimal frag reads AND staging writes; V-transpose
// writes remapped so each wave-op writes one full 64-col row = conflict-free).
// LDS 40KB -> 4 blocks/CU. setprio(1) around MFMA clusters (m191).
template<bool CAUSAL>
__global__ __launch_bounds__(256, 4) void flash_attn_kernel(
    const u16* __restrict__ Q, const u16* __restrict__ Kg, const u16* __restrict__ Vg,
    const int* __restrict__ valid_len, u16* __restrict__ O,
    int qld, int kld, int vld)
{
    const int h = blockIdx.y, b = blockIdx.z;
    const int qt0 = blockIdx.x * 64;
    const int tid = threadIdx.x;
    const int wave = tid >> 6, lane = tid & 63;
    const int quad = lane >> 4, l16 = lane & 15;

    __shared__ __align__(16) u16 Ks[2][64][64];   // 16 KB
    __shared__ __align__(16) u16 Vt[2][64][64];   // 16 KB (V transposed: [d][kv])
    __shared__ __align__(16) u16 Ps[4][16][64];   // 8 KB (per-wave private)

    // Q fragments in registers: A[l16][quad*8 + e] for kk-halves 0,32
    s16x8 aq[2];
    {
        const u16* qp = Q + ((long)b * T_N + qt0 + wave*16 + l16) * qld + h * 64 + quad * 8;
        aq[0] = *(const s16x8*)qp;
        aq[1] = *(const s16x8*)(qp + 32);
    }

    // staging geometry
    const int ksr = tid >> 2;          // K row 0..63 (4 thr/row)
    const int ks2 = (tid & 3) * 2;     // K chunk pair (16 elems/thread)
    const int vsr = tid & 63;          // V kv-row = Vt column (per-wave: all 64)
    const int vd0 = (tid >> 6) * 16;   // Vt row base (d-offset, wave-const)

    const u16* kp = Kg + ((long)b * T_N + ksr) * (long)kld + h * 64 + ks2 * 8;
    const u16* vp = Vg + ((long)b * T_N + vsr) * (long)vld + h * 64 + vd0;
    const long kstep = 64L * kld, vstep = 64L * vld;

    // lane-constant swizzle pieces
    const int fl  = swzf(l16);
    const int kc0 = ((quad ^ fl) & 7) * 8;          // chunk quad,   kk=0
    const int kc1 = (((quad + 4) ^ fl) & 7) * 8;    // chunk quad+4, kk=32

    float m_i[4] = {-1e30f, -1e30f, -1e30f, -1e30f};
    float l_i[4] = {0.f, 0.f, 0.f, 0.f};
    f32x4 o_acc[4] = {};

    int vl = 0, kend;
    if (CAUSAL) kend = qt0 + 64;
    else { vl = valid_len[b]; kend = (vl + 63) & ~63; }
    const int nt = kend >> 6;

    // ---- prologue: load tile 0 to regs, write LDS buf 0 ----
    s16x8 krA, krB, vrA, vrB;
    krA = *(const s16x8*)kp;       krB = *(const s16x8*)(kp + 8);
    vrA = *(const s16x8*)vp;       vrB = *(const s16x8*)(vp + 8);
    kp += kstep; vp += vstep;
    {
        *(s16x8*)&Ks[0][ksr][swzc(ks2*8,     ksr)] = krA;
        *(s16x8*)&Ks[0][ksr][swzc(ks2*8 + 8, ksr)] = krB;
        #pragma unroll
        for (int j = 0; j < 8; ++j) {
            Vt[0][vd0 + j    ][swzc(vsr, vd0 + j    )] = (u16)vrA[j];
            Vt[0][vd0 + 8 + j][swzc(vsr, vd0 + 8 + j)] = (u16)vrB[j];
        }
    }
    __syncthreads();

    for (int t = 0; t < nt; ++t) {
        const int cur = t & 1;
        const bool more = (t + 1) < nt;
        // issue next-tile loads early (latency hides under compute below)
        if (more) {
            krA = *(const s16x8*)kp;  krB = *(const s16x8*)(kp + 8);
            vrA = *(const s16x8*)vp;  vrB = *(const s16x8*)(vp + 8);
            kp += kstep; vp += vstep;
        }
        // ---- QK^T ----
        f32x4 sc[4] = {};
        __builtin_amdgcn_s_setprio(1);
        #pragma unroll
        for (int j = 0; j < 4; ++j) {
            s16x8 bk0 = *(const s16x8*)&Ks[cur][j*16 + l16][kc0];
            sc[j] = mfma16(aq[0], bk0, sc[j]);
        }
        #pragma unroll
        for (int j = 0; j < 4; ++j) {
            s16x8 bk1 = *(const s16x8*)&Ks[cur][j*16 + l16][kc1];
            sc[j] = mfma16(aq[1], bk1, sc[j]);
        }
        __builtin_amdgcn_s_setprio(0);
        // ---- mask + online softmax ----
        const int kv0 = t * 64;
        const int qrow = qt0 + wave*16 + quad*4;
        #pragma unroll
        for (int j = 0; j < 4; ++j) {
            int kcol = kv0 + j*16 + l16;
            #pragma unroll
            for (int r = 0; r < 4; ++r) {
                float s = sc[j][r] * 0.125f;
                bool ok = CAUSAL ? (kcol <= qrow + r) : (kcol < vl);
                sc[j][r] = ok ? s : -1e30f;
            }
        }
        float alpha[4];
        #pragma unroll
        for (int r = 0; r < 4; ++r) {
            float mx = fmaxf(fmaxf(sc[0][r], sc[1][r]), fmaxf(sc[2][r], sc[3][r]));
            #pragma unroll
            for (int d = 1; d < 16; d <<= 1) mx = fmaxf(mx, __shfl_xor(mx, d, 64));
            float mn = fmaxf(m_i[r], mx);
            alpha[r] = __expf(m_i[r] - mn);
            m_i[r] = mn;
        }
        float rsum[4] = {0.f, 0.f, 0.f, 0.f};
        #pragma unroll
        for (int j = 0; j < 4; ++j)
            #pragma unroll
            for (int r = 0; r < 4; ++r) {
                float pv = __expf(sc[j][r] - m_i[r]);
                sc[j][r] = pv;
                rsum[r] += pv;
            }
        #pragma unroll
        for (int r = 0; r < 4; ++r) {
            #pragma unroll
            for (int d = 1; d < 16; d <<= 1) rsum[r] += __shfl_xor(rsum[r], d, 64);
            l_i[r] = l_i[r] * alpha[r] + rsum[r];
        }
        // ---- P -> LDS (per-wave private slice; no barrier needed) ----
        #pragma unroll
        for (int j = 0; j < 4; ++j)
            #pragma unroll
            for (int r = 0; r < 4; ++r)
                Ps[wave][quad*4 + r][swzc(j*16 + l16, quad*4 + r)] = f2bf(sc[j][r]);
        #pragma unroll
        for (int j2 = 0; j2 < 4; ++j2)
            #pragma unroll
            for (int r = 0; r < 4; ++r)
                o_acc[j2][r] *= alpha[r];
        // ---- PV (same-wave DS RAW on Ps: in-order DS pipe + compiler lgkm) ----
        __builtin_amdgcn_s_setprio(1);
        {
            s16x8 ap0 = *(const s16x8*)&Ps[wave][l16][kc0];
            #pragma unroll
            for (int j2 = 0; j2 < 4; ++j2) {
                s16x8 bv = *(const s16x8*)&Vt[cur][j2*16 + l16][kc0];
                o_acc[j2] = mfma16(ap0, bv, o_acc[j2]);
            }
            s16x8 ap1 = *(const s16x8*)&Ps[wave][l16][kc1];
            #pragma unroll
            for (int j2 = 0; j2 < 4; ++j2) {
                s16x8 bv = *(const s16x8*)&Vt[cur][j2*16 + l16][kc1];
                o_acc[j2] = mfma16(ap1, bv, o_acc[j2]);
            }
        }
        __builtin_amdgcn_s_setprio(0);
        // ---- write-late: publish next tile into the other buffer ----
        if (more) {
            const int nb = cur ^ 1;
            *(s16x8*)&Ks[nb][ksr][swzc(ks2*8,     ksr)] = krA;
            *(s16x8*)&Ks[nb][ksr][swzc(ks2*8 + 8, ksr)] = krB;
            #pragma unroll
            for (int j = 0; j < 8; ++j) {
                Vt[nb][vd0 + j    ][swzc(vsr, vd0 + j    )] = (u16)vrA[j];
                Vt[nb][vd0 + 8 + j][swzc(vsr, vd0 + 8 + j)] = (u16)vrB[j];
            }
        }
        __syncthreads();
    }

    #pragma unroll
    for (int j2 = 0; j2 < 4; ++j2) {
        #pragma unroll
        for (int r = 0; r < 4; ++r) {
            float v = o_acc[j2][r] / l_i[r];
            long row = (long)b * T_N + qt0 + wave*16 + quad*4 + r;
            O[row * 1024 + h*64 + j2*16 + l16] = f2bf(v);
        }
    }
}

// ---------------------------------------------------------------- ssc[b,t,s] = qs.ks/32 (masked)
__global__ __launch_bounds__(256) void ssc_kernel(
    const u16* __restrict__ qs, const u16* __restrict__ ks,
    const int* __restrict__ svl, float* __restrict__ ssc, int qld)
{
    const int t = blockIdx.x, b = blockIdx.y;
    const int wave = threadIdx.x >> 6, lane = threadIdx.x & 63;
    const u16* qrow = qs + ((long)b * T_N + t) * qld + lane * 16;
    const int vl = svl[b];
    for (int s = wave; s < 16; s += 4) {
        const u16* krow = ks + ((long)b * 16 + s) * 1024 + lane * 16;
        float acc = 0.f;
        #pragma unroll
        for (int seg = 0; seg < 2; seg++) {
            s16x8 qv = *(const s16x8*)(qrow + seg*8);
            s16x8 kv = *(const s16x8*)(krow + seg*8);
            #pragma unroll
            for (int j = 0; j < 8; j++) acc += bf2f((u16)qv[j]) * bf2f((u16)kv[j]);
        }
        #pragma unroll
        for (int d = 1; d < 64; d <<= 1) acc += __shfl_xor(acc, d, 64);
        if (lane == 0)
            ssc[((long)b * T_N + t) * 16 + s] = (s < vl) ? acc * (1.f/32.f) : NEGV;
    }
}

// ---------------------------------------------------------------- top-8 stats, top-16 tokens, sparse combine
__global__ __launch_bounds__(256) void select_combine_kernel(
    const float* __restrict__ ssc, const float* __restrict__ tsc,
    const u16* __restrict__ vv, u16* __restrict__ out, int t0, int vld)
{
    const int tl = blockIdx.x, b = blockIdx.y;
    const int tg = t0 + tl;
    const int tid = threadIdx.x;
    const int wave = tid >> 6, lane = tid & 63;
    __shared__ float coeff[128];
    __shared__ long  rowoff[128];
    __shared__ int   sel_s[8];
    __shared__ float sel_w[8];

    if (wave == 0) {
        float cur = (lane < 16) ? ssc[((long)b * T_N + tg) * 16 + lane] : -3e38f;
        float mx0 = 0.f, ssum = 0.f, myv = -3e38f;
        int myi = 0;
        #pragma unroll
        for (int it = 0; it < 8; it++) {
            float mv = cur; int mi = lane;
            #pragma unroll
            for (int d = 1; d < 64; d <<= 1) {
                float ov = __shfl_xor(mv, d, 64);
                int   oi = __shfl_xor(mi, d, 64);
                if (ov > mv || (ov == mv && oi < mi)) { mv = ov; mi = oi; }
            }
            if (it == 0) mx0 = mv;
            ssum += __expf(mv - mx0);
            if (lane == it) { myv = mv; myi = mi; }
            if (lane == mi) cur = -3e38f;
        }
        if (lane < 8) { sel_s[lane] = myi; sel_w[lane] = __expf(myv - mx0) / ssum; }
    }
    __syncthreads();

    for (int slot = wave; slot < 8; slot += 4) {
        int s = sel_s[slot];
        float sw = sel_w[slot];
        const float* trow = tsc + (((long)b * 16 + s) * 512 + tl) * 256;
        float4 lv4 = *(const float4*)(trow + lane * 4);
        float loc[4] = { lv4.x, lv4.y, lv4.z, lv4.w };
        float mx0 = 0.f, tsum = 0.f, myv = -3e38f;
        int myi = 0;
        for (int it = 0; it < 16; it++) {
            float mv = -3e38f; int mi = 0;
            #pragma unroll
            for (int u = 0; u < 4; u++)
                if (loc[u] > mv) { mv = loc[u]; mi = lane*4 + u; }
            #pragma unroll
            for (int d = 1; d < 64; d <<= 1) {
                float ov = __shfl_xor(mv, d, 64);
                int   oi = __shfl_xor(mi, d, 64);
                if (ov > mv || (ov == mv && oi < mi)) { mv = ov; mi = oi; }
            }
            if (it == 0) mx0 = mv * (1.f/32.f);
            tsum += __expf(mv * (1.f/32.f) - mx0);
            if (lane == it) { myv = mv; myi = mi; }
            if ((mi >> 2) == lane) {
                int u = mi & 3;
                if (u == 0) loc[0] = -3e38f;
                else if (u == 1) loc[1] = -3e38f;
                else if (u == 2) loc[2] = -3e38f;
                else loc[3] = -3e38f;
            }
        }
        if (lane < 16) {
            coeff[slot * 16 + lane]  = sw * __expf(myv * (1.f/32.f) - mx0) / tsum;
            rowoff[slot * 16 + lane] = (long)((b * 16 + s) * 256 + myi) * vld;
        }
    }
    __syncthreads();

    const int d0 = tid * 4;
    float a0 = 0.f, a1 = 0.f, a2 = 0.f, a3 = 0.f;
    for (int r = 0; r < 128; r++) {
        float c = coeff[r];
        const u16* vp = vv + rowoff[r] + d0;
        u16x4 v4 = *(const u16x4*)vp;
        a0 += c * bf2f(v4[0]);
        a1 += c * bf2f(v4[1]);
        a2 += c * bf2f(v4[2]);
        a3 += c * bf2f(v4[3]);
    }
    u16x4 o4 = { f2bf(a0), f2bf(a1), f2bf(a2), f2bf(a3) };
    *(u16x4*)(out + ((long)b * T_N + tg) * 1024 + d0) = o4;
}

// ---------------------------------------------------------------- LN kernels
__device__ __forceinline__ float block_sum(float v, float* red) {
    #pragma unroll
    for (int d = 1; d < 64; d <<= 1) v += __shfl_xor(v, d, 64);
    __syncthreads();
    if ((threadIdx.x & 63) == 0) red[threadIdx.x >> 6] = v;
    __syncthreads();
    return red[0] + red[1] + red[2] + red[3];
}

__global__ __launch_bounds__(256) void ln1_kernel(
    const float* __restrict__ x, const float* __restrict__ x2,
    const float* __restrict__ intent, const float* __restrict__ g, const float* __restrict__ be,
    u16* __restrict__ yi)
{
    __shared__ float red[4];
    const long row = blockIdx.x;
    const int tid = threadIdx.x;
    const long base = row * 1024 + tid * 4;
    float4 xv = *(const float4*)(x + base);
    float4 dv = *(const float4*)(x2 + base);
    float h0 = xv.x + dv.x, h1 = xv.y + dv.y, h2 = xv.z + dv.z, h3 = xv.w + dv.w;
    float s1 = block_sum(h0 + h1 + h2 + h3, red);
    float s2 = block_sum(h0*h0 + h1*h1 + h2*h2 + h3*h3, red);
    float mean = s1 * (1.f/1024.f);
    float var = s2 * (1.f/1024.f) - mean * mean;
    float inv = rsqrtf(var + 1e-5f);
    const int c = tid * 4;
    float4 gv = *(const float4*)(g + c);
    float4 bv = *(const float4*)(be + c);
    float o0 = (h0 - mean) * inv * gv.x + bv.x;
    float o1 = (h1 - mean) * inv * gv.y + bv.y;
    float o2 = (h2 - mean) * inv * gv.z + bv.z;
    float o3 = (h3 - mean) * inv * gv.w + bv.w;
    u16x4 ob = { f2bf(o0), f2bf(o1), f2bf(o2), f2bf(o3) };
    *(u16x4*)(yi + row * 1280 + c) = ob;
    const int b = (int)(row >> 10);
    yi[row * 1280 + 1024 + tid] = f2bf(intent[b * 256 + tid]);
}

__global__ __launch_bounds__(256) void gate_ln2_kernel(
    const u16* __restrict__ yi, const float* __restrict__ y2s, const float* __restrict__ y2e,
    const float* __restrict__ Wg, const float* __restrict__ g, const float* __restrict__ be,
    float* __restrict__ z, u16* __restrict__ zbf)
{
    __shared__ float red[4];
    const long row = blockIdx.x;
    const int tid = threadIdx.x;
    const long base = row * 1024 + tid * 4;
    const int c = tid * 4;
    float4 sv = *(const float4*)(y2s + base);
    float4 ev = *(const float4*)(y2e + base);
    float4 w1 = *(const float4*)(Wg + c);
    float4 w2 = *(const float4*)(Wg + 1024 + c);
    float dot = sv.x*w1.x + sv.y*w1.y + sv.z*w1.z + sv.w*w1.w
              + ev.x*w2.x + ev.y*w2.y + ev.z*w2.z + ev.w*w2.w;
    float tot = block_sum(dot, red);
    float gate = 1.f / (1.f + __expf(-tot));
    u16x4 yv4 = *(const u16x4*)(yi + row * 1280 + c);
    float h0 = bf2f(yv4[0]) + 2.f * (gate * sv.x + (1.f - gate) * ev.x);
    float h1 = bf2f(yv4[1]) + 2.f * (gate * sv.y + (1.f - gate) * ev.y);
    float h2 = bf2f(yv4[2]) + 2.f * (gate * sv.z + (1.f - gate) * ev.z);
    float h3 = bf2f(yv4[3]) + 2.f * (gate * sv.w + (1.f - gate) * ev.w);
    float s1 = block_sum(h0 + h1 + h2 + h3, red);
    float s2 = block_sum(h0*h0 + h1*h1 + h2*h2 + h3*h3, red);
    float mean = s1 * (1.f/1024.f);
    float var = s2 * (1.f/1024.f) - mean * mean;
    float inv = rsqrtf(var + 1e-5f);
    float4 gv = *(const float4*)(g + c);
    float4 bv = *(const float4*)(be + c);
    float o0 = (h0 - mean) * inv * gv.x + bv.x;
    float o1 = (h1 - mean) * inv * gv.y + bv.y;
    float o2 = (h2 - mean) * inv * gv.z + bv.z;
    float o3 = (h3 - mean) * inv * gv.w + bv.w;
    *(float4*)(z + base) = make_float4(o0, o1, o2, o3);
    u16x4 ob = { f2bf(o0), f2bf(o1), f2bf(o2), f2bf(o3) };
    *(u16x4*)(zbf + row * 1024 + c) = ob;
}

// final LN over z + (p0 + p1 + b2)  — FFN2 split-K partials fused here
__global__ __launch_bounds__(256) void ln3_kernel(
    const float* __restrict__ z, const float* __restrict__ p0, const float* __restrict__ p1,
    const float* __restrict__ b2,
    const float* __restrict__ g, const float* __restrict__ be, float* __restrict__ out)
{
    __shared__ float red[4];
    const long row = blockIdx.x;
    const int tid = threadIdx.x;
    const long base = row * 1024 + tid * 4;
    const int c = tid * 4;
    float4 zv = *(const float4*)(z + base);
    float4 f0 = *(const float4*)(p0 + base);
    float4 f1 = *(const float4*)(p1 + base);
    float4 bb = *(const float4*)(b2 + c);
    float h0 = zv.x + f0.x + f1.x + bb.x;
    float h1 = zv.y + f0.y + f1.y + bb.y;
    float h2 = zv.z + f0.z + f1.z + bb.z;
    float h3 = zv.w + f0.w + f1.w + bb.w;
    float s1 = block_sum(h0 + h1 + h2 + h3, red);
    float s2 = block_sum(h0*h0 + h1*h1 + h2*h2 + h3*h3, red);
    float mean = s1 * (1.f/1024.f);
    float var = s2 * (1.f/1024.f) - mean * mean;
    float inv = rsqrtf(var + 1e-5f);
    float4 gv = *(const float4*)(g + c);
    float4 bv = *(const float4*)(be + c);
    float o0 = (h0 - mean) * inv * gv.x + bv.x;
    float o1 = (h1 - mean) * inv * gv.y + bv.y;
    float o2 = (h2 - mean) * inv * gv.z + bv.z;
    float o3 = (h3 - mean) * inv * gv.w + bv.w;
    *(float4*)(out + base) = make_float4(o0, o1, o2, o3);
}

// ---------------------------------------------------------------- host
extern "C" void kernel_launch(void* const* d_in, const int* in_sizes, int n_in,
                              void* d_out, int out_size, void* d_ws, size_t ws_size,
                              hipStream_t stream)
{
    (void)in_sizes; (void)n_in; (void)out_size; (void)ws_size;
    const float* x      = (const float*)d_in[0];
    const float* stat_e = (const float*)d_in[1];
    const float* exem   = (const float*)d_in[2];
    const float* sfeat  = (const float*)d_in[3];
    const float* intent = (const float*)d_in[4];
    const float* Wg  = (const float*)d_in[19];
    const float* b1  = (const float*)d_in[21];
    const float* b2  = (const float*)d_in[23];
    const float* g1  = (const float*)d_in[24]; const float* be1 = (const float*)d_in[25];
    const float* g2  = (const float*)d_in[26]; const float* be2 = (const float*)d_in[27];
    const float* g3  = (const float*)d_in[28]; const float* be3 = (const float*)d_in[29];
    const int* svl = (const int*)d_in[30];
    const int* evl = (const int*)d_in[31];
    float* outp = (float*)d_out;

    // ---- workspace plan: 171 MB, lifetime-aliased ----
    char* base = (char*)d_ws;
    u16*  bufA  = (u16*)(base + 0*MB);        // 8MB: xbf / attn-outs / y2s_pre
    u16*  qkv1  = (u16*)(base + 8*MB);        // 24MB fused [4096,3072] (phase 3)
    float* x2a  = (float*)(base + 8*MB);      // 16MB (after flash1)
    u16*  kv2   = (u16*)(base + 8*MB);        // 16MB fused [4096,2048] (phase 5)
    u16*  w1t   = (u16*)(base + 8*MB);        // 8MB (phase 7)
    u16*  w2t   = (u16*)(base + 16*MB);       // 8MB (phase 7)
    u16*  yibf  = (u16*)(base + 32*MB);       // 10MB [4096,1280]
    u16*  buf3  = (u16*)(base + 42*MB);       // 24MB fused qs|qt|q2 [4096,3072]
    u16*  zbf   = (u16*)(base + 42*MB);       // 8MB (after flash2)
    u16*  sebf  = (u16*)(base + 66*MB);       // 32MB stat_enc bf16 / tsc-half fp32 / ffn hidden
    float* tsch = (float*)(base + 66*MB);
    u16*  hid   = (u16*)(base + 66*MB);
    u16*  ktvv  = (u16*)(base + 98*MB);       // 64MB fused [16384,2048]
    float* y2sf = (float*)(base + 98*MB);     // 16MB (after select)
    float* p0f  = (float*)(base + 98*MB);     // 32MB FFN2 partials (after gate_ln2; y2ef dead)
    u16*  exbf  = (u16*)(base + 114*MB);      // 8MB
    float* y2ef = (float*)(base + 122*MB);    // 16MB
    float* zf   = (float*)(base + 138*MB);    // 16MB
    u16*  sfbf  = (u16*)(base + 162*MB);                  // 128KB
    u16*  ksbf  = (u16*)(base + 162*MB + 256*1024);       // 128KB
    float* sscf = (float*)(base + 162*MB + 512*1024);     // 256KB
    char* wpool = base + 163*MB;              // 8MB rotating weight pool (total 171MB)

    dim3 blk(256);
    dim3 blk512(512);
    auto cast = [&](const float* s, u16* d, long n) {
        cast_bf16_kernel<<<dim3((unsigned)((n/4 + 255) / 256)), blk, 0, stream>>>(s, d, n);
    };
    auto g_n = [&](const u16* A, const u16* Bt, u16* C, int M, int N, int K,
                   int lda, int ldb, int ldc) {
        gemm_bt<u16,false,false><<<dim3(N/128, (M+127)/128, 1), blk, 0, stream>>>(
            A, Bt, C, nullptr, M, N, K, lda, ldb, ldc, 1, 0, 0, 0);
    };
    auto g_f = [&](const u16* A, const u16* Bt, float* C, int M, int N, int K,
                   int lda, int ldb, int ldc) {
        gemm_bt<float,false,false><<<dim3(N/128, (M+127)/128, 1), blk, 0, stream>>>(
            A, Bt, C, nullptr, M, N, K, lda, ldb, ldc, 1, 0, 0, 0);
    };
    // 256^2 deep-pipelined GEMM — M,N multiples of 256, grid must fill >=192 CUs
    auto g256_n = [&](const u16* A, const u16* Bt, u16* C, int M, int N, int K,
                      int lda, int ldb, int ldc) {
        gemm_bt256<u16,false,false><<<dim3(N/256, M/256, 1), blk512, 0, stream>>>(
            A, Bt, C, nullptr, M, N, K, lda, ldb, ldc, 1, 0, 0, 0);
    };

    // ---- phase 3: self-attention ----
    u16* wqkv1t = (u16*)wpool;                       // [3072,1024] stacked
    u16* wo1t   = (u16*)(wpool) + 3L*1024*1024;
    {
        P6 pp{};
        pp.s[0]=(const float*)d_in[5]; pp.d[0]=wqkv1t;
        pp.s[1]=(const float*)d_in[6]; pp.d[1]=wqkv1t + 1L*1024*1024;
        pp.s[2]=(const float*)d_in[7]; pp.d[2]=wqkv1t + 2L*1024*1024;
        pp.s[3]=(const float*)d_in[8]; pp.d[3]=wo1t;
        transpose_cast_batch<<<dim3(32, 32, 4), blk, 0, stream>>>(pp, 1024, 1024);
    }
    cast(x, bufA, 4096L*1024);
    g256_n(bufA, wqkv1t, qkv1, 4096, 3072, 1024, 1024, 1024, 3072);
    flash_attn_kernel<true><<<dim3(16, 16, 4), blk, 0, stream>>>(
        qkv1, qkv1 + 1024, qkv1 + 2048, nullptr, bufA, 3072, 3072, 3072);
    g_f(bufA, wo1t, x2a, 4096, 1024, 1024, 1024, 1024, 1024);
    ln1_kernel<<<dim3(4096), blk, 0, stream>>>(x, x2a, intent, g1, be1, yibf);

    // ---- phase 4: selective hierarchical attention ----
    u16* wq3t = (u16*)wpool;
    {
        P6 pp{};
        pp.s[0]=(const float*)d_in[9];  pp.d[0]=wq3t;
        pp.s[1]=(const float*)d_in[10]; pp.d[1]=wq3t + 1L*1024*1280;
        pp.s[2]=(const float*)d_in[15]; pp.d[2]=wq3t + 2L*1024*1280;
        transpose_cast_batch<<<dim3(32, 40, 3), blk, 0, stream>>>(pp, 1280, 1024);
    }
    g256_n(yibf, wq3t, buf3, 4096, 3072, 1280, 1280, 1280, 3072);   // qs|qt|q2
    u16* wkst = (u16*)wpool;
    u16* wkv  = (u16*)(wpool) + 1L*1024*1024;
    {
        P6 pp{};
        pp.s[0]=(const float*)d_in[11]; pp.d[0]=wkst;
        pp.s[1]=(const float*)d_in[12]; pp.d[1]=wkv;
        pp.s[2]=(const float*)d_in[13]; pp.d[2]=wkv + 1L*1024*1024;
        transpose_cast_batch<<<dim3(32, 32, 3), blk, 0, stream>>>(pp, 1024, 1024);
    }
    cast(sfeat, sfbf, 64L*1024);
    cast(stat_e, sebf, 16384L*1024);
    g_n(sfbf, wkst, ksbf, 64, 1024, 1024, 1024, 1024, 1024);
    g256_n(sebf, wkv, ktvv, 16384, 2048, 1024, 1024, 1024, 2048);   // kt|vv
    ssc_kernel<<<dim3(1024, 4), blk, 0, stream>>>(buf3, ksbf, svl, sscf, 3072);
    for (int hh = 0; hh < 2; hh++) {
        long t0 = hh * 512;
        gemm_bt<float,false,false><<<dim3(2, 4, 64), blk, 0, stream>>>(
            buf3 + 1024 + t0*3072, ktvv, tsch, nullptr, 512, 256, 1024,
            3072, 2048, 256, 16, (long)T_N*3072, 256L*2048, 512L*256);
        select_combine_kernel<<<dim3(512, 4), blk, 0, stream>>>(
            sscf, tsch, ktvv + 1024, bufA, (int)t0, 2048);
    }
    u16* wost = (u16*)wpool;
    u16* wkv2 = (u16*)(wpool) + 1L*1024*1024;
    u16* wo2t = (u16*)(wpool) + 3L*1024*1024;
    {
        P6 pp{};
        pp.s[0]=(const float*)d_in[14]; pp.d[0]=wost;
        pp.s[1]=(const float*)d_in[16]; pp.d[1]=wkv2;
        pp.s[2]=(const float*)d_in[17]; pp.d[2]=wkv2 + 1L*1024*1024;
        pp.s[3]=(const float*)d_in[18]; pp.d[3]=wo2t;
        transpose_cast_batch<<<dim3(32, 32, 4), blk, 0, stream>>>(pp, 1024, 1024);
    }
    g_f(bufA, wost, y2sf, 4096, 1024, 1024, 1024, 1024, 1024);

    // ---- phase 5: exemplar cross-attention ----
    cast(exem, exbf, 4096L*1024);
    g_n(exbf, wkv2, kv2, 4096, 2048, 1024, 1024, 1024, 2048);       // k2|v2 (128^2: 512 blocks)
    flash_attn_kernel<false><<<dim3(16, 16, 4), blk, 0, stream>>>(
        buf3 + 2048, kv2, kv2 + 1024, evl, bufA, 3072, 2048, 2048);
    g_f(bufA, wo2t, y2ef, 4096, 1024, 1024, 1024, 1024, 1024);

    // ---- phase 6: gate + LN2 ----
    gate_ln2_kernel<<<dim3(4096), blk, 0, stream>>>(yibf, y2sf, y2ef, Wg, g2, be2, zf, zbf);

    // ---- phase 7: FFN ----
    {
        P6 pp{}; pp.s[0] = (const float*)d_in[20]; pp.d[0] = w1t;
        transpose_cast_batch<<<dim3(128, 32, 1), blk, 0, stream>>>(pp, 1024, 4096);
    }
    {
        P6 pp{}; pp.s[0] = (const float*)d_in[22]; pp.d[0] = w2t;
        transpose_cast_batch<<<dim3(32, 128, 1), blk, 0, stream>>>(pp, 4096, 1024);
    }
    gemm_bt256<u16,true,true><<<dim3(16, 16, 1), blk512, 0, stream>>>(
        zbf, w1t, hid, b1, 4096, 4096, 1024, 1024, 1024, 4096, 1, 0, 0, 0);
    // FFN2 split-K x2 in one dispatch (z picks K-half): p[z] = hid[:,z*2048:] @ w2t[:,z*2048:]^T
    gemm_bt<float,false,false><<<dim3(8, 32, 2), blk, 0, stream>>>(
        hid, w2t, p0f, nullptr, 4096, 1024, 2048, 4096, 4096, 1024,
        1, 2048, 2048, 4096L*1024);

    // ---- phase 8: final LN (fuses p0+p1+b2) ----
    ln3_kernel<<<dim3(4096), blk, 0, stream>>>(zf, p0f, p0f + 4096L*1024, b2, g3, be3, outp);
}

// Round 5
// 976.358 us; speedup vs baseline: 1.0849x; 1.0119x over previous
//
#include <hip/hip_runtime.h>

typedef unsigned short u16;
typedef short s16x8 __attribute__((ext_vector_type(8)));
typedef u16 u16x4 __attribute__((ext_vector_type(4)));
typedef float f32x4 __attribute__((ext_vector_type(4)));

#define T_N   1024
#define NEGV  -1e6f
#define MB    (1L << 20)

__device__ __forceinline__ u16 f2bf(float f) {
    unsigned u = __float_as_uint(f);
    u += 0x7fffu + ((u >> 16) & 1u);     // RNE
    return (u16)(u >> 16);
}
__device__ __forceinline__ float bf2f(u16 h) {
    return __uint_as_float(((unsigned)h) << 16);
}
__device__ __forceinline__ f32x4 mfma16(s16x8 a, s16x8 b, f32x4 c) {
    return __builtin_amdgcn_mfma_f32_16x16x32_bf16(a, b, c, 0, 0, 0);
}
// async global->LDS, 16B per lane; LDS dest = wave-uniform base + lane*16 (m97/m104)
__device__ __forceinline__ void gll16(const u16* g, u16* l) {
    __builtin_amdgcn_global_load_lds((const __attribute__((address_space(1))) void*)g,
                                     (__attribute__((address_space(3))) void*)l, 16, 0, 0);
}
// 3-bit row-derived chunk swizzle for [.][64] u16 LDS arrays (flash kernel)
__device__ __forceinline__ int swzf(int row) {
    return ((row >> 1) & 3) | ((row & 1) << 2);
}
__device__ __forceinline__ int swzc(int col, int row) {
    return (((col >> 3) ^ swzf(row)) << 3) | (col & 7);
}

// ---------------------------------------------------------------- transpose+cast
struct P6 { const float* s[6]; u16* d[6]; };

__global__ __launch_bounds__(256) void transpose_cast_batch(P6 pp, int K, int N) {
    const float* __restrict__ src = pp.s[blockIdx.z];
    u16* __restrict__ dst = pp.d[blockIdx.z];
    __shared__ float tile[32][33];
    int nb = blockIdx.x * 32, kb = blockIdx.y * 32;
    int tx = threadIdx.x & 31, ty = threadIdx.x >> 5;   // ty 0..7
    #pragma unroll
    for (int i = 0; i < 4; i++)
        tile[ty + 8*i][tx] = src[(long)(kb + ty + 8*i) * N + nb + tx];
    __syncthreads();
    #pragma unroll
    for (int i = 0; i < 4; i++)
        dst[(long)(nb + ty + 8*i) * K + kb + tx] = f2bf(tile[tx][ty + 8*i]);
}

__global__ __launch_bounds__(256) void cast_bf16_kernel(const float* __restrict__ src,
                                                        u16* __restrict__ dst, long n) {
    long i = ((long)blockIdx.x * 256 + threadIdx.x) * 4;
    if (i >= n) return;
    float4 v = *(const float4*)(src + i);
    u16x4 o = { f2bf(v.x), f2bf(v.y), f2bf(v.z), f2bf(v.w) };
    *(u16x4*)(dst + i) = o;
}

// ---------------------------------------------------------------- GEMM: C[M,N] = A[M,K] * Bt[N,K]^T
// 128x128-tile fallback kernel (m97 structure) — for small/odd shapes.
template<typename OutT, bool RELU, bool HAS_BIAS>
__global__ __launch_bounds__(256) void gemm_bt(
    const u16* __restrict__ A, const u16* __restrict__ Bt, OutT* __restrict__ C,
    const float* __restrict__ bias, int M, int N, int K,
    int lda, int ldb, int ldc,
    int batchDivA, long sA, long sB, long sC)
{
    A  += (long)(blockIdx.z / batchDivA) * sA;
    Bt += (long)blockIdx.z * sB;
    C  += (long)blockIdx.z * sC;
    __shared__ __align__(16) u16 As[4096];   // [128][32] row-major, 8 KB
    __shared__ __align__(16) u16 Bs[4096];
    const int tid = threadIdx.x;
    const int wave = tid >> 6, lane = tid & 63;
    const int quad = lane >> 4, l16 = lane & 15;
    const int wr = (wave >> 1) * 64, wc = (wave & 1) * 64;
    const long row0 = (long)blockIdx.y * 128, col0 = (long)blockIdx.x * 128;

    f32x4 acc[4][4] = {};

    const int l4r = lane >> 2;
    const int l4c = (lane & 3) * 8;
    const int ra = wave * 32 + l4r;
    const u16* Ap0 = A + (row0 + ra) * (long)lda + l4c;
    const u16* Ap1 = Ap0 + 16L * lda;
    const u16* Bp0 = Bt + (col0 + ra) * (long)ldb + l4c;
    const u16* Bp1 = Bp0 + 16L * ldb;
    u16* AsW0 = &As[(wave * 32) * 32];
    u16* AsW1 = &As[(wave * 32 + 16) * 32];
    u16* BsW0 = &Bs[(wave * 32) * 32];
    u16* BsW1 = &Bs[(wave * 32 + 16) * 32];
    const bool aok0 = (row0 + wave * 32) < M;
    const bool aok1 = (row0 + wave * 32 + 16) < M;

    for (int k0 = 0; k0 < K; k0 += 32) {
        __syncthreads();
        if (aok0) gll16(Ap0 + k0, AsW0);
        if (aok1) gll16(Ap1 + k0, AsW1);
        gll16(Bp0 + k0, BsW0);
        gll16(Bp1 + k0, BsW1);
        __syncthreads();
        s16x8 af[4], bfr[4];
        #pragma unroll
        for (int i = 0; i < 4; i++)
            af[i]  = *(const s16x8*)&As[(wr + i*16 + l16) * 32 + quad*8];
        #pragma unroll
        for (int j = 0; j < 4; j++)
            bfr[j] = *(const s16x8*)&Bs[(wc + j*16 + l16) * 32 + quad*8];
        #pragma unroll
        for (int i = 0; i < 4; i++)
            #pragma unroll
            for (int j = 0; j < 4; j++)
                acc[i][j] = mfma16(af[i], bfr[j], acc[i][j]);
    }

    #pragma unroll
    for (int i = 0; i < 4; i++) {
        long row = row0 + wr + i*16 + quad*4;
        #pragma unroll
        for (int j = 0; j < 4; j++) {
            long col = col0 + wc + j*16 + l16;
            float bv = 0.f;
            if constexpr (HAS_BIAS) bv = bias[col];
            #pragma unroll
            for (int r = 0; r < 4; r++) {
                if (row + r < M) {
                    float v = acc[i][j][r] + bv;
                    if constexpr (RELU) v = fmaxf(v, 0.f);
                    if constexpr (sizeof(OutT) == 2) C[(row + r) * (long)ldc + col] = f2bf(v);
                    else                             C[(row + r) * (long)ldc + col] = v;
                }
            }
        }
    }
}

// ---------------------------------------------------------------- GEMM M128xN256, depth-2, 2 blocks/CU
// Round-5 redesign. The 256^2 tile was structurally capped at 1 block/CU
// (acc=128 VGPR/lane -> 2 waves/SIMD; 128 KB LDS) so the per-slice barrier
// re-phased all resident waves: LDS-port burst (~1000-1500 cy/slice) and MFMA
// burst (~1200 cy) SERIALIZED (sum ~2700 ~= measured 2830 cy/slice, MfmaUtil
// 37%). This kernel: tile M=128 x N=256, 8 waves (2M x 4N) of 64x64 output ->
// acc = 64 VGPR (~115 total, fits __launch_bounds__(512,4)); depth-2 LDS ring
// = 48 KB -> TWO blocks/CU. While one block sits in its barrier/ds-read
// burst, the co-resident block issues MFMA (m114 inter-wave overlap) — port
// and matrix pipes overlap across blocks instead of alternating.
// Grids also double vs 256^2 (qkv1/buf3 192->384 fixes 64 idle CUs).
//
// Per slice per wave: 8 frag ds_read_b128, 3 global_load_lds (A:1, B:2),
// 16 MFMA, one vmcnt(0) + barrier. Stage into buf^1 while reading buf;
// old contents of buf^1 were last read in slice kt-1, fenced by its barrier.
// T2 chunk swizzle (source-col XOR on row bits 1..2, linear DMA dest,
// XOR'd read chunk) and T1 bijective XCD remap carried over.
// Requires: M%128==0, N%256==0, K%32==0.
template<typename OutT, bool RELU, bool HAS_BIAS>
__global__ __launch_bounds__(512, 4) void gemm_bt128(
    const u16* __restrict__ A, const u16* __restrict__ Bt, OutT* __restrict__ C,
    const float* __restrict__ bias, int M, int N, int K,
    int lda, int ldb, int ldc,
    int batchDivA, long sA, long sB, long sC)
{
    // T1: XCD-aware bijective block remap (contiguous chunk per XCD)
    int bx = blockIdx.x, by = blockIdx.y;
    {
        const int nwg = gridDim.x * gridDim.y;
        if ((nwg & 7) == 0) {
            const int flat = by * gridDim.x + bx;
            const int nf = (flat & 7) * (nwg >> 3) + (flat >> 3);
            bx = nf % gridDim.x;
            by = nf / gridDim.x;
        }
    }
    A  += (long)(blockIdx.z / batchDivA) * sA;
    Bt += (long)blockIdx.z * sB;
    C  += (long)blockIdx.z * sC;
    __shared__ __align__(16) u16 As[2][4096];   // [128][32] each, 8 KB x2
    __shared__ __align__(16) u16 Bs[2][8192];   // [256][32] each, 16 KB x2
    const int tid = threadIdx.x;
    const int wave = tid >> 6, lane = tid & 63;
    const int quad = lane >> 4, l16 = lane & 15;
    const int wm = wave >> 2, wn = wave & 3;           // 2M x 4N wave grid
    const long row0 = (long)by * 128, col0 = (long)bx * 256;

    // staging: thread t covers row t>>2; SOURCE chunk is XOR-swizzled so the
    // linear DMA write leaves LDS(r,c) = global chunk (r, c ^ ((r>>1)&3)).
    const int srow = tid >> 2;
    const int scol = ((tid & 3) ^ ((srow >> 1) & 3)) * 8;
    const u16* Ag = A  + (row0 + srow) * (long)lda + scol;
    const u16* Bg = Bt + (col0 + srow) * (long)ldb + scol;
    const int ldsoff = wave * 512;                      // wave-uniform elem offset

    f32x4 acc[4][4] = {};
    const int NT = K >> 5;

    auto stage = [&](int kt, int buf) {
        gll16(Ag + (long)kt * 32,            &As[buf][ldsoff]);
        gll16(Bg + (long)kt * 32,            &Bs[buf][ldsoff]);
        gll16(Bg + (long)kt * 32 + 128L*ldb, &Bs[buf][4096 + ldsoff]);
    };

    stage(0, 0);
    asm volatile("s_waitcnt vmcnt(0)" ::: "memory");
    __builtin_amdgcn_s_barrier();
    __builtin_amdgcn_sched_barrier(0);

    const int arow = wm * 64 + l16;
    const int brow = wn * 64 + l16;
    const int kq   = (quad ^ ((l16 >> 1) & 3)) * 8;     // swizzled chunk offset

    for (int kt = 0; kt < NT; ++kt) {
        const int b = kt & 1;
        const bool st = (kt + 1) < NT;
        const u16* Ab = As[b];
        const u16* Bb = Bs[b];

        s16x8 af[4], bfr[4];
        #pragma unroll
        for (int j = 0; j < 4; ++j)
            bfr[j] = *(const s16x8*)&Bb[(brow + j*16) * 32 + kq];
        #pragma unroll
        for (int i = 0; i < 4; ++i)
            af[i] = *(const s16x8*)&Ab[(arow + i*16) * 32 + kq];

        if (st) stage(kt + 1, b ^ 1);

        #pragma unroll
        for (int i = 0; i < 4; ++i)
            #pragma unroll
            for (int j = 0; j < 4; ++j)
                acc[i][j] = mfma16(af[i], bfr[j], acc[i][j]);

        asm volatile("s_waitcnt vmcnt(0)" ::: "memory");
        __builtin_amdgcn_s_barrier();
        __builtin_amdgcn_sched_barrier(0);
    }

    #pragma unroll
    for (int i = 0; i < 4; ++i) {
        const long row = row0 + wm*64 + i*16 + quad*4;
        #pragma unroll
        for (int j = 0; j < 4; ++j) {
            const long col = col0 + wn*64 + j*16 + l16;
            float bv = 0.f;
            if constexpr (HAS_BIAS) bv = bias[col];
            #pragma unroll
            for (int r = 0; r < 4; ++r) {
                float v = acc[i][j][r] + bv;
                if constexpr (RELU) v = fmaxf(v, 0.f);
                if constexpr (sizeof(OutT) == 2) C[(row + r) * (long)ldc + col] = f2bf(v);
                else                             C[(row + r) * (long)ldc + col] = v;
            }
        }
    }
}

// ---------------------------------------------------------------- flash attention (dh=64, H=16)
// (round-4 version: async double-buffer, 1 barrier/tile, Q in regs, swizzled
// stride-64 LDS — verified, dropped out of top-5)
template<bool CAUSAL>
__global__ __launch_bounds__(256, 4) void flash_attn_kernel(
    const u16* __restrict__ Q, const u16* __restrict__ Kg, const u16* __restrict__ Vg,
    const int* __restrict__ valid_len, u16* __restrict__ O,
    int qld, int kld, int vld)
{
    const int h = blockIdx.y, b = blockIdx.z;
    const int qt0 = blockIdx.x * 64;
    const int tid = threadIdx.x;
    const int wave = tid >> 6, lane = tid & 63;
    const int quad = lane >> 4, l16 = lane & 15;

    __shared__ __align__(16) u16 Ks[2][64][64];   // 16 KB
    __shared__ __align__(16) u16 Vt[2][64][64];   // 16 KB (V transposed: [d][kv])
    __shared__ __align__(16) u16 Ps[4][16][64];   // 8 KB (per-wave private)

    s16x8 aq[2];
    {
        const u16* qp = Q + ((long)b * T_N + qt0 + wave*16 + l16) * qld + h * 64 + quad * 8;
        aq[0] = *(const s16x8*)qp;
        aq[1] = *(const s16x8*)(qp + 32);
    }

    const int ksr = tid >> 2;
    const int ks2 = (tid & 3) * 2;
    const int vsr = tid & 63;
    const int vd0 = (tid >> 6) * 16;

    const u16* kp = Kg + ((long)b * T_N + ksr) * (long)kld + h * 64 + ks2 * 8;
    const u16* vp = Vg + ((long)b * T_N + vsr) * (long)vld + h * 64 + vd0;
    const long kstep = 64L * kld, vstep = 64L * vld;

    const int fl  = swzf(l16);
    const int kc0 = ((quad ^ fl) & 7) * 8;
    const int kc1 = (((quad + 4) ^ fl) & 7) * 8;

    float m_i[4] = {-1e30f, -1e30f, -1e30f, -1e30f};
    float l_i[4] = {0.f, 0.f, 0.f, 0.f};
    f32x4 o_acc[4] = {};

    int vl = 0, kend;
    if (CAUSAL) kend = qt0 + 64;
    else { vl = valid_len[b]; kend = (vl + 63) & ~63; }
    const int nt = kend >> 6;

    s16x8 krA, krB, vrA, vrB;
    krA = *(const s16x8*)kp;       krB = *(const s16x8*)(kp + 8);
    vrA = *(const s16x8*)vp;       vrB = *(const s16x8*)(vp + 8);
    kp += kstep; vp += vstep;
    {
        *(s16x8*)&Ks[0][ksr][swzc(ks2*8,     ksr)] = krA;
        *(s16x8*)&Ks[0][ksr][swzc(ks2*8 + 8, ksr)] = krB;
        #pragma unroll
        for (int j = 0; j < 8; ++j) {
            Vt[0][vd0 + j    ][swzc(vsr, vd0 + j    )] = (u16)vrA[j];
            Vt[0][vd0 + 8 + j][swzc(vsr, vd0 + 8 + j)] = (u16)vrB[j];
        }
    }
    __syncthreads();

    for (int t = 0; t < nt; ++t) {
        const int cur = t & 1;
        const bool more = (t + 1) < nt;
        if (more) {
            krA = *(const s16x8*)kp;  krB = *(const s16x8*)(kp + 8);
            vrA = *(const s16x8*)vp;  vrB = *(const s16x8*)(vp + 8);
            kp += kstep; vp += vstep;
        }
        f32x4 sc[4] = {};
        __builtin_amdgcn_s_setprio(1);
        #pragma unroll
        for (int j = 0; j < 4; ++j) {
            s16x8 bk0 = *(const s16x8*)&Ks[cur][j*16 + l16][kc0];
            sc[j] = mfma16(aq[0], bk0, sc[j]);
        }
        #pragma unroll
        for (int j = 0; j < 4; ++j) {
            s16x8 bk1 = *(const s16x8*)&Ks[cur][j*16 + l16][kc1];
            sc[j] = mfma16(aq[1], bk1, sc[j]);
        }
        __builtin_amdgcn_s_setprio(0);
        const int kv0 = t * 64;
        const int qrow = qt0 + wave*16 + quad*4;
        #pragma unroll
        for (int j = 0; j < 4; ++j) {
            int kcol = kv0 + j*16 + l16;
            #pragma unroll
            for (int r = 0; r < 4; ++r) {
                float s = sc[j][r] * 0.125f;
                bool ok = CAUSAL ? (kcol <= qrow + r) : (kcol < vl);
                sc[j][r] = ok ? s : -1e30f;
            }
        }
        float alpha[4];
        #pragma unroll
        for (int r = 0; r < 4; ++r) {
            float mx = fmaxf(fmaxf(sc[0][r], sc[1][r]), fmaxf(sc[2][r], sc[3][r]));
            #pragma unroll
            for (int d = 1; d < 16; d <<= 1) mx = fmaxf(mx, __shfl_xor(mx, d, 64));
            float mn = fmaxf(m_i[r], mx);
            alpha[r] = __expf(m_i[r] - mn);
            m_i[r] = mn;
        }
        float rsum[4] = {0.f, 0.f, 0.f, 0.f};
        #pragma unroll
        for (int j = 0; j < 4; ++j)
            #pragma unroll
            for (int r = 0; r < 4; ++r) {
                float pv = __expf(sc[j][r] - m_i[r]);
                sc[j][r] = pv;
                rsum[r] += pv;
            }
        #pragma unroll
        for (int r = 0; r < 4; ++r) {
            #pragma unroll
            for (int d = 1; d < 16; d <<= 1) rsum[r] += __shfl_xor(rsum[r], d, 64);
            l_i[r] = l_i[r] * alpha[r] + rsum[r];
        }
        #pragma unroll
        for (int j = 0; j < 4; ++j)
            #pragma unroll
            for (int r = 0; r < 4; ++r)
                Ps[wave][quad*4 + r][swzc(j*16 + l16, quad*4 + r)] = f2bf(sc[j][r]);
        #pragma unroll
        for (int j2 = 0; j2 < 4; ++j2)
            #pragma unroll
            for (int r = 0; r < 4; ++r)
                o_acc[j2][r] *= alpha[r];
        __builtin_amdgcn_s_setprio(1);
        {
            s16x8 ap0 = *(const s16x8*)&Ps[wave][l16][kc0];
            #pragma unroll
            for (int j2 = 0; j2 < 4; ++j2) {
                s16x8 bv = *(const s16x8*)&Vt[cur][j2*16 + l16][kc0];
                o_acc[j2] = mfma16(ap0, bv, o_acc[j2]);
            }
            s16x8 ap1 = *(const s16x8*)&Ps[wave][l16][kc1];
            #pragma unroll
            for (int j2 = 0; j2 < 4; ++j2) {
                s16x8 bv = *(const s16x8*)&Vt[cur][j2*16 + l16][kc1];
                o_acc[j2] = mfma16(ap1, bv, o_acc[j2]);
            }
        }
        __builtin_amdgcn_s_setprio(0);
        if (more) {
            const int nb = cur ^ 1;
            *(s16x8*)&Ks[nb][ksr][swzc(ks2*8,     ksr)] = krA;
            *(s16x8*)&Ks[nb][ksr][swzc(ks2*8 + 8, ksr)] = krB;
            #pragma unroll
            for (int j = 0; j < 8; ++j) {
                Vt[nb][vd0 + j    ][swzc(vsr, vd0 + j    )] = (u16)vrA[j];
                Vt[nb][vd0 + 8 + j][swzc(vsr, vd0 + 8 + j)] = (u16)vrB[j];
            }
        }
        __syncthreads();
    }

    #pragma unroll
    for (int j2 = 0; j2 < 4; ++j2) {
        #pragma unroll
        for (int r = 0; r < 4; ++r) {
            float v = o_acc[j2][r] / l_i[r];
            long row = (long)b * T_N + qt0 + wave*16 + quad*4 + r;
            O[row * 1024 + h*64 + j2*16 + l16] = f2bf(v);
        }
    }
}

// ---------------------------------------------------------------- ssc[b,t,s] = qs.ks/32 (masked)
__global__ __launch_bounds__(256) void ssc_kernel(
    const u16* __restrict__ qs, const u16* __restrict__ ks,
    const int* __restrict__ svl, float* __restrict__ ssc, int qld)
{
    const int t = blockIdx.x, b = blockIdx.y;
    const int wave = threadIdx.x >> 6, lane = threadIdx.x & 63;
    const u16* qrow = qs + ((long)b * T_N + t) * qld + lane * 16;
    const int vl = svl[b];
    for (int s = wave; s < 16; s += 4) {
        const u16* krow = ks + ((long)b * 16 + s) * 1024 + lane * 16;
        float acc = 0.f;
        #pragma unroll
        for (int seg = 0; seg < 2; seg++) {
            s16x8 qv = *(const s16x8*)(qrow + seg*8);
            s16x8 kv = *(const s16x8*)(krow + seg*8);
            #pragma unroll
            for (int j = 0; j < 8; j++) acc += bf2f((u16)qv[j]) * bf2f((u16)kv[j]);
        }
        #pragma unroll
        for (int d = 1; d < 64; d <<= 1) acc += __shfl_xor(acc, d, 64);
        if (lane == 0)
            ssc[((long)b * T_N + t) * 16 + s] = (s < vl) ? acc * (1.f/32.f) : NEGV;
    }
}

// ---------------------------------------------------------------- top-8 stats, top-16 tokens, sparse combine
__global__ __launch_bounds__(256) void select_combine_kernel(
    const float* __restrict__ ssc, const float* __restrict__ tsc,
    const u16* __restrict__ vv, u16* __restrict__ out, int t0, int vld)
{
    const int tl = blockIdx.x, b = blockIdx.y;
    const int tg = t0 + tl;
    const int tid = threadIdx.x;
    const int wave = tid >> 6, lane = tid & 63;
    __shared__ float coeff[128];
    __shared__ long  rowoff[128];
    __shared__ int   sel_s[8];
    __shared__ float sel_w[8];

    if (wave == 0) {
        float cur = (lane < 16) ? ssc[((long)b * T_N + tg) * 16 + lane] : -3e38f;
        float mx0 = 0.f, ssum = 0.f, myv = -3e38f;
        int myi = 0;
        #pragma unroll
        for (int it = 0; it < 8; it++) {
            float mv = cur; int mi = lane;
            #pragma unroll
            for (int d = 1; d < 64; d <<= 1) {
                float ov = __shfl_xor(mv, d, 64);
                int   oi = __shfl_xor(mi, d, 64);
                if (ov > mv || (ov == mv && oi < mi)) { mv = ov; mi = oi; }
            }
            if (it == 0) mx0 = mv;
            ssum += __expf(mv - mx0);
            if (lane == it) { myv = mv; myi = mi; }
            if (lane == mi) cur = -3e38f;
        }
        if (lane < 8) { sel_s[lane] = myi; sel_w[lane] = __expf(myv - mx0) / ssum; }
    }
    __syncthreads();

    for (int slot = wave; slot < 8; slot += 4) {
        int s = sel_s[slot];
        float sw = sel_w[slot];
        const float* trow = tsc + (((long)b * 16 + s) * 512 + tl) * 256;
        float4 lv4 = *(const float4*)(trow + lane * 4);
        float loc[4] = { lv4.x, lv4.y, lv4.z, lv4.w };
        float mx0 = 0.f, tsum = 0.f, myv = -3e38f;
        int myi = 0;
        for (int it = 0; it < 16; it++) {
            float mv = -3e38f; int mi = 0;
            #pragma unroll
            for (int u = 0; u < 4; u++)
                if (loc[u] > mv) { mv = loc[u]; mi = lane*4 + u; }
            #pragma unroll
            for (int d = 1; d < 64; d <<= 1) {
                float ov = __shfl_xor(mv, d, 64);
                int   oi = __shfl_xor(mi, d, 64);
                if (ov > mv || (ov == mv && oi < mi)) { mv = ov; mi = oi; }
            }
            if (it == 0) mx0 = mv * (1.f/32.f);
            tsum += __expf(mv * (1.f/32.f) - mx0);
            if (lane == it) { myv = mv; myi = mi; }
            if ((mi >> 2) == lane) {
                int u = mi & 3;
                if (u == 0) loc[0] = -3e38f;
                else if (u == 1) loc[1] = -3e38f;
                else if (u == 2) loc[2] = -3e38f;
                else loc[3] = -3e38f;
            }
        }
        if (lane < 16) {
            coeff[slot * 16 + lane]  = sw * __expf(myv * (1.f/32.f) - mx0) / tsum;
            rowoff[slot * 16 + lane] = (long)((b * 16 + s) * 256 + myi) * vld;
        }
    }
    __syncthreads();

    const int d0 = tid * 4;
    float a0 = 0.f, a1 = 0.f, a2 = 0.f, a3 = 0.f;
    for (int r = 0; r < 128; r++) {
        float c = coeff[r];
        const u16* vp = vv + rowoff[r] + d0;
        u16x4 v4 = *(const u16x4*)vp;
        a0 += c * bf2f(v4[0]);
        a1 += c * bf2f(v4[1]);
        a2 += c * bf2f(v4[2]);
        a3 += c * bf2f(v4[3]);
    }
    u16x4 o4 = { f2bf(a0), f2bf(a1), f2bf(a2), f2bf(a3) };
    *(u16x4*)(out + ((long)b * T_N + tg) * 1024 + d0) = o4;
}

// ---------------------------------------------------------------- LN kernels
__device__ __forceinline__ float block_sum(float v, float* red) {
    #pragma unroll
    for (int d = 1; d < 64; d <<= 1) v += __shfl_xor(v, d, 64);
    __syncthreads();
    if ((threadIdx.x & 63) == 0) red[threadIdx.x >> 6] = v;
    __syncthreads();
    return red[0] + red[1] + red[2] + red[3];
}

__global__ __launch_bounds__(256) void ln1_kernel(
    const float* __restrict__ x, const float* __restrict__ x2,
    const float* __restrict__ intent, const float* __restrict__ g, const float* __restrict__ be,
    u16* __restrict__ yi)
{
    __shared__ float red[4];
    const long row = blockIdx.x;
    const int tid = threadIdx.x;
    const long base = row * 1024 + tid * 4;
    float4 xv = *(const float4*)(x + base);
    float4 dv = *(const float4*)(x2 + base);
    float h0 = xv.x + dv.x, h1 = xv.y + dv.y, h2 = xv.z + dv.z, h3 = xv.w + dv.w;
    float s1 = block_sum(h0 + h1 + h2 + h3, red);
    float s2 = block_sum(h0*h0 + h1*h1 + h2*h2 + h3*h3, red);
    float mean = s1 * (1.f/1024.f);
    float var = s2 * (1.f/1024.f) - mean * mean;
    float inv = rsqrtf(var + 1e-5f);
    const int c = tid * 4;
    float4 gv = *(const float4*)(g + c);
    float4 bv = *(const float4*)(be + c);
    float o0 = (h0 - mean) * inv * gv.x + bv.x;
    float o1 = (h1 - mean) * inv * gv.y + bv.y;
    float o2 = (h2 - mean) * inv * gv.z + bv.z;
    float o3 = (h3 - mean) * inv * gv.w + bv.w;
    u16x4 ob = { f2bf(o0), f2bf(o1), f2bf(o2), f2bf(o3) };
    *(u16x4*)(yi + row * 1280 + c) = ob;
    const int b = (int)(row >> 10);
    yi[row * 1280 + 1024 + tid] = f2bf(intent[b * 256 + tid]);
}

__global__ __launch_bounds__(256) void gate_ln2_kernel(
    const u16* __restrict__ yi, const float* __restrict__ y2s, const float* __restrict__ y2e,
    const float* __restrict__ Wg, const float* __restrict__ g, const float* __restrict__ be,
    float* __restrict__ z, u16* __restrict__ zbf)
{
    __shared__ float red[4];
    const long row = blockIdx.x;
    const int tid = threadIdx.x;
    const long base = row * 1024 + tid * 4;
    const int c = tid * 4;
    float4 sv = *(const float4*)(y2s + base);
    float4 ev = *(const float4*)(y2e + base);
    float4 w1 = *(const float4*)(Wg + c);
    float4 w2 = *(const float4*)(Wg + 1024 + c);
    float dot = sv.x*w1.x + sv.y*w1.y + sv.z*w1.z + sv.w*w1.w
              + ev.x*w2.x + ev.y*w2.y + ev.z*w2.z + ev.w*w2.w;
    float tot = block_sum(dot, red);
    float gate = 1.f / (1.f + __expf(-tot));
    u16x4 yv4 = *(const u16x4*)(yi + row * 1280 + c);
    float h0 = bf2f(yv4[0]) + 2.f * (gate * sv.x + (1.f - gate) * ev.x);
    float h1 = bf2f(yv4[1]) + 2.f * (gate * sv.y + (1.f - gate) * ev.y);
    float h2 = bf2f(yv4[2]) + 2.f * (gate * sv.z + (1.f - gate) * ev.z);
    float h3 = bf2f(yv4[3]) + 2.f * (gate * sv.w + (1.f - gate) * ev.w);
    float s1 = block_sum(h0 + h1 + h2 + h3, red);
    float s2 = block_sum(h0*h0 + h1*h1 + h2*h2 + h3*h3, red);
    float mean = s1 * (1.f/1024.f);
    float var = s2 * (1.f/1024.f) - mean * mean;
    float inv = rsqrtf(var + 1e-5f);
    float4 gv = *(const float4*)(g + c);
    float4 bv = *(const float4*)(be + c);
    float o0 = (h0 - mean) * inv * gv.x + bv.x;
    float o1 = (h1 - mean) * inv * gv.y + bv.y;
    float o2 = (h2 - mean) * inv * gv.z + bv.z;
    float o3 = (h3 - mean) * inv * gv.w + bv.w;
    *(float4*)(z + base) = make_float4(o0, o1, o2, o3);
    u16x4 ob = { f2bf(o0), f2bf(o1), f2bf(o2), f2bf(o3) };
    *(u16x4*)(zbf + row * 1024 + c) = ob;
}

// final LN over z + (p0 + p1 + b2)  — FFN2 split-K partials fused here
__global__ __launch_bounds__(256) void ln3_kernel(
    const float* __restrict__ z, const float* __restrict__ p0, const float* __restrict__ p1,
    const float* __restrict__ b2,
    const float* __restrict__ g, const float* __restrict__ be, float* __restrict__ out)
{
    __shared__ float red[4];
    const long row = blockIdx.x;
    const int tid = threadIdx.x;
    const long base = row * 1024 + tid * 4;
    const int c = tid * 4;
    float4 zv = *(const float4*)(z + base);
    float4 f0 = *(const float4*)(p0 + base);
    float4 f1 = *(const float4*)(p1 + base);
    float4 bb = *(const float4*)(b2 + c);
    float h0 = zv.x + f0.x + f1.x + bb.x;
    float h1 = zv.y + f0.y + f1.y + bb.y;
    float h2 = zv.z + f0.z + f1.z + bb.z;
    float h3 = zv.w + f0.w + f1.w + bb.w;
    float s1 = block_sum(h0 + h1 + h2 + h3, red);
    float s2 = block_sum(h0*h0 + h1*h1 + h2*h2 + h3*h3, red);
    float mean = s1 * (1.f/1024.f);
    float var = s2 * (1.f/1024.f) - mean * mean;
    float inv = rsqrtf(var + 1e-5f);
    float4 gv = *(const float4*)(g + c);
    float4 bv = *(const float4*)(be + c);
    float o0 = (h0 - mean) * inv * gv.x + bv.x;
    float o1 = (h1 - mean) * inv * gv.y + bv.y;
    float o2 = (h2 - mean) * inv * gv.z + bv.z;
    float o3 = (h3 - mean) * inv * gv.w + bv.w;
    *(float4*)(out + base) = make_float4(o0, o1, o2, o3);
}

// ---------------------------------------------------------------- host
extern "C" void kernel_launch(void* const* d_in, const int* in_sizes, int n_in,
                              void* d_out, int out_size, void* d_ws, size_t ws_size,
                              hipStream_t stream)
{
    (void)in_sizes; (void)n_in; (void)out_size; (void)ws_size;
    const float* x      = (const float*)d_in[0];
    const float* stat_e = (const float*)d_in[1];
    const float* exem   = (const float*)d_in[2];
    const float* sfeat  = (const float*)d_in[3];
    const float* intent = (const float*)d_in[4];
    const float* Wg  = (const float*)d_in[19];
    const float* b1  = (const float*)d_in[21];
    const float* b2  = (const float*)d_in[23];
    const float* g1  = (const float*)d_in[24]; const float* be1 = (const float*)d_in[25];
    const float* g2  = (const float*)d_in[26]; const float* be2 = (const float*)d_in[27];
    const float* g3  = (const float*)d_in[28]; const float* be3 = (const float*)d_in[29];
    const int* svl = (const int*)d_in[30];
    const int* evl = (const int*)d_in[31];
    float* outp = (float*)d_out;

    // ---- workspace plan: 171 MB, lifetime-aliased ----
    char* base = (char*)d_ws;
    u16*  bufA  = (u16*)(base + 0*MB);        // 8MB: xbf / attn-outs / y2s_pre
    u16*  qkv1  = (u16*)(base + 8*MB);        // 24MB fused [4096,3072] (phase 3)
    float* x2a  = (float*)(base + 8*MB);      // 16MB (after flash1)
    u16*  kv2   = (u16*)(base + 8*MB);        // 16MB fused [4096,2048] (phase 5)
    u16*  w1t   = (u16*)(base + 8*MB);        // 8MB (phase 7)
    u16*  w2t   = (u16*)(base + 16*MB);       // 8MB (phase 7)
    u16*  yibf  = (u16*)(base + 32*MB);       // 10MB [4096,1280]
    u16*  buf3  = (u16*)(base + 42*MB);       // 24MB fused qs|qt|q2 [4096,3072]
    u16*  zbf   = (u16*)(base + 42*MB);       // 8MB (after flash2)
    u16*  sebf  = (u16*)(base + 66*MB);       // 32MB stat_enc bf16 / tsc-half fp32 / ffn hidden
    float* tsch = (float*)(base + 66*MB);
    u16*  hid   = (u16*)(base + 66*MB);
    u16*  ktvv  = (u16*)(base + 98*MB);       // 64MB fused [16384,2048]
    float* y2sf = (float*)(base + 98*MB);     // 16MB (after select)
    float* p0f  = (float*)(base + 98*MB);     // 32MB FFN2 partials (after gate_ln2; y2ef dead)
    u16*  exbf  = (u16*)(base + 114*MB);      // 8MB
    float* y2ef = (float*)(base + 122*MB);    // 16MB
    float* zf   = (float*)(base + 138*MB);    // 16MB
    u16*  sfbf  = (u16*)(base + 162*MB);                  // 128KB
    u16*  ksbf  = (u16*)(base + 162*MB + 256*1024);       // 128KB
    float* sscf = (float*)(base + 162*MB + 512*1024);     // 256KB
    char* wpool = base + 163*MB;              // 8MB rotating weight pool (total 171MB)

    dim3 blk(256);
    dim3 blk512(512);
    auto cast = [&](const float* s, u16* d, long n) {
        cast_bf16_kernel<<<dim3((unsigned)((n/4 + 255) / 256)), blk, 0, stream>>>(s, d, n);
    };
    auto g_n = [&](const u16* A, const u16* Bt, u16* C, int M, int N, int K,
                   int lda, int ldb, int ldc) {
        gemm_bt<u16,false,false><<<dim3(N/128, (M+127)/128, 1), blk, 0, stream>>>(
            A, Bt, C, nullptr, M, N, K, lda, ldb, ldc, 1, 0, 0, 0);
    };
    auto g_f = [&](const u16* A, const u16* Bt, float* C, int M, int N, int K,
                   int lda, int ldb, int ldc) {
        gemm_bt<float,false,false><<<dim3(N/128, (M+127)/128, 1), blk, 0, stream>>>(
            A, Bt, C, nullptr, M, N, K, lda, ldb, ldc, 1, 0, 0, 0);
    };
    // M128xN256 depth-2 2-block/CU GEMM — M%128, N%256
    auto g128_n = [&](const u16* A, const u16* Bt, u16* C, int M, int N, int K,
                      int lda, int ldb, int ldc) {
        gemm_bt128<u16,false,false><<<dim3(N/256, M/128, 1), blk512, 0, stream>>>(
            A, Bt, C, nullptr, M, N, K, lda, ldb, ldc, 1, 0, 0, 0);
    };

    // ---- phase 3: self-attention ----
    u16* wqkv1t = (u16*)wpool;                       // [3072,1024] stacked
    u16* wo1t   = (u16*)(wpool) + 3L*1024*1024;
    {
        P6 pp{};
        pp.s[0]=(const float*)d_in[5]; pp.d[0]=wqkv1t;
        pp.s[1]=(const float*)d_in[6]; pp.d[1]=wqkv1t + 1L*1024*1024;
        pp.s[2]=(const float*)d_in[7]; pp.d[2]=wqkv1t + 2L*1024*1024;
        pp.s[3]=(const float*)d_in[8]; pp.d[3]=wo1t;
        transpose_cast_batch<<<dim3(32, 32, 4), blk, 0, stream>>>(pp, 1024, 1024);
    }
    cast(x, bufA, 4096L*1024);
    g128_n(bufA, wqkv1t, qkv1, 4096, 3072, 1024, 1024, 1024, 3072);
    flash_attn_kernel<true><<<dim3(16, 16, 4), blk, 0, stream>>>(
        qkv1, qkv1 + 1024, qkv1 + 2048, nullptr, bufA, 3072, 3072, 3072);
    g_f(bufA, wo1t, x2a, 4096, 1024, 1024, 1024, 1024, 1024);
    ln1_kernel<<<dim3(4096), blk, 0, stream>>>(x, x2a, intent, g1, be1, yibf);

    // ---- phase 4: selective hierarchical attention ----
    u16* wq3t = (u16*)wpool;
    {
        P6 pp{};
        pp.s[0]=(const float*)d_in[9];  pp.d[0]=wq3t;
        pp.s[1]=(const float*)d_in[10]; pp.d[1]=wq3t + 1L*1024*1280;
        pp.s[2]=(const float*)d_in[15]; pp.d[2]=wq3t + 2L*1024*1280;
        transpose_cast_batch<<<dim3(32, 40, 3), blk, 0, stream>>>(pp, 1280, 1024);
    }
    g128_n(yibf, wq3t, buf3, 4096, 3072, 1280, 1280, 1280, 3072);   // qs|qt|q2
    u16* wkst = (u16*)wpool;
    u16* wkv  = (u16*)(wpool) + 1L*1024*1024;
    {
        P6 pp{};
        pp.s[0]=(const float*)d_in[11]; pp.d[0]=wkst;
        pp.s[1]=(const float*)d_in[12]; pp.d[1]=wkv;
        pp.s[2]=(const float*)d_in[13]; pp.d[2]=wkv + 1L*1024*1024;
        transpose_cast_batch<<<dim3(32, 32, 3), blk, 0, stream>>>(pp, 1024, 1024);
    }
    cast(sfeat, sfbf, 64L*1024);
    cast(stat_e, sebf, 16384L*1024);
    g_n(sfbf, wkst, ksbf, 64, 1024, 1024, 1024, 1024, 1024);
    g128_n(sebf, wkv, ktvv, 16384, 2048, 1024, 1024, 1024, 2048);   // kt|vv
    ssc_kernel<<<dim3(1024, 4), blk, 0, stream>>>(buf3, ksbf, svl, sscf, 3072);
    for (int hh = 0; hh < 2; hh++) {
        long t0 = hh * 512;
        gemm_bt<float,false,false><<<dim3(2, 4, 64), blk, 0, stream>>>(
            buf3 + 1024 + t0*3072, ktvv, tsch, nullptr, 512, 256, 1024,
            3072, 2048, 256, 16, (long)T_N*3072, 256L*2048, 512L*256);
        select_combine_kernel<<<dim3(512, 4), blk, 0, stream>>>(
            sscf, tsch, ktvv + 1024, bufA, (int)t0, 2048);
    }
    u16* wost = (u16*)wpool;
    u16* wkv2 = (u16*)(wpool) + 1L*1024*1024;
    u16* wo2t = (u16*)(wpool) + 3L*1024*1024;
    {
        P6 pp{};
        pp.s[0]=(const float*)d_in[14]; pp.d[0]=wost;
        pp.s[1]=(const float*)d_in[16]; pp.d[1]=wkv2;
        pp.s[2]=(const float*)d_in[17]; pp.d[2]=wkv2 + 1L*1024*1024;
        pp.s[3]=(const float*)d_in[18]; pp.d[3]=wo2t;
        transpose_cast_batch<<<dim3(32, 32, 4), blk, 0, stream>>>(pp, 1024, 1024);
    }
    g_f(bufA, wost, y2sf, 4096, 1024, 1024, 1024, 1024, 1024);

    // ---- phase 5: exemplar cross-attention ----
    cast(exem, exbf, 4096L*1024);
    g_n(exbf, wkv2, kv2, 4096, 2048, 1024, 1024, 1024, 2048);       // k2|v2 (128^2: 512 blocks)
    flash_attn_kernel<false><<<dim3(16, 16, 4), blk, 0, stream>>>(
        buf3 + 2048, kv2, kv2 + 1024, evl, bufA, 3072, 2048, 2048);
    g_f(bufA, wo2t, y2ef, 4096, 1024, 1024, 1024, 1024, 1024);

    // ---- phase 6: gate + LN2 ----
    gate_ln2_kernel<<<dim3(4096), blk, 0, stream>>>(yibf, y2sf, y2ef, Wg, g2, be2, zf, zbf);

    // ---- phase 7: FFN ----
    {
        P6 pp{}; pp.s[0] = (const float*)d_in[20]; pp.d[0] = w1t;
        transpose_cast_batch<<<dim3(128, 32, 1), blk, 0, stream>>>(pp, 1024, 4096);
    }
    {
        P6 pp{}; pp.s[0] = (const float*)d_in[22]; pp.d[0] = w2t;
        transpose_cast_batch<<<dim3(32, 128, 1), blk, 0, stream>>>(pp, 4096, 1024);
    }
    gemm_bt128<u16,true,true><<<dim3(16, 32, 1), blk512, 0, stream>>>(
        zbf, w1t, hid, b1, 4096, 4096, 1024, 1024, 1024, 4096, 1, 0, 0, 0);
    // FFN2 split-K x2 in one dispatch (z picks K-half): p[z] = hid[:,z*2048:] @ w2t[:,z*2048:]^T
    gemm_bt<float,false,false><<<dim3(8, 32, 2), blk, 0, stream>>>(
        hid, w2t, p0f, nullptr, 4096, 1024, 2048, 4096, 4096, 1024,
        1, 2048, 2048, 4096L*1024);

    // ---- phase 8: final LN (fuses p0+p1+b2) ----
    ln3_kernel<<<dim3(4096), blk, 0, stream>>>(zf, p0f, p0f + 4096L*1024, b2, g3, be3, outp);
}